// Round 1
// baseline (644.706 us; speedup 1.0000x reference)
//
#include <hip/hip_runtime.h>
#include <math.h>

// Problem constants
#define B_ 4
#define L_ 2048
#define D_ 256
#define H_ 8
#define DH_ 32
#define NH_ 32           // B*H
#define U_ 40
#define LD_ 524288       // L_*D_ floats per batch

static __device__ __forceinline__ unsigned long long ullmin_(unsigned long long a, unsigned long long b) {
    return a < b ? a : b;
}

// ---------------------------------------------------------------------------
// Generic Y[r,c] = sum_k X[r,k] * W[c,k] + bias[c];  N=K=256 fixed, M variable.
// 64x64 tile, 256 threads, 4x4 per thread. LDS leading pad 68 (=17 float4s):
// store bank = (4*kk + r)%32 -> 4-way on store only; b128 reads conflict-free.
// ---------------------------------------------------------------------------
__global__ __launch_bounds__(256) void gemm_xwT(const float* __restrict__ X,
                                                const float* __restrict__ W,
                                                const float* __restrict__ bias,
                                                float* __restrict__ Y, int M) {
    __shared__ float As[32 * 68];
    __shared__ float Bs[32 * 68];
    const int tid = threadIdx.x;
    const int tx = tid & 15, ty = tid >> 4;
    const int rowBase = blockIdx.x * 64;
    const int colBase = blockIdx.y * 64;

    float acc[4][4] = {};

    for (int kt = 0; kt < 256; kt += 32) {
#pragma unroll
        for (int jj = 0; jj < 8; ++jj) {
            int e = tid + 256 * jj;
            int r = e >> 5, kk = e & 31;
            int gr = rowBase + r;
            float xv = (gr < M) ? X[(size_t)gr * 256 + kt + kk] : 0.f;
            As[kk * 68 + r] = xv;
            int gc = colBase + r;  // always < 256
            Bs[kk * 68 + r] = W[(size_t)gc * 256 + kt + kk];
        }
        __syncthreads();
#pragma unroll
        for (int kk = 0; kk < 32; ++kk) {
            const float4 a4 = *(const float4*)&As[kk * 68 + ty * 4];
            const float4 b4 = *(const float4*)&Bs[kk * 68 + tx * 4];
            float av[4] = {a4.x, a4.y, a4.z, a4.w};
            float bv[4] = {b4.x, b4.y, b4.z, b4.w};
#pragma unroll
            for (int i = 0; i < 4; ++i)
#pragma unroll
                for (int j = 0; j < 4; ++j)
                    acc[i][j] = fmaf(av[i], bv[j], acc[i][j]);
        }
        __syncthreads();
    }

#pragma unroll
    for (int i = 0; i < 4; ++i) {
        int gr = rowBase + ty * 4 + i;
        if (gr >= M) continue;
#pragma unroll
        for (int j = 0; j < 4; ++j) {
            int gc = colBase + tx * 4 + j;
            Y[(size_t)gr * 256 + gc] = acc[i][j] + bias[gc];
        }
    }
}

// ---------------------------------------------------------------------------
// Ssum[i][d] = sum_u kp[b, idx[u], h*32+d]   (i = b*8+h, u over all 2048)
// ---------------------------------------------------------------------------
__global__ __launch_bounds__(256) void ksum_kernel(const float* __restrict__ kp,
                                                   const int* __restrict__ idx,
                                                   float* __restrict__ Ssum) {
    const int i = blockIdx.x;
    const int b = i >> 3, h = i & 7;
    const int t = threadIdx.x;
    const int d = t & 31, g = t >> 5;
    const float* base = kp + (size_t)b * LD_ + h * DH_ + d;
    float acc = 0.f;
    for (int u = g; u < L_; u += 8) acc += base[(size_t)idx[u] * D_];
    __shared__ float part[256];
    part[t] = acc;
    __syncthreads();
    if (t < 32) {
        float s = 0.f;
#pragma unroll
        for (int g2 = 0; g2 < 8; ++g2) s += part[g2 * 32 + t];
        Ssum[i * 32 + t] = s;
    }
}

// ---------------------------------------------------------------------------
// Partial max over a u-range: Mpart[(i*2048+l)*4 + uh] = max_{u in group uh}
//   qf[i,l]·K_sample[i,u].   Grid: 32 i x 4 ltile x 4 uh = 512 blocks.
// Each thread handles 2 l rows (l0, l0+256); K rows staged to LDS (gathered).
// ---------------------------------------------------------------------------
__global__ __launch_bounds__(256) void mpart_kernel(const float* __restrict__ qp,
                                                    const float* __restrict__ kp,
                                                    const int* __restrict__ idx,
                                                    float* __restrict__ Mpart) {
    const int blk = blockIdx.x;
    const int uh = blk & 3;
    const int lt = (blk >> 2) & 3;
    const int i = blk >> 4;
    const int b = i >> 3, h = i & 7;
    const int t = threadIdx.x;
    const int l0 = lt * 512 + t;  // and l0 + 256

    float qv0[32], qv1[32];
    {
        const float4* q0 = (const float4*)(qp + (size_t)i * 65536 + (size_t)l0 * 32);
        const float4* q1 = (const float4*)(qp + (size_t)i * 65536 + (size_t)(l0 + 256) * 32);
#pragma unroll
        for (int z = 0; z < 8; ++z) {
            float4 a = q0[z];
            qv0[4 * z] = a.x; qv0[4 * z + 1] = a.y; qv0[4 * z + 2] = a.z; qv0[4 * z + 3] = a.w;
            float4 c = q1[z];
            qv1[4 * z] = c.x; qv1[4 * z + 1] = c.y; qv1[4 * z + 2] = c.z; qv1[4 * z + 3] = c.w;
        }
    }

    __shared__ float Ks[128 * 32];
    const float* kbase = kp + (size_t)b * LD_ + h * DH_;
    float m0 = -INFINITY, m1 = -INFINITY;
    const int ubase = uh * 512;

    for (int ut = 0; ut < 4; ++ut) {
        const int u0 = ubase + ut * 128;
#pragma unroll
        for (int jj = 0; jj < 16; ++jj) {
            int e = t + 256 * jj;
            int ul = e >> 5, d2 = e & 31;
            Ks[e] = kbase[(size_t)idx[u0 + ul] * D_ + d2];
        }
        __syncthreads();
#pragma unroll 2
        for (int ul = 0; ul < 128; ++ul) {
            const float4* kr = (const float4*)&Ks[ul * 32];
            float a0 = 0, a1 = 0, a2 = 0, a3 = 0;
            float c0 = 0, c1 = 0, c2 = 0, c3 = 0;
#pragma unroll
            for (int z = 0; z < 8; ++z) {
                float4 kv = kr[z];
                a0 = fmaf(qv0[4 * z], kv.x, a0);
                a1 = fmaf(qv0[4 * z + 1], kv.y, a1);
                a2 = fmaf(qv0[4 * z + 2], kv.z, a2);
                a3 = fmaf(qv0[4 * z + 3], kv.w, a3);
                c0 = fmaf(qv1[4 * z], kv.x, c0);
                c1 = fmaf(qv1[4 * z + 1], kv.y, c1);
                c2 = fmaf(qv1[4 * z + 2], kv.z, c2);
                c3 = fmaf(qv1[4 * z + 3], kv.w, c3);
            }
            m0 = fmaxf(m0, (a0 + a1) + (a2 + a3));
            m1 = fmaxf(m1, (c0 + c1) + (c2 + c3));
        }
        __syncthreads();
    }
    Mpart[((size_t)i * 2048 + l0) * 4 + uh] = m0;
    Mpart[((size_t)i * 2048 + l0 + 256) * 4 + uh] = m1;
}

// ---------------------------------------------------------------------------
// Mv[i,l] = max(parts) - (qf[i,l]·Ssum[i]) / L
// ---------------------------------------------------------------------------
__global__ __launch_bounds__(256) void mcombine_kernel(const float* __restrict__ Mpart,
                                                       const float* __restrict__ qp,
                                                       const float* __restrict__ Ssum,
                                                       float* __restrict__ Mv) {
    const int blk = blockIdx.x;  // 256 blocks
    const int i = blk >> 3;
    const int lt = blk & 7;
    const int t = threadIdx.x;
    const int l = lt * 256 + t;
    const float4 p = *(const float4*)&Mpart[((size_t)i * 2048 + l) * 4];
    float vmax = fmaxf(fmaxf(p.x, p.y), fmaxf(p.z, p.w));
    const float4* q = (const float4*)(qp + (size_t)i * 65536 + (size_t)l * 32);
    const float4* s = (const float4*)(Ssum + i * 32);
    float qs = 0.f;
#pragma unroll
    for (int z = 0; z < 8; ++z) {
        float4 a = q[z];
        float4 c = s[z];
        qs = fmaf(a.x, c.x, qs);
        qs = fmaf(a.y, c.y, qs);
        qs = fmaf(a.z, c.z, qs);
        qs = fmaf(a.w, c.w, qs);
    }
    Mv[(size_t)i * 2048 + l] = vmax - qs * (1.0f / 2048.0f);
}

// ---------------------------------------------------------------------------
// Exact top-40 smallest Mv per i, ascending, ties -> smaller index
// (matches jax.lax.top_k(-M) stable order). 40 x argmin via uint64 keys.
// ---------------------------------------------------------------------------
__global__ __launch_bounds__(256) void topk_kernel(const float* __restrict__ Mv,
                                                   int* __restrict__ topIdx) {
    const int i = blockIdx.x;
    const int t = threadIdx.x;
    __shared__ float mv[2048];
    __shared__ unsigned long long wred[4];
#pragma unroll
    for (int j = 0; j < 8; ++j) mv[t + 256 * j] = Mv[(size_t)i * 2048 + t + 256 * j];
    __syncthreads();
    for (int it = 0; it < 40; ++it) {
        unsigned long long best = ~0ULL;
#pragma unroll
        for (int j = 0; j < 8; ++j) {
            int l = t + 256 * j;
            unsigned u32 = __float_as_uint(mv[l]);
            u32 = (u32 & 0x80000000u) ? ~u32 : (u32 | 0x80000000u);
            best = ullmin_(best, ((unsigned long long)u32 << 32) | (unsigned)l);
        }
#pragma unroll
        for (int off = 32; off > 0; off >>= 1)
            best = ullmin_(best, __shfl_down(best, off, 64));
        if ((t & 63) == 0) wred[t >> 6] = best;
        __syncthreads();
        if (t == 0) {
            unsigned long long m = ullmin_(ullmin_(wred[0], wred[1]), ullmin_(wred[2], wred[3]));
            int l = (int)(m & 0xffffffffu);
            topIdx[i * 40 + it] = l;
            mv[l] = INFINITY;
        }
        __syncthreads();
    }
}

// ---------------------------------------------------------------------------
// Dense attention for the 40 selected queries. Block per (i, j).
// scores in LDS, exact two-pass softmax, coalesced PV accumulation.
// attnOut[b*40+j][h*32+d]
// ---------------------------------------------------------------------------
__global__ __launch_bounds__(256) void attn_kernel(const float* __restrict__ qp,
                                                   const float* __restrict__ kp,
                                                   const float* __restrict__ vp,
                                                   const int* __restrict__ topIdx,
                                                   float* __restrict__ attnOut) {
    const int blk = blockIdx.x;
    const int i = blk / 40, j = blk % 40;
    const int b = i >> 3, h = i & 7;
    const int t = threadIdx.x;
    __shared__ float sc[2048];
    __shared__ float qsh[32];
    __shared__ float red[12];
    __shared__ float outp[256];

    const int lq = topIdx[i * 40 + j];
    if (t < 32) qsh[t] = qp[(size_t)i * 65536 + (size_t)lq * 32 + t];
    __syncthreads();
    float qv[32];
#pragma unroll
    for (int d = 0; d < 32; ++d) qv[d] = qsh[d];

    const float scale = 0.17677669529663687f;  // 1/sqrt(32)
    const float* kbase = kp + (size_t)b * LD_ + h * DH_;
    float lmax = -INFINITY;
#pragma unroll
    for (int jj = 0; jj < 8; ++jj) {
        int l = t + 256 * jj;
        const float4* kr = (const float4*)(kbase + (size_t)l * D_);
        float a0 = 0, a1 = 0, a2 = 0, a3 = 0;
#pragma unroll
        for (int z = 0; z < 8; ++z) {
            float4 kv = kr[z];
            a0 = fmaf(qv[4 * z], kv.x, a0);
            a1 = fmaf(qv[4 * z + 1], kv.y, a1);
            a2 = fmaf(qv[4 * z + 2], kv.z, a2);
            a3 = fmaf(qv[4 * z + 3], kv.w, a3);
        }
        float s = ((a0 + a1) + (a2 + a3)) * scale;
        sc[l] = s;
        lmax = fmaxf(lmax, s);
    }
#pragma unroll
    for (int off = 32; off > 0; off >>= 1)
        lmax = fmaxf(lmax, __shfl_down(lmax, off, 64));
    if ((t & 63) == 0) red[t >> 6] = lmax;
    __syncthreads();
    const float bmax = fmaxf(fmaxf(red[0], red[1]), fmaxf(red[2], red[3]));

    float lsum = 0.f;
#pragma unroll
    for (int jj = 0; jj < 8; ++jj) {
        int l = t + 256 * jj;
        float e = __expf(sc[l] - bmax);
        sc[l] = e;
        lsum += e;
    }
#pragma unroll
    for (int off = 32; off > 0; off >>= 1)
        lsum += __shfl_down(lsum, off, 64);
    if ((t & 63) == 0) red[8 - 4 + (t >> 6) + 4] = lsum;  // red[8..11]
    __syncthreads();
    const float bsum = (red[8] + red[9]) + (red[10] + red[11]);

    const int d = t & 31, g = t >> 5;
    const float* vbase = vp + (size_t)b * LD_ + h * DH_ + d;
    float acc = 0.f;
    for (int l = g; l < 2048; l += 8)
        acc = fmaf(sc[l], vbase[(size_t)l * D_], acc);
    outp[t] = acc;
    __syncthreads();
    if (t < 32) {
        float s = 0.f;
#pragma unroll
        for (int g2 = 0; g2 < 8; ++g2) s += outp[g2 * 32 + t];
        attnOut[((size_t)b * 40 + j) * 256 + h * 32 + t] = s / bsum;
    }
}

// ---------------------------------------------------------------------------
extern "C" void kernel_launch(void* const* d_in, const int* in_sizes, int n_in,
                              void* d_out, int out_size, void* d_ws, size_t ws_size,
                              hipStream_t stream) {
    const float* q  = (const float*)d_in[0];
    const float* k  = (const float*)d_in[1];
    const float* v  = (const float*)d_in[2];
    const float* Wq = (const float*)d_in[3];
    const float* bq = (const float*)d_in[4];
    const float* Wk = (const float*)d_in[5];
    const float* bk = (const float*)d_in[6];
    const float* Wv = (const float*)d_in[7];
    const float* bv = (const float*)d_in[8];
    const float* Wc = (const float*)d_in[9];
    const float* bc = (const float*)d_in[10];
    const int* idx  = (const int*)d_in[11];
    float* out = (float*)d_out;

    char* w = (char*)d_ws;
    float* qp     = (float*)(w);                    // 8 MB
    float* kp     = (float*)(w + (8u << 20));       // 8 MB
    float* vp     = (float*)(w + (16u << 20));      // 8 MB
    float* Mpart  = (float*)(w + (24u << 20));      // 1 MB
    float* Mv     = (float*)(w + (25u << 20));      // 256 KB
    float* Ssum   = (float*)(w + (25u << 20) + (512u << 10));  // 4 KB
    int*   topIdx = (int*)  (w + (25u << 20) + (768u << 10));  // 5 KB
    float* attnOut= (float*)(w + (26u << 20));      // 160 KB

    const int Mrows = B_ * L_;  // 8192
    dim3 gProj((Mrows + 63) / 64, 4);
    hipLaunchKernelGGL(gemm_xwT, gProj, dim3(256), 0, stream, q, Wq, bq, qp, Mrows);
    hipLaunchKernelGGL(gemm_xwT, gProj, dim3(256), 0, stream, k, Wk, bk, kp, Mrows);
    hipLaunchKernelGGL(gemm_xwT, gProj, dim3(256), 0, stream, v, Wv, bv, vp, Mrows);

    hipLaunchKernelGGL(ksum_kernel, dim3(32), dim3(256), 0, stream, kp, idx, Ssum);
    hipLaunchKernelGGL(mpart_kernel, dim3(512), dim3(256), 0, stream, qp, kp, idx, Mpart);
    hipLaunchKernelGGL(mcombine_kernel, dim3(256), dim3(256), 0, stream, Mpart, qp, Ssum, Mv);
    hipLaunchKernelGGL(topk_kernel, dim3(32), dim3(256), 0, stream, Mv, topIdx);
    hipLaunchKernelGGL(attn_kernel, dim3(NH_ * U_), dim3(256), 0, stream, qp, kp, vp, topIdx, attnOut);

    dim3 gOut((B_ * U_ + 63) / 64, 4);  // M = 160
    hipLaunchKernelGGL(gemm_xwT, gOut, dim3(256), 0, stream, attnOut, Wc, bc, out, B_ * U_);
}

// Round 2
// 576.598 us; speedup vs baseline: 1.1181x; 1.1181x over previous
//
#include <hip/hip_runtime.h>
#include <math.h>

// Problem constants
#define B_ 4
#define L_ 2048
#define D_ 256
#define H_ 8
#define DH_ 32
#define NH_ 32           // B*H
#define U_ 40
#define LD_ 524288       // L_*D_ floats per batch

typedef __attribute__((ext_vector_type(8))) short short8;
typedef __attribute__((ext_vector_type(4))) float floatx4;

static __device__ __forceinline__ unsigned long long ullmin_(unsigned long long a, unsigned long long b) {
    return a < b ? a : b;
}
static __device__ __forceinline__ unsigned short f2bf_rne(float x) {
    unsigned u = __float_as_uint(x);
    unsigned r = u + 0x7FFFu + ((u >> 16) & 1u);
    return (unsigned short)(r >> 16);
}
static __device__ __forceinline__ float bf2f(unsigned short h) {
    return __uint_as_float(((unsigned)h) << 16);
}

// ---------------------------------------------------------------------------
// Generic Y[r,c] = sum_k X[r,k] * W[c,k] + bias[c];  N=K=256 fixed, M variable.
// ---------------------------------------------------------------------------
__global__ __launch_bounds__(256) void gemm_xwT(const float* __restrict__ X,
                                                const float* __restrict__ W,
                                                const float* __restrict__ bias,
                                                float* __restrict__ Y, int M) {
    __shared__ float As[32 * 68];
    __shared__ float Bs[32 * 68];
    const int tid = threadIdx.x;
    const int tx = tid & 15, ty = tid >> 4;
    const int rowBase = blockIdx.x * 64;
    const int colBase = blockIdx.y * 64;

    float acc[4][4] = {};

    for (int kt = 0; kt < 256; kt += 32) {
#pragma unroll
        for (int jj = 0; jj < 8; ++jj) {
            int e = tid + 256 * jj;
            int r = e >> 5, kk = e & 31;
            int gr = rowBase + r;
            float xv = (gr < M) ? X[(size_t)gr * 256 + kt + kk] : 0.f;
            As[kk * 68 + r] = xv;
            int gc = colBase + r;  // always < 256
            Bs[kk * 68 + r] = W[(size_t)gc * 256 + kt + kk];
        }
        __syncthreads();
#pragma unroll
        for (int kk = 0; kk < 32; ++kk) {
            const float4 a4 = *(const float4*)&As[kk * 68 + ty * 4];
            const float4 b4 = *(const float4*)&Bs[kk * 68 + tx * 4];
            float av[4] = {a4.x, a4.y, a4.z, a4.w};
            float bv[4] = {b4.x, b4.y, b4.z, b4.w};
#pragma unroll
            for (int i = 0; i < 4; ++i)
#pragma unroll
                for (int j = 0; j < 4; ++j)
                    acc[i][j] = fmaf(av[i], bv[j], acc[i][j]);
        }
        __syncthreads();
    }

#pragma unroll
    for (int i = 0; i < 4; ++i) {
        int gr = rowBase + ty * 4 + i;
        if (gr >= M) continue;
#pragma unroll
        for (int j = 0; j < 4; ++j) {
            int gc = colBase + tx * 4 + j;
            Y[(size_t)gr * 256 + gc] = acc[i][j] + bias[gc];
        }
    }
}

// ---------------------------------------------------------------------------
// Ssum[i][d] = sum_u kp[b, idx[u], h*32+d]
// ---------------------------------------------------------------------------
__global__ __launch_bounds__(256) void ksum_kernel(const float* __restrict__ kp,
                                                   const int* __restrict__ idx,
                                                   float* __restrict__ Ssum) {
    const int i = blockIdx.x;
    const int b = i >> 3, h = i & 7;
    const int t = threadIdx.x;
    const int d = t & 31, g = t >> 5;
    const float* base = kp + (size_t)b * LD_ + h * DH_ + d;
    float acc = 0.f;
    for (int u = g; u < L_; u += 8) acc += base[(size_t)idx[u] * D_];
    __shared__ float part[256];
    part[t] = acc;
    __syncthreads();
    if (t < 32) {
        float s = 0.f;
#pragma unroll
        for (int g2 = 0; g2 < 8; ++g2) s += part[g2 * 32 + t];
        Ssum[i * 32 + t] = s;
    }
}

// ---------------------------------------------------------------------------
// Gather K_sample rows per head and split fp32 -> bf16 hi/lo.
// Khi/Klo layout: [i][u][d] bf16, contiguous (i=b*8+h, u=0..2047, d=0..31)
// ---------------------------------------------------------------------------
__global__ __launch_bounds__(256) void kconv_kernel(const float* __restrict__ kp,
                                                    const int* __restrict__ idx,
                                                    unsigned short* __restrict__ Khi,
                                                    unsigned short* __restrict__ Klo) {
    const int blk = blockIdx.x;  // 256: i*8 + uc
    const int i = blk >> 3, uc = blk & 7;
    const int b = i >> 3, h = i & 7;
    const int t = threadIdx.x;
    const int dq = (t & 7) * 4;
    const int ur = t >> 3;  // 0..31
#pragma unroll
    for (int p = 0; p < 8; ++p) {
        int u = uc * 256 + p * 32 + ur;
        const float4 x = *(const float4*)(kp + (size_t)b * LD_ + (size_t)idx[u] * D_ + h * DH_ + dq);
        float xs[4] = {x.x, x.y, x.z, x.w};
        unsigned short hv[4], lv[4];
#pragma unroll
        for (int j = 0; j < 4; ++j) {
            hv[j] = f2bf_rne(xs[j]);
            lv[j] = f2bf_rne(xs[j] - bf2f(hv[j]));
        }
        size_t o = ((size_t)i * 2048 + u) * 32 + dq;
        *(ushort4*)(Khi + o) = make_ushort4(hv[0], hv[1], hv[2], hv[3]);
        *(ushort4*)(Klo + o) = make_ushort4(lv[0], lv[1], lv[2], lv[3]);
    }
}

// ---------------------------------------------------------------------------
// Approx M-sweep on MFMA: Mmax[i][l] = max_u qf[i,l]·K_sample[i,u]
// via split-bf16 (hi*hi + hi*lo + lo*hi), 16x16x32 MFMA, K=32=DH.
// Block: 256 thr = 4 waves; block covers 64 l rows (4 l-tiles per wave,
// all waves same l-set); waves split u into 4 quarters of 512.
// No LDS in hot loop: B-frags stream from L2.
// Grid: 32 i * 32 lgroups = 1024 blocks.
// ---------------------------------------------------------------------------
__global__ __launch_bounds__(256) void mpart_mfma(const float* __restrict__ qp,
                                                  const unsigned short* __restrict__ Khi,
                                                  const unsigned short* __restrict__ Klo,
                                                  float* __restrict__ Mmax) {
    const int blk = blockIdx.x;
    const int i = blk >> 5;
    const int lg = blk & 31;
    const int t = threadIdx.x;
    const int w = t >> 6;
    const int lane = t & 63;
    const int lq = lane & 15;    // A m-index (l within tile) / B n-index (u within tile)
    const int quad = lane >> 4;  // k-group: k = quad*8 + j

    // A fragments (Q rows), converted fp32 -> bf16 hi/lo in-registers.
    short8 Ah[4], Al[4];
#pragma unroll
    for (int lt = 0; lt < 4; ++lt) {
        const int l = lg * 64 + lt * 16 + lq;
        const float* qrow = qp + ((size_t)i * 2048 + l) * 32 + quad * 8;
        float4 x0 = *(const float4*)(qrow);
        float4 x1 = *(const float4*)(qrow + 4);
        float xs[8] = {x0.x, x0.y, x0.z, x0.w, x1.x, x1.y, x1.z, x1.w};
#pragma unroll
        for (int j = 0; j < 8; ++j) {
            unsigned short h = f2bf_rne(xs[j]);
            unsigned short lo = f2bf_rne(xs[j] - bf2f(h));
            Ah[lt][j] = (short)h;
            Al[lt][j] = (short)lo;
        }
    }

    floatx4 rmax[4];
#pragma unroll
    for (int lt = 0; lt < 4; ++lt)
        rmax[lt] = (floatx4){-INFINITY, -INFINITY, -INFINITY, -INFINITY};

    const size_t kfrag = ((size_t)i * 2048 + w * 512 + lq) * 32 + quad * 8;
    const unsigned short* ph = Khi + kfrag;
    const unsigned short* pl = Klo + kfrag;
#pragma unroll 2
    for (int s = 0; s < 32; ++s) {
        short8 Bh = *(const short8*)(ph + (size_t)s * 512);
        short8 Bl = *(const short8*)(pl + (size_t)s * 512);
#pragma unroll
        for (int lt = 0; lt < 4; ++lt) {
            floatx4 acc = (floatx4){0.f, 0.f, 0.f, 0.f};
            acc = __builtin_amdgcn_mfma_f32_16x16x32_bf16(Al[lt], Bh, acc, 0, 0, 0);
            acc = __builtin_amdgcn_mfma_f32_16x16x32_bf16(Ah[lt], Bl, acc, 0, 0, 0);
            acc = __builtin_amdgcn_mfma_f32_16x16x32_bf16(Ah[lt], Bh, acc, 0, 0, 0);
#pragma unroll
            for (int r = 0; r < 4; ++r) rmax[lt][r] = fmaxf(rmax[lt][r], acc[r]);
        }
    }

    // C layout: row(l) = quad*4 + reg, col(u) = lane&15. Reduce max over cols.
#pragma unroll
    for (int lt = 0; lt < 4; ++lt)
#pragma unroll
        for (int r = 0; r < 4; ++r) {
            float v = rmax[lt][r];
#pragma unroll
            for (int off = 1; off < 16; off <<= 1)
                v = fmaxf(v, __shfl_xor(v, off, 64));
            rmax[lt][r] = v;
        }
    __shared__ float red[4][64];
    if (lq == 0) {
#pragma unroll
        for (int lt = 0; lt < 4; ++lt)
#pragma unroll
            for (int r = 0; r < 4; ++r)
                red[w][lt * 16 + quad * 4 + r] = rmax[lt][r];
    }
    __syncthreads();
    if (t < 64) {
        float m = fmaxf(fmaxf(red[0][t], red[1][t]), fmaxf(red[2][t], red[3][t]));
        Mmax[(size_t)i * 2048 + lg * 64 + t] = m;
    }
}

// ---------------------------------------------------------------------------
// Mv[i,l] = Mmax[i,l] - qmean;  also stores Qmean[i,l] = (q·Ssum)/L for refine.
// ---------------------------------------------------------------------------
__global__ __launch_bounds__(256) void mcombine_kernel(const float* __restrict__ Mmax,
                                                       const float* __restrict__ qp,
                                                       const float* __restrict__ Ssum,
                                                       float* __restrict__ Mv,
                                                       float* __restrict__ Qmean) {
    const int blk = blockIdx.x;  // 256 blocks
    const int i = blk >> 3;
    const int lt = blk & 7;
    const int t = threadIdx.x;
    const int l = lt * 256 + t;
    const float4* q = (const float4*)(qp + (size_t)i * 65536 + (size_t)l * 32);
    const float4* s = (const float4*)(Ssum + i * 32);
    float qs = 0.f;
#pragma unroll
    for (int z = 0; z < 8; ++z) {
        float4 a = q[z];
        float4 c = s[z];
        qs = fmaf(a.x, c.x, qs);
        qs = fmaf(a.y, c.y, qs);
        qs = fmaf(a.z, c.z, qs);
        qs = fmaf(a.w, c.w, qs);
    }
    float qm = qs * (1.0f / 2048.0f);
    Qmean[(size_t)i * 2048 + l] = qm;
    Mv[(size_t)i * 2048 + l] = Mmax[(size_t)i * 2048 + l] - qm;
}

// ---------------------------------------------------------------------------
// Bottom-64 candidates per i from approx Mv (ascending, index tie-break).
// ---------------------------------------------------------------------------
__global__ __launch_bounds__(256) void topk64_kernel(const float* __restrict__ Mv,
                                                     int* __restrict__ candIdx) {
    const int i = blockIdx.x;
    const int t = threadIdx.x;
    __shared__ unsigned long long keys[2048];
    __shared__ unsigned long long wred[4];
#pragma unroll
    for (int j = 0; j < 8; ++j) {
        int l = t + 256 * j;
        unsigned u32 = __float_as_uint(Mv[(size_t)i * 2048 + l]);
        u32 = (u32 & 0x80000000u) ? ~u32 : (u32 | 0x80000000u);
        keys[l] = ((unsigned long long)u32 << 32) | (unsigned)l;
    }
    __syncthreads();
    for (int it = 0; it < 64; ++it) {
        unsigned long long best = ~0ULL;
#pragma unroll
        for (int j = 0; j < 8; ++j) best = ullmin_(best, keys[t + 256 * j]);
#pragma unroll
        for (int off = 32; off > 0; off >>= 1)
            best = ullmin_(best, __shfl_down(best, off, 64));
        if ((t & 63) == 0) wred[t >> 6] = best;
        __syncthreads();
        unsigned long long m = ullmin_(ullmin_(wred[0], wred[1]), ullmin_(wred[2], wred[3]));
        int l = (int)(m & 0xffffffffu);
        if (t == 0) {
            candIdx[i * 64 + it] = l;
            keys[l] = ~0ULL;
        }
        __syncthreads();
    }
}

// ---------------------------------------------------------------------------
// Exact fp32 re-computation of max_u q·K_sample for the 64 candidates.
// Grid: 32 i x 4 u-chunks (512 u each). Thread: cand = t>>2, usub = t&3.
// ---------------------------------------------------------------------------
__global__ __launch_bounds__(256) void refine_kernel(const float* __restrict__ qp,
                                                     const float* __restrict__ kp,
                                                     const int* __restrict__ idx,
                                                     const int* __restrict__ candIdx,
                                                     float* __restrict__ refPart) {
    const int blk = blockIdx.x;  // 128
    const int i = blk >> 2, c = blk & 3;
    const int b = i >> 3, h = i & 7;
    const int t = threadIdx.x;
    __shared__ float qc[64][40];
    __shared__ float Ks[128][40];

    {
        const int cand = t >> 2, dp = (t & 3) * 8;
        const int l = candIdx[i * 64 + cand];
        const float* src = qp + ((size_t)i * 2048 + l) * 32 + dp;
        *(float4*)&qc[cand][dp] = *(const float4*)(src);
        *(float4*)&qc[cand][dp + 4] = *(const float4*)(src + 4);
    }
    __syncthreads();

    const int cand = t >> 2, usub = t & 3;
    float qv[32];
#pragma unroll
    for (int z = 0; z < 8; ++z) {
        float4 a = *(const float4*)&qc[cand][z * 4];
        qv[4 * z] = a.x; qv[4 * z + 1] = a.y; qv[4 * z + 2] = a.z; qv[4 * z + 3] = a.w;
    }

    float m = -INFINITY;
    for (int s = 0; s < 4; ++s) {
        {
            const int r = t >> 1, half = t & 1;
            const int u = c * 512 + s * 128 + r;
            const float* krow = kp + (size_t)b * LD_ + (size_t)idx[u] * D_ + h * DH_ + half * 16;
#pragma unroll
            for (int z = 0; z < 4; ++z)
                *(float4*)&Ks[r][half * 16 + z * 4] = *(const float4*)(krow + z * 4);
        }
        __syncthreads();
        for (int ur = usub; ur < 128; ur += 4) {
            float a0 = 0, a1 = 0, a2 = 0, a3 = 0;
#pragma unroll
            for (int z = 0; z < 8; ++z) {
                float4 kv = *(const float4*)&Ks[ur][z * 4];
                a0 = fmaf(qv[4 * z], kv.x, a0);
                a1 = fmaf(qv[4 * z + 1], kv.y, a1);
                a2 = fmaf(qv[4 * z + 2], kv.z, a2);
                a3 = fmaf(qv[4 * z + 3], kv.w, a3);
            }
            m = fmaxf(m, (a0 + a1) + (a2 + a3));
        }
        __syncthreads();
    }
#pragma unroll
    for (int off = 1; off < 4; off <<= 1)
        m = fmaxf(m, __shfl_xor(m, off, 64));
    if ((t & 3) == 0) refPart[((size_t)i * 4 + c) * 64 + cand] = m;
}

// ---------------------------------------------------------------------------
// Final exact top-40 (ascending exact M, index tie-break) from 64 candidates.
// One wave per i.
// ---------------------------------------------------------------------------
__global__ __launch_bounds__(64) void select40_kernel(const int* __restrict__ candIdx,
                                                      const float* __restrict__ refPart,
                                                      const float* __restrict__ Qmean,
                                                      int* __restrict__ topIdx) {
    const int i = blockIdx.x;
    const int t = threadIdx.x;
    const int l = candIdx[i * 64 + t];
    float m = -INFINITY;
#pragma unroll
    for (int c = 0; c < 4; ++c) m = fmaxf(m, refPart[((size_t)i * 4 + c) * 64 + t]);
    float Mex = m - Qmean[(size_t)i * 2048 + l];
    unsigned u32 = __float_as_uint(Mex);
    u32 = (u32 & 0x80000000u) ? ~u32 : (u32 | 0x80000000u);
    unsigned long long key = ((unsigned long long)u32 << 32) | (unsigned)l;
    for (int it = 0; it < 40; ++it) {
        unsigned long long k2 = key;
#pragma unroll
        for (int off = 1; off < 64; off <<= 1) k2 = ullmin_(k2, __shfl_xor(k2, off, 64));
        if (key == k2) {
            topIdx[i * 40 + it] = l;
            key = ~0ULL;
        }
    }
}

// ---------------------------------------------------------------------------
// Dense attention for the 40 selected queries (exact fp32).
// ---------------------------------------------------------------------------
__global__ __launch_bounds__(256) void attn_kernel(const float* __restrict__ qp,
                                                   const float* __restrict__ kp,
                                                   const float* __restrict__ vp,
                                                   const int* __restrict__ topIdx,
                                                   float* __restrict__ attnOut) {
    const int blk = blockIdx.x;
    const int i = blk / 40, j = blk % 40;
    const int b = i >> 3, h = i & 7;
    const int t = threadIdx.x;
    __shared__ float sc[2048];
    __shared__ float qsh[32];
    __shared__ float red[12];
    __shared__ float outp[256];

    const int lq = topIdx[i * 40 + j];
    if (t < 32) qsh[t] = qp[(size_t)i * 65536 + (size_t)lq * 32 + t];
    __syncthreads();
    float qv[32];
#pragma unroll
    for (int d = 0; d < 32; ++d) qv[d] = qsh[d];

    const float scale = 0.17677669529663687f;  // 1/sqrt(32)
    const float* kbase = kp + (size_t)b * LD_ + h * DH_;
    float lmax = -INFINITY;
#pragma unroll
    for (int jj = 0; jj < 8; ++jj) {
        int l = t + 256 * jj;
        const float4* kr = (const float4*)(kbase + (size_t)l * D_);
        float a0 = 0, a1 = 0, a2 = 0, a3 = 0;
#pragma unroll
        for (int z = 0; z < 8; ++z) {
            float4 kv = kr[z];
            a0 = fmaf(qv[4 * z], kv.x, a0);
            a1 = fmaf(qv[4 * z + 1], kv.y, a1);
            a2 = fmaf(qv[4 * z + 2], kv.z, a2);
            a3 = fmaf(qv[4 * z + 3], kv.w, a3);
        }
        float s = ((a0 + a1) + (a2 + a3)) * scale;
        sc[l] = s;
        lmax = fmaxf(lmax, s);
    }
#pragma unroll
    for (int off = 32; off > 0; off >>= 1)
        lmax = fmaxf(lmax, __shfl_down(lmax, off, 64));
    if ((t & 63) == 0) red[t >> 6] = lmax;
    __syncthreads();
    const float bmax = fmaxf(fmaxf(red[0], red[1]), fmaxf(red[2], red[3]));

    float lsum = 0.f;
#pragma unroll
    for (int jj = 0; jj < 8; ++jj) {
        int l = t + 256 * jj;
        float e = __expf(sc[l] - bmax);
        sc[l] = e;
        lsum += e;
    }
#pragma unroll
    for (int off = 32; off > 0; off >>= 1)
        lsum += __shfl_down(lsum, off, 64);
    if ((t & 63) == 0) red[8 + (t >> 6)] = lsum;
    __syncthreads();
    const float bsum = (red[8] + red[9]) + (red[10] + red[11]);

    const int d = t & 31, g = t >> 5;
    const float* vbase = vp + (size_t)b * LD_ + h * DH_ + d;
    float acc = 0.f;
    for (int l = g; l < 2048; l += 8)
        acc = fmaf(sc[l], vbase[(size_t)l * D_], acc);
    outp[t] = acc;
    __syncthreads();
    if (t < 32) {
        float s = 0.f;
#pragma unroll
        for (int g2 = 0; g2 < 8; ++g2) s += outp[g2 * 32 + t];
        attnOut[((size_t)b * 40 + j) * 256 + h * 32 + t] = s / bsum;
    }
}

// ---------------------------------------------------------------------------
extern "C" void kernel_launch(void* const* d_in, const int* in_sizes, int n_in,
                              void* d_out, int out_size, void* d_ws, size_t ws_size,
                              hipStream_t stream) {
    const float* q  = (const float*)d_in[0];
    const float* k  = (const float*)d_in[1];
    const float* v  = (const float*)d_in[2];
    const float* Wq = (const float*)d_in[3];
    const float* bq = (const float*)d_in[4];
    const float* Wk = (const float*)d_in[5];
    const float* bk = (const float*)d_in[6];
    const float* Wv = (const float*)d_in[7];
    const float* bv = (const float*)d_in[8];
    const float* Wc = (const float*)d_in[9];
    const float* bc = (const float*)d_in[10];
    const int* idx  = (const int*)d_in[11];
    float* out = (float*)d_out;

    char* w = (char*)d_ws;
    float*          qp      = (float*)(w);                       // 8 MB
    float*          kp      = (float*)(w + (8u << 20));          // 8 MB
    float*          vp      = (float*)(w + (16u << 20));         // 8 MB
    unsigned short* Khi     = (unsigned short*)(w + (24u << 20)); // 4 MB
    unsigned short* Klo     = (unsigned short*)(w + (28u << 20)); // 4 MB
    float*          Mmax    = (float*)(w + (32u << 20));                     // 256 KB
    float*          Mv      = (float*)(w + (32u << 20) + (256u << 10));     // 256 KB
    float*          Qmean   = (float*)(w + (32u << 20) + (512u << 10));     // 256 KB
    float*          Ssum    = (float*)(w + (32u << 20) + (768u << 10));     // 4 KB
    int*            candIdx = (int*)  (w + (32u << 20) + (772u << 10));     // 8 KB
    float*          refPart = (float*)(w + (32u << 20) + (780u << 10));     // 32 KB
    int*            topIdx  = (int*)  (w + (32u << 20) + (812u << 10));     // 5 KB
    float*          attnOut = (float*)(w + (32u << 20) + (820u << 10));     // 160 KB

    const int Mrows = B_ * L_;  // 8192
    dim3 gProj((Mrows + 63) / 64, 4);
    hipLaunchKernelGGL(gemm_xwT, gProj, dim3(256), 0, stream, q, Wq, bq, qp, Mrows);
    hipLaunchKernelGGL(gemm_xwT, gProj, dim3(256), 0, stream, k, Wk, bk, kp, Mrows);
    hipLaunchKernelGGL(gemm_xwT, gProj, dim3(256), 0, stream, v, Wv, bv, vp, Mrows);

    hipLaunchKernelGGL(ksum_kernel, dim3(32), dim3(256), 0, stream, kp, idx, Ssum);
    hipLaunchKernelGGL(kconv_kernel, dim3(256), dim3(256), 0, stream, kp, idx, Khi, Klo);
    hipLaunchKernelGGL(mpart_mfma, dim3(1024), dim3(256), 0, stream, qp, Khi, Klo, Mmax);
    hipLaunchKernelGGL(mcombine_kernel, dim3(256), dim3(256), 0, stream, Mmax, qp, Ssum, Mv, Qmean);
    hipLaunchKernelGGL(topk64_kernel, dim3(32), dim3(256), 0, stream, Mv, candIdx);
    hipLaunchKernelGGL(refine_kernel, dim3(128), dim3(256), 0, stream, qp, kp, idx, candIdx, refPart);
    hipLaunchKernelGGL(select40_kernel, dim3(32), dim3(64), 0, stream, candIdx, refPart, Qmean, topIdx);
    hipLaunchKernelGGL(attn_kernel, dim3(NH_ * U_), dim3(256), 0, stream, qp, kp, vp, topIdx, attnOut);

    dim3 gOut((B_ * U_ + 63) / 64, 4);  // M = 160
    hipLaunchKernelGGL(gemm_xwT, gOut, dim3(256), 0, stream, attnOut, Wc, bc, out, B_ * U_);
}

// Round 3
// 462.125 us; speedup vs baseline: 1.3951x; 1.2477x over previous
//
#include <hip/hip_runtime.h>
#include <math.h>

// Problem constants
#define B_ 4
#define L_ 2048
#define D_ 256
#define H_ 8
#define DH_ 32
#define NH_ 32           // B*H
#define U_ 40
#define LD_ 524288       // L_*D_ floats per batch

typedef __attribute__((ext_vector_type(8))) short short8;
typedef __attribute__((ext_vector_type(4))) float floatx4;

static __device__ __forceinline__ unsigned long long ullmin_(unsigned long long a, unsigned long long b) {
    return a < b ? a : b;
}
static __device__ __forceinline__ unsigned short f2bf_rne(float x) {
    unsigned u = __float_as_uint(x);
    unsigned r = u + 0x7FFFu + ((u >> 16) & 1u);
    return (unsigned short)(r >> 16);
}
static __device__ __forceinline__ float bf2f(unsigned short h) {
    return __uint_as_float(((unsigned)h) << 16);
}

// ---------------------------------------------------------------------------
// Generic Y[r,c] = sum_k X[r,k] * W[c,k] + bias[c];  N=K=256 fixed, M variable.
// ---------------------------------------------------------------------------
__global__ __launch_bounds__(256) void gemm_xwT(const float* __restrict__ X,
                                                const float* __restrict__ W,
                                                const float* __restrict__ bias,
                                                float* __restrict__ Y, int M) {
    __shared__ float As[32 * 68];
    __shared__ float Bs[32 * 68];
    const int tid = threadIdx.x;
    const int tx = tid & 15, ty = tid >> 4;
    const int rowBase = blockIdx.x * 64;
    const int colBase = blockIdx.y * 64;

    float acc[4][4] = {};

    for (int kt = 0; kt < 256; kt += 32) {
#pragma unroll
        for (int jj = 0; jj < 8; ++jj) {
            int e = tid + 256 * jj;
            int r = e >> 5, kk = e & 31;
            int gr = rowBase + r;
            float xv = (gr < M) ? X[(size_t)gr * 256 + kt + kk] : 0.f;
            As[kk * 68 + r] = xv;
            int gc = colBase + r;  // always < 256
            Bs[kk * 68 + r] = W[(size_t)gc * 256 + kt + kk];
        }
        __syncthreads();
#pragma unroll
        for (int kk = 0; kk < 32; ++kk) {
            const float4 a4 = *(const float4*)&As[kk * 68 + ty * 4];
            const float4 b4 = *(const float4*)&Bs[kk * 68 + tx * 4];
            float av[4] = {a4.x, a4.y, a4.z, a4.w};
            float bv[4] = {b4.x, b4.y, b4.z, b4.w};
#pragma unroll
            for (int i = 0; i < 4; ++i)
#pragma unroll
                for (int j = 0; j < 4; ++j)
                    acc[i][j] = fmaf(av[i], bv[j], acc[i][j]);
        }
        __syncthreads();
    }

#pragma unroll
    for (int i = 0; i < 4; ++i) {
        int gr = rowBase + ty * 4 + i;
        if (gr >= M) continue;
#pragma unroll
        for (int j = 0; j < 4; ++j) {
            int gc = colBase + tx * 4 + j;
            Y[(size_t)gr * 256 + gc] = acc[i][j] + bias[gc];
        }
    }
}

// ---------------------------------------------------------------------------
// Ssum[i][d] = sum_u kp[b, idx[u], h*32+d]
// ---------------------------------------------------------------------------
__global__ __launch_bounds__(256) void ksum_kernel(const float* __restrict__ kp,
                                                   const int* __restrict__ idx,
                                                   float* __restrict__ Ssum) {
    const int i = blockIdx.x;
    const int b = i >> 3, h = i & 7;
    const int t = threadIdx.x;
    const int d = t & 31, g = t >> 5;
    const float* base = kp + (size_t)b * LD_ + h * DH_ + d;
    float acc = 0.f;
    for (int u = g; u < L_; u += 8) acc += base[(size_t)idx[u] * D_];
    __shared__ float part[256];
    part[t] = acc;
    __syncthreads();
    if (t < 32) {
        float s = 0.f;
#pragma unroll
        for (int g2 = 0; g2 < 8; ++g2) s += part[g2 * 32 + t];
        Ssum[i * 32 + t] = s;
    }
}

// ---------------------------------------------------------------------------
// Gather K_sample rows per head and split fp32 -> bf16 hi/lo.
// ---------------------------------------------------------------------------
__global__ __launch_bounds__(256) void kconv_kernel(const float* __restrict__ kp,
                                                    const int* __restrict__ idx,
                                                    unsigned short* __restrict__ Khi,
                                                    unsigned short* __restrict__ Klo) {
    const int blk = blockIdx.x;  // 256: i*8 + uc
    const int i = blk >> 3, uc = blk & 7;
    const int b = i >> 3, h = i & 7;
    const int t = threadIdx.x;
    const int dq = (t & 7) * 4;
    const int ur = t >> 3;  // 0..31
#pragma unroll
    for (int p = 0; p < 8; ++p) {
        int u = uc * 256 + p * 32 + ur;
        const float4 x = *(const float4*)(kp + (size_t)b * LD_ + (size_t)idx[u] * D_ + h * DH_ + dq);
        float xs[4] = {x.x, x.y, x.z, x.w};
        unsigned short hv[4], lv[4];
#pragma unroll
        for (int j = 0; j < 4; ++j) {
            hv[j] = f2bf_rne(xs[j]);
            lv[j] = f2bf_rne(xs[j] - bf2f(hv[j]));
        }
        size_t o = ((size_t)i * 2048 + u) * 32 + dq;
        *(ushort4*)(Khi + o) = make_ushort4(hv[0], hv[1], hv[2], hv[3]);
        *(ushort4*)(Klo + o) = make_ushort4(lv[0], lv[1], lv[2], lv[3]);
    }
}

// ---------------------------------------------------------------------------
// Approx M-sweep on MFMA (split-bf16, 16x16x32, K=DH=32).
// ---------------------------------------------------------------------------
__global__ __launch_bounds__(256) void mpart_mfma(const float* __restrict__ qp,
                                                  const unsigned short* __restrict__ Khi,
                                                  const unsigned short* __restrict__ Klo,
                                                  float* __restrict__ Mmax) {
    const int blk = blockIdx.x;
    const int i = blk >> 5;
    const int lg = blk & 31;
    const int t = threadIdx.x;
    const int w = t >> 6;
    const int lane = t & 63;
    const int lq = lane & 15;
    const int quad = lane >> 4;

    short8 Ah[4], Al[4];
#pragma unroll
    for (int lt = 0; lt < 4; ++lt) {
        const int l = lg * 64 + lt * 16 + lq;
        const float* qrow = qp + ((size_t)i * 2048 + l) * 32 + quad * 8;
        float4 x0 = *(const float4*)(qrow);
        float4 x1 = *(const float4*)(qrow + 4);
        float xs[8] = {x0.x, x0.y, x0.z, x0.w, x1.x, x1.y, x1.z, x1.w};
#pragma unroll
        for (int j = 0; j < 8; ++j) {
            unsigned short h = f2bf_rne(xs[j]);
            unsigned short lo = f2bf_rne(xs[j] - bf2f(h));
            Ah[lt][j] = (short)h;
            Al[lt][j] = (short)lo;
        }
    }

    floatx4 rmax[4];
#pragma unroll
    for (int lt = 0; lt < 4; ++lt)
        rmax[lt] = (floatx4){-INFINITY, -INFINITY, -INFINITY, -INFINITY};

    const size_t kfrag = ((size_t)i * 2048 + w * 512 + lq) * 32 + quad * 8;
    const unsigned short* ph = Khi + kfrag;
    const unsigned short* pl = Klo + kfrag;
#pragma unroll 2
    for (int s = 0; s < 32; ++s) {
        short8 Bh = *(const short8*)(ph + (size_t)s * 512);
        short8 Bl = *(const short8*)(pl + (size_t)s * 512);
#pragma unroll
        for (int lt = 0; lt < 4; ++lt) {
            floatx4 acc = (floatx4){0.f, 0.f, 0.f, 0.f};
            acc = __builtin_amdgcn_mfma_f32_16x16x32_bf16(Al[lt], Bh, acc, 0, 0, 0);
            acc = __builtin_amdgcn_mfma_f32_16x16x32_bf16(Ah[lt], Bl, acc, 0, 0, 0);
            acc = __builtin_amdgcn_mfma_f32_16x16x32_bf16(Ah[lt], Bh, acc, 0, 0, 0);
#pragma unroll
            for (int r = 0; r < 4; ++r) rmax[lt][r] = fmaxf(rmax[lt][r], acc[r]);
        }
    }

#pragma unroll
    for (int lt = 0; lt < 4; ++lt)
#pragma unroll
        for (int r = 0; r < 4; ++r) {
            float v = rmax[lt][r];
#pragma unroll
            for (int off = 1; off < 16; off <<= 1)
                v = fmaxf(v, __shfl_xor(v, off, 64));
            rmax[lt][r] = v;
        }
    __shared__ float red[4][64];
    if (lq == 0) {
#pragma unroll
        for (int lt = 0; lt < 4; ++lt)
#pragma unroll
            for (int r = 0; r < 4; ++r)
                red[w][lt * 16 + quad * 4 + r] = rmax[lt][r];
    }
    __syncthreads();
    if (t < 64) {
        float m = fmaxf(fmaxf(red[0][t], red[1][t]), fmaxf(red[2][t], red[3][t]));
        Mmax[(size_t)i * 2048 + lg * 64 + t] = m;
    }
}

// ---------------------------------------------------------------------------
// Mv[i,l] = Mmax[i,l] - qmean;  Qmean[i,l] = (q·Ssum)/L
// ---------------------------------------------------------------------------
__global__ __launch_bounds__(256) void mcombine_kernel(const float* __restrict__ Mmax,
                                                       const float* __restrict__ qp,
                                                       const float* __restrict__ Ssum,
                                                       float* __restrict__ Mv,
                                                       float* __restrict__ Qmean) {
    const int blk = blockIdx.x;  // 256 blocks
    const int i = blk >> 3;
    const int lt = blk & 7;
    const int t = threadIdx.x;
    const int l = lt * 256 + t;
    const float4* q = (const float4*)(qp + (size_t)i * 65536 + (size_t)l * 32);
    const float4* s = (const float4*)(Ssum + i * 32);
    float qs = 0.f;
#pragma unroll
    for (int z = 0; z < 8; ++z) {
        float4 a = q[z];
        float4 c = s[z];
        qs = fmaf(a.x, c.x, qs);
        qs = fmaf(a.y, c.y, qs);
        qs = fmaf(a.z, c.z, qs);
        qs = fmaf(a.w, c.w, qs);
    }
    float qm = qs * (1.0f / 2048.0f);
    Qmean[(size_t)i * 2048 + l] = qm;
    Mv[(size_t)i * 2048 + l] = Mmax[(size_t)i * 2048 + l] - qm;
}

// ---------------------------------------------------------------------------
// Bottom-64 candidates per i from approx Mv (ascending, index tie-break).
// ---------------------------------------------------------------------------
__global__ __launch_bounds__(256) void topk64_kernel(const float* __restrict__ Mv,
                                                     int* __restrict__ candIdx) {
    const int i = blockIdx.x;
    const int t = threadIdx.x;
    __shared__ unsigned long long keys[2048];
    __shared__ unsigned long long wred[4];
#pragma unroll
    for (int j = 0; j < 8; ++j) {
        int l = t + 256 * j;
        unsigned u32 = __float_as_uint(Mv[(size_t)i * 2048 + l]);
        u32 = (u32 & 0x80000000u) ? ~u32 : (u32 | 0x80000000u);
        keys[l] = ((unsigned long long)u32 << 32) | (unsigned)l;
    }
    __syncthreads();
    for (int it = 0; it < 64; ++it) {
        unsigned long long best = ~0ULL;
#pragma unroll
        for (int j = 0; j < 8; ++j) best = ullmin_(best, keys[t + 256 * j]);
#pragma unroll
        for (int off = 32; off > 0; off >>= 1)
            best = ullmin_(best, __shfl_down(best, off, 64));
        if ((t & 63) == 0) wred[t >> 6] = best;
        __syncthreads();
        unsigned long long m = ullmin_(ullmin_(wred[0], wred[1]), ullmin_(wred[2], wred[3]));
        int l = (int)(m & 0xffffffffu);
        if (t == 0) {
            candIdx[i * 64 + it] = l;
            keys[l] = ~0ULL;
        }
        __syncthreads();
    }
}

// ---------------------------------------------------------------------------
// Exact fp32 re-computation of max_u q·K_sample for the 64 candidates.
// ---------------------------------------------------------------------------
__global__ __launch_bounds__(256) void refine_kernel(const float* __restrict__ qp,
                                                     const float* __restrict__ kp,
                                                     const int* __restrict__ idx,
                                                     const int* __restrict__ candIdx,
                                                     float* __restrict__ refPart) {
    const int blk = blockIdx.x;  // 128
    const int i = blk >> 2, c = blk & 3;
    const int b = i >> 3, h = i & 7;
    const int t = threadIdx.x;
    __shared__ float qc[64][40];
    __shared__ float Ks[128][40];

    {
        const int cand = t >> 2, dp = (t & 3) * 8;
        const int l = candIdx[i * 64 + cand];
        const float* src = qp + ((size_t)i * 2048 + l) * 32 + dp;
        *(float4*)&qc[cand][dp] = *(const float4*)(src);
        *(float4*)&qc[cand][dp + 4] = *(const float4*)(src + 4);
    }
    __syncthreads();

    const int cand = t >> 2, usub = t & 3;
    float qv[32];
#pragma unroll
    for (int z = 0; z < 8; ++z) {
        float4 a = *(const float4*)&qc[cand][z * 4];
        qv[4 * z] = a.x; qv[4 * z + 1] = a.y; qv[4 * z + 2] = a.z; qv[4 * z + 3] = a.w;
    }

    float m = -INFINITY;
    for (int s = 0; s < 4; ++s) {
        {
            const int r = t >> 1, half = t & 1;
            const int u = c * 512 + s * 128 + r;
            const float* krow = kp + (size_t)b * LD_ + (size_t)idx[u] * D_ + h * DH_ + half * 16;
#pragma unroll
            for (int z = 0; z < 4; ++z)
                *(float4*)&Ks[r][half * 16 + z * 4] = *(const float4*)(krow + z * 4);
        }
        __syncthreads();
        for (int ur = usub; ur < 128; ur += 4) {
            float a0 = 0, a1 = 0, a2 = 0, a3 = 0;
#pragma unroll
            for (int z = 0; z < 8; ++z) {
                float4 kv = *(const float4*)&Ks[ur][z * 4];
                a0 = fmaf(qv[4 * z], kv.x, a0);
                a1 = fmaf(qv[4 * z + 1], kv.y, a1);
                a2 = fmaf(qv[4 * z + 2], kv.z, a2);
                a3 = fmaf(qv[4 * z + 3], kv.w, a3);
            }
            m = fmaxf(m, (a0 + a1) + (a2 + a3));
        }
        __syncthreads();
    }
#pragma unroll
    for (int off = 1; off < 4; off <<= 1)
        m = fmaxf(m, __shfl_xor(m, off, 64));
    if ((t & 3) == 0) refPart[((size_t)i * 4 + c) * 64 + cand] = m;
}

// ---------------------------------------------------------------------------
// Final exact top-40 from 64 candidates. One wave per i.
// ---------------------------------------------------------------------------
__global__ __launch_bounds__(64) void select40_kernel(const int* __restrict__ candIdx,
                                                      const float* __restrict__ refPart,
                                                      const float* __restrict__ Qmean,
                                                      int* __restrict__ topIdx) {
    const int i = blockIdx.x;
    const int t = threadIdx.x;
    const int l = candIdx[i * 64 + t];
    float m = -INFINITY;
#pragma unroll
    for (int c = 0; c < 4; ++c) m = fmaxf(m, refPart[((size_t)i * 4 + c) * 64 + t]);
    float Mex = m - Qmean[(size_t)i * 2048 + l];
    unsigned u32 = __float_as_uint(Mex);
    u32 = (u32 & 0x80000000u) ? ~u32 : (u32 | 0x80000000u);
    unsigned long long key = ((unsigned long long)u32 << 32) | (unsigned)l;
    for (int it = 0; it < 40; ++it) {
        unsigned long long k2 = key;
#pragma unroll
        for (int off = 1; off < 64; off <<= 1) k2 = ullmin_(k2, __shfl_xor(k2, off, 64));
        if (key == k2) {
            topIdx[i * 40 + it] = l;
            key = ~0ULL;
        }
    }
}

// ---------------------------------------------------------------------------
// Flash-style attention, split over L. Grid: 32 i x 8 chunks, 320 threads.
// All 40 queries of head i share the K/V chunk -> each kp/vp byte read once.
// Per chunk: scores (fp32), chunk softmax (m, sum), partial PV.
// ---------------------------------------------------------------------------
#define SCP 258   // sc row pad (floats): bank = (2j + l) % 32
#define VSP 36    // Vs row pad (floats)

__global__ __launch_bounds__(320) void attn_part(const float* __restrict__ qp,
                                                 const float* __restrict__ kp,
                                                 const float* __restrict__ vp,
                                                 const int* __restrict__ topIdx,
                                                 float* __restrict__ mPart,
                                                 float* __restrict__ sPart,
                                                 float* __restrict__ oPart) {
    const int blk = blockIdx.x;  // 256 = i*8 + c
    const int i = blk >> 3, c = blk & 7;
    const int b = i >> 3, h = i & 7;
    const int t = threadIdx.x;

    __shared__ float Qs[40][32];
    __shared__ float Vs[256][VSP];
    __shared__ float sc[40][SCP];
    __shared__ float mred[40], sred[40];

    // Load 40 Q rows (320 float4s, one per thread)
    {
        const int r = t >> 3, qq = t & 7;
        const int lq = topIdx[i * 40 + r];
        *(float4*)&Qs[r][qq * 4] = *(const float4*)(qp + ((size_t)i * 2048 + lq) * 32 + qq * 4);
    }
    // Load V chunk (2048 float4s)
    for (int e = t; e < 2048; e += 320) {
        const int r = e >> 3, qq = e & 7;
        *(float4*)&Vs[r][qq * 4] =
            *(const float4*)(vp + (size_t)b * LD_ + (size_t)(c * 256 + r) * 256 + h * 32 + qq * 4);
    }
    __syncthreads();

    const float scale = 0.17677669529663687f;  // 1/sqrt(32)

    // Phase 1: scores. Thread t<256 owns K row l = c*256+t (direct from global).
    if (t < 256) {
        const float* kr = kp + (size_t)b * LD_ + (size_t)(c * 256 + t) * 256 + h * 32;
        float kv[32];
#pragma unroll
        for (int z = 0; z < 8; ++z) {
            float4 x = *(const float4*)(kr + z * 4);
            kv[4 * z] = x.x; kv[4 * z + 1] = x.y; kv[4 * z + 2] = x.z; kv[4 * z + 3] = x.w;
        }
#pragma unroll 4
        for (int j = 0; j < 40; ++j) {
            float a0 = 0, a1 = 0, a2 = 0, a3 = 0;
#pragma unroll
            for (int z = 0; z < 8; ++z) {
                const float4 q4 = *(const float4*)&Qs[j][z * 4];
                a0 = fmaf(kv[4 * z], q4.x, a0);
                a1 = fmaf(kv[4 * z + 1], q4.y, a1);
                a2 = fmaf(kv[4 * z + 2], q4.z, a2);
                a3 = fmaf(kv[4 * z + 3], q4.w, a3);
            }
            sc[j][t] = ((a0 + a1) + (a2 + a3)) * scale;
        }
    }
    __syncthreads();

    // Phase 2+3: per-row (j) chunk softmax. 5 waves x 8 rows.
    {
        const int w = t >> 6, lane = t & 63;
#pragma unroll
        for (int r = 0; r < 8; ++r) {
            const int j = w * 8 + r;
            float x0 = sc[j][lane], x1 = sc[j][lane + 64];
            float x2 = sc[j][lane + 128], x3 = sc[j][lane + 192];
            float m = fmaxf(fmaxf(x0, x1), fmaxf(x2, x3));
#pragma unroll
            for (int off = 1; off < 64; off <<= 1) m = fmaxf(m, __shfl_xor(m, off, 64));
            const float e0 = __expf(x0 - m), e1 = __expf(x1 - m);
            const float e2 = __expf(x2 - m), e3 = __expf(x3 - m);
            sc[j][lane] = e0; sc[j][lane + 64] = e1;
            sc[j][lane + 128] = e2; sc[j][lane + 192] = e3;
            float s = (e0 + e1) + (e2 + e3);
#pragma unroll
            for (int off = 1; off < 64; off <<= 1) s += __shfl_xor(s, off, 64);
            if (lane == 0) { mred[j] = m; sred[j] = s; }
        }
    }
    __syncthreads();

    // Phase 4: partial PV. Thread owns (j = t>>3, d4 = (t&7)*4).
    {
        const int j = t >> 3, qq = t & 7;
        float4 acc = make_float4(0.f, 0.f, 0.f, 0.f);
        for (int l = 0; l < 256; ++l) {
            const float p = sc[j][l];
            const float4 v4 = *(const float4*)&Vs[l][qq * 4];
            acc.x = fmaf(p, v4.x, acc.x);
            acc.y = fmaf(p, v4.y, acc.y);
            acc.z = fmaf(p, v4.z, acc.z);
            acc.w = fmaf(p, v4.w, acc.w);
        }
        const size_t o = (size_t)(i * 8 + c) * 40 + j;
        *(float4*)&oPart[o * 32 + qq * 4] = acc;
        if (qq == 0) { mPart[o] = mred[j]; sPart[o] = sred[j]; }
    }
}

// ---------------------------------------------------------------------------
// Merge the 8 chunk partials per (i,j) with softmax rescaling.
// attnOut[b*40+j][h*32+d]
// ---------------------------------------------------------------------------
__global__ __launch_bounds__(256) void attn_combine(const float* __restrict__ mPart,
                                                    const float* __restrict__ sPart,
                                                    const float* __restrict__ oPart,
                                                    float* __restrict__ attnOut) {
    const int i = blockIdx.x;
    const int b = i >> 3, h = i & 7;
    const int t = threadIdx.x;
    for (int e = t; e < 1280; e += 256) {
        const int j = e >> 5, d = e & 31;
        float mv[8];
        float M = -INFINITY;
#pragma unroll
        for (int c = 0; c < 8; ++c) {
            mv[c] = mPart[(size_t)(i * 8 + c) * 40 + j];
            M = fmaxf(M, mv[c]);
        }
        float S = 0.f, O = 0.f;
#pragma unroll
        for (int c = 0; c < 8; ++c) {
            const float sc_ = __expf(mv[c] - M);
            const size_t o = (size_t)(i * 8 + c) * 40 + j;
            S = fmaf(sPart[o], sc_, S);
            O = fmaf(oPart[o * 32 + d], sc_, O);
        }
        attnOut[((size_t)b * 40 + j) * 256 + h * 32 + d] = O / S;
    }
}

// ---------------------------------------------------------------------------
extern "C" void kernel_launch(void* const* d_in, const int* in_sizes, int n_in,
                              void* d_out, int out_size, void* d_ws, size_t ws_size,
                              hipStream_t stream) {
    const float* q  = (const float*)d_in[0];
    const float* k  = (const float*)d_in[1];
    const float* v  = (const float*)d_in[2];
    const float* Wq = (const float*)d_in[3];
    const float* bq = (const float*)d_in[4];
    const float* Wk = (const float*)d_in[5];
    const float* bk = (const float*)d_in[6];
    const float* Wv = (const float*)d_in[7];
    const float* bv = (const float*)d_in[8];
    const float* Wc = (const float*)d_in[9];
    const float* bc = (const float*)d_in[10];
    const int* idx  = (const int*)d_in[11];
    float* out = (float*)d_out;

    char* w = (char*)d_ws;
    float*          qp      = (float*)(w);                        // 8 MB
    float*          kp      = (float*)(w + (8u << 20));           // 8 MB
    float*          vp      = (float*)(w + (16u << 20));          // 8 MB
    unsigned short* Khi     = (unsigned short*)(w + (24u << 20)); // 4 MB (dead after mpart_mfma)
    unsigned short* Klo     = (unsigned short*)(w + (28u << 20)); // 4 MB
    float*          Mmax    = (float*)(w + (32u << 20));                    // 256 KB
    float*          Mv      = (float*)(w + (32u << 20) + (256u << 10));     // 256 KB
    float*          Qmean   = (float*)(w + (32u << 20) + (512u << 10));     // 256 KB
    float*          Ssum    = (float*)(w + (32u << 20) + (768u << 10));     // 4 KB
    int*            candIdx = (int*)  (w + (32u << 20) + (772u << 10));     // 8 KB
    float*          refPart = (float*)(w + (32u << 20) + (780u << 10));     // 32 KB
    int*            topIdx  = (int*)  (w + (32u << 20) + (812u << 10));     // 5 KB
    float*          attnOut = (float*)(w + (32u << 20) + (820u << 10));     // 160 KB
    // attn partials overlay the Khi region (free once mpart_mfma is done):
    float*          mPart   = (float*)(w + (24u << 20));                    // 40 KB
    float*          sPart   = (float*)(w + (24u << 20) + (64u << 10));      // 40 KB
    float*          oPart   = (float*)(w + (24u << 20) + (128u << 10));     // 1.25 MB

    const int Mrows = B_ * L_;  // 8192
    dim3 gProj((Mrows + 63) / 64, 4);
    hipLaunchKernelGGL(gemm_xwT, gProj, dim3(256), 0, stream, q, Wq, bq, qp, Mrows);
    hipLaunchKernelGGL(gemm_xwT, gProj, dim3(256), 0, stream, k, Wk, bk, kp, Mrows);
    hipLaunchKernelGGL(gemm_xwT, gProj, dim3(256), 0, stream, v, Wv, bv, vp, Mrows);

    hipLaunchKernelGGL(ksum_kernel, dim3(32), dim3(256), 0, stream, kp, idx, Ssum);
    hipLaunchKernelGGL(kconv_kernel, dim3(256), dim3(256), 0, stream, kp, idx, Khi, Klo);
    hipLaunchKernelGGL(mpart_mfma, dim3(1024), dim3(256), 0, stream, qp, Khi, Klo, Mmax);
    hipLaunchKernelGGL(mcombine_kernel, dim3(256), dim3(256), 0, stream, Mmax, qp, Ssum, Mv, Qmean);
    hipLaunchKernelGGL(topk64_kernel, dim3(32), dim3(256), 0, stream, Mv, candIdx);
    hipLaunchKernelGGL(refine_kernel, dim3(128), dim3(256), 0, stream, qp, kp, idx, candIdx, refPart);
    hipLaunchKernelGGL(select40_kernel, dim3(32), dim3(64), 0, stream, candIdx, refPart, Qmean, topIdx);
    hipLaunchKernelGGL(attn_part, dim3(256), dim3(320), 0, stream, qp, kp, vp, topIdx, mPart, sPart, oPart);
    hipLaunchKernelGGL(attn_combine, dim3(32), dim3(256), 0, stream, mPart, sPart, oPart, attnOut);

    dim3 gOut((B_ * U_ + 63) / 64, 4);  // M = 160
    hipLaunchKernelGGL(gemm_xwT, gOut, dim3(256), 0, stream, attnOut, Wc, bc, out, B_ * U_);
}

// Round 4
// 352.193 us; speedup vs baseline: 1.8305x; 1.3121x over previous
//
#include <hip/hip_runtime.h>
#include <math.h>

// Problem constants
#define B_ 4
#define L_ 2048
#define D_ 256
#define H_ 8
#define DH_ 32
#define NH_ 32           // B*H
#define U_ 40
#define LD_ 524288       // L_*D_ floats per batch

typedef __attribute__((ext_vector_type(8))) short short8;
typedef __attribute__((ext_vector_type(4))) float floatx4;

static __device__ __forceinline__ unsigned long long ullmin_(unsigned long long a, unsigned long long b) {
    return a < b ? a : b;
}
static __device__ __forceinline__ unsigned short f2bf_rne(float x) {
    unsigned u = __float_as_uint(x);
    unsigned r = u + 0x7FFFu + ((u >> 16) & 1u);
    return (unsigned short)(r >> 16);
}
static __device__ __forceinline__ float bf2f(unsigned short h) {
    return __uint_as_float(((unsigned)h) << 16);
}

// ---------------------------------------------------------------------------
// Generic Y[r,c] = sum_k X[r,k] * W[c,k] + bias[c];  N=K=256 fixed, M variable.
// ---------------------------------------------------------------------------
__global__ __launch_bounds__(256) void gemm_xwT(const float* __restrict__ X,
                                                const float* __restrict__ W,
                                                const float* __restrict__ bias,
                                                float* __restrict__ Y, int M) {
    __shared__ float As[32 * 68];
    __shared__ float Bs[32 * 68];
    const int tid = threadIdx.x;
    const int tx = tid & 15, ty = tid >> 4;
    const int rowBase = blockIdx.x * 64;
    const int colBase = blockIdx.y * 64;

    float acc[4][4] = {};

    for (int kt = 0; kt < 256; kt += 32) {
#pragma unroll
        for (int jj = 0; jj < 8; ++jj) {
            int e = tid + 256 * jj;
            int r = e >> 5, kk = e & 31;
            int gr = rowBase + r;
            float xv = (gr < M) ? X[(size_t)gr * 256 + kt + kk] : 0.f;
            As[kk * 68 + r] = xv;
            int gc = colBase + r;  // always < 256
            Bs[kk * 68 + r] = W[(size_t)gc * 256 + kt + kk];
        }
        __syncthreads();
#pragma unroll
        for (int kk = 0; kk < 32; ++kk) {
            const float4 a4 = *(const float4*)&As[kk * 68 + ty * 4];
            const float4 b4 = *(const float4*)&Bs[kk * 68 + tx * 4];
            float av[4] = {a4.x, a4.y, a4.z, a4.w};
            float bv[4] = {b4.x, b4.y, b4.z, b4.w};
#pragma unroll
            for (int i = 0; i < 4; ++i)
#pragma unroll
                for (int j = 0; j < 4; ++j)
                    acc[i][j] = fmaf(av[i], bv[j], acc[i][j]);
        }
        __syncthreads();
    }

#pragma unroll
    for (int i = 0; i < 4; ++i) {
        int gr = rowBase + ty * 4 + i;
        if (gr >= M) continue;
#pragma unroll
        for (int j = 0; j < 4; ++j) {
            int gc = colBase + tx * 4 + j;
            Y[(size_t)gr * 256 + gc] = acc[i][j] + bias[gc];
        }
    }
}

// ---------------------------------------------------------------------------
// Stage 1: Kpart[(b*64+c)][d] = sum_{u in chunk c (32 rows)} kp[b, idx[u], d]
// Grid: 256 blocks (b*64+c), 256 threads (d). Coalesced row reads.
// ---------------------------------------------------------------------------
__global__ __launch_bounds__(256) void ksum_part(const float* __restrict__ kp,
                                                 const int* __restrict__ idx,
                                                 float* __restrict__ Kpart) {
    const int blk = blockIdx.x;
    const int b = blk >> 6, c = blk & 63;
    const int t = threadIdx.x;
    const float* base = kp + (size_t)b * LD_ + t;
    float acc = 0.f;
#pragma unroll 4
    for (int r = 0; r < 32; ++r)
        acc += base[(size_t)idx[c * 32 + r] * D_];
    Kpart[(size_t)blk * D_ + t] = acc;
}

// ---------------------------------------------------------------------------
// Stage 2: Ssum[b*8+h][d] = sum_{c=0..63} Kpart[b*64+c][h*32+d]  (fixed order)
// ---------------------------------------------------------------------------
__global__ __launch_bounds__(256) void ksum_final(const float* __restrict__ Kpart,
                                                  float* __restrict__ Ssum) {
    const int b = blockIdx.x;
    const int t = threadIdx.x;
    const float* p = Kpart + (size_t)b * 64 * D_ + t;
    float acc = 0.f;
#pragma unroll 8
    for (int c = 0; c < 64; ++c) acc += p[(size_t)c * D_];
    const int h = t >> 5, d = t & 31;
    Ssum[(b * 8 + h) * 32 + d] = acc;
}

// ---------------------------------------------------------------------------
// Gather K_sample rows per head and split fp32 -> bf16 hi/lo.
// ---------------------------------------------------------------------------
__global__ __launch_bounds__(256) void kconv_kernel(const float* __restrict__ kp,
                                                    const int* __restrict__ idx,
                                                    unsigned short* __restrict__ Khi,
                                                    unsigned short* __restrict__ Klo) {
    const int blk = blockIdx.x;  // 256: i*8 + uc
    const int i = blk >> 3, uc = blk & 7;
    const int b = i >> 3, h = i & 7;
    const int t = threadIdx.x;
    const int dq = (t & 7) * 4;
    const int ur = t >> 3;  // 0..31
#pragma unroll
    for (int p = 0; p < 8; ++p) {
        int u = uc * 256 + p * 32 + ur;
        const float4 x = *(const float4*)(kp + (size_t)b * LD_ + (size_t)idx[u] * D_ + h * DH_ + dq);
        float xs[4] = {x.x, x.y, x.z, x.w};
        unsigned short hv[4], lv[4];
#pragma unroll
        for (int j = 0; j < 4; ++j) {
            hv[j] = f2bf_rne(xs[j]);
            lv[j] = f2bf_rne(xs[j] - bf2f(hv[j]));
        }
        size_t o = ((size_t)i * 2048 + u) * 32 + dq;
        *(ushort4*)(Khi + o) = make_ushort4(hv[0], hv[1], hv[2], hv[3]);
        *(ushort4*)(Klo + o) = make_ushort4(lv[0], lv[1], lv[2], lv[3]);
    }
}

// ---------------------------------------------------------------------------
// Approx M-sweep on MFMA (split-bf16, 16x16x32, K=DH=32).
// ---------------------------------------------------------------------------
__global__ __launch_bounds__(256) void mpart_mfma(const float* __restrict__ qp,
                                                  const unsigned short* __restrict__ Khi,
                                                  const unsigned short* __restrict__ Klo,
                                                  float* __restrict__ Mmax) {
    const int blk = blockIdx.x;
    const int i = blk >> 5;
    const int lg = blk & 31;
    const int t = threadIdx.x;
    const int w = t >> 6;
    const int lane = t & 63;
    const int lq = lane & 15;
    const int quad = lane >> 4;

    short8 Ah[4], Al[4];
#pragma unroll
    for (int lt = 0; lt < 4; ++lt) {
        const int l = lg * 64 + lt * 16 + lq;
        const float* qrow = qp + ((size_t)i * 2048 + l) * 32 + quad * 8;
        float4 x0 = *(const float4*)(qrow);
        float4 x1 = *(const float4*)(qrow + 4);
        float xs[8] = {x0.x, x0.y, x0.z, x0.w, x1.x, x1.y, x1.z, x1.w};
#pragma unroll
        for (int j = 0; j < 8; ++j) {
            unsigned short h = f2bf_rne(xs[j]);
            unsigned short lo = f2bf_rne(xs[j] - bf2f(h));
            Ah[lt][j] = (short)h;
            Al[lt][j] = (short)lo;
        }
    }

    floatx4 rmax[4];
#pragma unroll
    for (int lt = 0; lt < 4; ++lt)
        rmax[lt] = (floatx4){-INFINITY, -INFINITY, -INFINITY, -INFINITY};

    const size_t kfrag = ((size_t)i * 2048 + w * 512 + lq) * 32 + quad * 8;
    const unsigned short* ph = Khi + kfrag;
    const unsigned short* pl = Klo + kfrag;
#pragma unroll 2
    for (int s = 0; s < 32; ++s) {
        short8 Bh = *(const short8*)(ph + (size_t)s * 512);
        short8 Bl = *(const short8*)(pl + (size_t)s * 512);
#pragma unroll
        for (int lt = 0; lt < 4; ++lt) {
            floatx4 acc = (floatx4){0.f, 0.f, 0.f, 0.f};
            acc = __builtin_amdgcn_mfma_f32_16x16x32_bf16(Al[lt], Bh, acc, 0, 0, 0);
            acc = __builtin_amdgcn_mfma_f32_16x16x32_bf16(Ah[lt], Bl, acc, 0, 0, 0);
            acc = __builtin_amdgcn_mfma_f32_16x16x32_bf16(Ah[lt], Bh, acc, 0, 0, 0);
#pragma unroll
            for (int r = 0; r < 4; ++r) rmax[lt][r] = fmaxf(rmax[lt][r], acc[r]);
        }
    }

#pragma unroll
    for (int lt = 0; lt < 4; ++lt)
#pragma unroll
        for (int r = 0; r < 4; ++r) {
            float v = rmax[lt][r];
#pragma unroll
            for (int off = 1; off < 16; off <<= 1)
                v = fmaxf(v, __shfl_xor(v, off, 64));
            rmax[lt][r] = v;
        }
    __shared__ float red[4][64];
    if (lq == 0) {
#pragma unroll
        for (int lt = 0; lt < 4; ++lt)
#pragma unroll
            for (int r = 0; r < 4; ++r)
                red[w][lt * 16 + quad * 4 + r] = rmax[lt][r];
    }
    __syncthreads();
    if (t < 64) {
        float m = fmaxf(fmaxf(red[0][t], red[1][t]), fmaxf(red[2][t], red[3][t]));
        Mmax[(size_t)i * 2048 + lg * 64 + t] = m;
    }
}

// ---------------------------------------------------------------------------
// Mv[i,l] = Mmax[i,l] - qmean;  Qmean[i,l] = (q·Ssum)/L
// ---------------------------------------------------------------------------
__global__ __launch_bounds__(256) void mcombine_kernel(const float* __restrict__ Mmax,
                                                       const float* __restrict__ qp,
                                                       const float* __restrict__ Ssum,
                                                       float* __restrict__ Mv,
                                                       float* __restrict__ Qmean) {
    const int blk = blockIdx.x;  // 256 blocks
    const int i = blk >> 3;
    const int lt = blk & 7;
    const int t = threadIdx.x;
    const int l = lt * 256 + t;
    const float4* q = (const float4*)(qp + (size_t)i * 65536 + (size_t)l * 32);
    const float4* s = (const float4*)(Ssum + i * 32);
    float qs = 0.f;
#pragma unroll
    for (int z = 0; z < 8; ++z) {
        float4 a = q[z];
        float4 c = s[z];
        qs = fmaf(a.x, c.x, qs);
        qs = fmaf(a.y, c.y, qs);
        qs = fmaf(a.z, c.z, qs);
        qs = fmaf(a.w, c.w, qs);
    }
    float qm = qs * (1.0f / 2048.0f);
    Qmean[(size_t)i * 2048 + l] = qm;
    Mv[(size_t)i * 2048 + l] = Mmax[(size_t)i * 2048 + l] - qm;
}

// ---------------------------------------------------------------------------
// Bottom-64 candidates per i from approx Mv (ascending, index tie-break).
// ---------------------------------------------------------------------------
__global__ __launch_bounds__(256) void topk64_kernel(const float* __restrict__ Mv,
                                                     int* __restrict__ candIdx) {
    const int i = blockIdx.x;
    const int t = threadIdx.x;
    __shared__ unsigned long long keys[2048];
    __shared__ unsigned long long wred[4];
#pragma unroll
    for (int j = 0; j < 8; ++j) {
        int l = t + 256 * j;
        unsigned u32 = __float_as_uint(Mv[(size_t)i * 2048 + l]);
        u32 = (u32 & 0x80000000u) ? ~u32 : (u32 | 0x80000000u);
        keys[l] = ((unsigned long long)u32 << 32) | (unsigned)l;
    }
    __syncthreads();
    for (int it = 0; it < 64; ++it) {
        unsigned long long best = ~0ULL;
#pragma unroll
        for (int j = 0; j < 8; ++j) best = ullmin_(best, keys[t + 256 * j]);
#pragma unroll
        for (int off = 32; off > 0; off >>= 1)
            best = ullmin_(best, __shfl_down(best, off, 64));
        if ((t & 63) == 0) wred[t >> 6] = best;
        __syncthreads();
        unsigned long long m = ullmin_(ullmin_(wred[0], wred[1]), ullmin_(wred[2], wred[3]));
        int l = (int)(m & 0xffffffffu);
        if (t == 0) {
            candIdx[i * 64 + it] = l;
            keys[l] = ~0ULL;
        }
        __syncthreads();
    }
}

// ---------------------------------------------------------------------------
// Exact fp32 re-computation of max_u q·K_sample for the 64 candidates.
// ---------------------------------------------------------------------------
__global__ __launch_bounds__(256) void refine_kernel(const float* __restrict__ qp,
                                                     const float* __restrict__ kp,
                                                     const int* __restrict__ idx,
                                                     const int* __restrict__ candIdx,
                                                     float* __restrict__ refPart) {
    const int blk = blockIdx.x;  // 128
    const int i = blk >> 2, c = blk & 3;
    const int b = i >> 3, h = i & 7;
    const int t = threadIdx.x;
    __shared__ float qc[64][40];
    __shared__ float Ks[128][40];

    {
        const int cand = t >> 2, dp = (t & 3) * 8;
        const int l = candIdx[i * 64 + cand];
        const float* src = qp + ((size_t)i * 2048 + l) * 32 + dp;
        *(float4*)&qc[cand][dp] = *(const float4*)(src);
        *(float4*)&qc[cand][dp + 4] = *(const float4*)(src + 4);
    }
    __syncthreads();

    const int cand = t >> 2, usub = t & 3;
    float qv[32];
#pragma unroll
    for (int z = 0; z < 8; ++z) {
        float4 a = *(const float4*)&qc[cand][z * 4];
        qv[4 * z] = a.x; qv[4 * z + 1] = a.y; qv[4 * z + 2] = a.z; qv[4 * z + 3] = a.w;
    }

    float m = -INFINITY;
    for (int s = 0; s < 4; ++s) {
        {
            const int r = t >> 1, half = t & 1;
            const int u = c * 512 + s * 128 + r;
            const float* krow = kp + (size_t)b * LD_ + (size_t)idx[u] * D_ + h * DH_ + half * 16;
#pragma unroll
            for (int z = 0; z < 4; ++z)
                *(float4*)&Ks[r][half * 16 + z * 4] = *(const float4*)(krow + z * 4);
        }
        __syncthreads();
        for (int ur = usub; ur < 128; ur += 4) {
            float a0 = 0, a1 = 0, a2 = 0, a3 = 0;
#pragma unroll
            for (int z = 0; z < 8; ++z) {
                float4 kv = *(const float4*)&Ks[ur][z * 4];
                a0 = fmaf(qv[4 * z], kv.x, a0);
                a1 = fmaf(qv[4 * z + 1], kv.y, a1);
                a2 = fmaf(qv[4 * z + 2], kv.z, a2);
                a3 = fmaf(qv[4 * z + 3], kv.w, a3);
            }
            m = fmaxf(m, (a0 + a1) + (a2 + a3));
        }
        __syncthreads();
    }
#pragma unroll
    for (int off = 1; off < 4; off <<= 1)
        m = fmaxf(m, __shfl_xor(m, off, 64));
    if ((t & 3) == 0) refPart[((size_t)i * 4 + c) * 64 + cand] = m;
}

// ---------------------------------------------------------------------------
// Final exact top-40 from 64 candidates. One wave per i.
// ---------------------------------------------------------------------------
__global__ __launch_bounds__(64) void select40_kernel(const int* __restrict__ candIdx,
                                                      const float* __restrict__ refPart,
                                                      const float* __restrict__ Qmean,
                                                      int* __restrict__ topIdx) {
    const int i = blockIdx.x;
    const int t = threadIdx.x;
    const int l = candIdx[i * 64 + t];
    float m = -INFINITY;
#pragma unroll
    for (int c = 0; c < 4; ++c) m = fmaxf(m, refPart[((size_t)i * 4 + c) * 64 + t]);
    float Mex = m - Qmean[(size_t)i * 2048 + l];
    unsigned u32 = __float_as_uint(Mex);
    u32 = (u32 & 0x80000000u) ? ~u32 : (u32 | 0x80000000u);
    unsigned long long key = ((unsigned long long)u32 << 32) | (unsigned)l;
    for (int it = 0; it < 40; ++it) {
        unsigned long long k2 = key;
#pragma unroll
        for (int off = 1; off < 64; off <<= 1) k2 = ullmin_(k2, __shfl_xor(k2, off, 64));
        if (key == k2) {
            topIdx[i * 40 + it] = l;
            key = ~0ULL;
        }
    }
}

// ---------------------------------------------------------------------------
// Flash-style attention, split over L. Grid: 32 i x 8 chunks, 320 threads.
// ---------------------------------------------------------------------------
#define SCP 258   // sc row pad (floats)
#define VSP 36    // Vs row pad (floats)

__global__ __launch_bounds__(320) void attn_part(const float* __restrict__ qp,
                                                 const float* __restrict__ kp,
                                                 const float* __restrict__ vp,
                                                 const int* __restrict__ topIdx,
                                                 float* __restrict__ mPart,
                                                 float* __restrict__ sPart,
                                                 float* __restrict__ oPart) {
    const int blk = blockIdx.x;  // 256 = i*8 + c
    const int i = blk >> 3, c = blk & 7;
    const int b = i >> 3, h = i & 7;
    const int t = threadIdx.x;

    __shared__ float Qs[40][32];
    __shared__ float Vs[256][VSP];
    __shared__ float sc[40][SCP];
    __shared__ float mred[40], sred[40];

    {
        const int r = t >> 3, qq = t & 7;
        const int lq = topIdx[i * 40 + r];
        *(float4*)&Qs[r][qq * 4] = *(const float4*)(qp + ((size_t)i * 2048 + lq) * 32 + qq * 4);
    }
    for (int e = t; e < 2048; e += 320) {
        const int r = e >> 3, qq = e & 7;
        *(float4*)&Vs[r][qq * 4] =
            *(const float4*)(vp + (size_t)b * LD_ + (size_t)(c * 256 + r) * 256 + h * 32 + qq * 4);
    }
    __syncthreads();

    const float scale = 0.17677669529663687f;  // 1/sqrt(32)

    if (t < 256) {
        const float* kr = kp + (size_t)b * LD_ + (size_t)(c * 256 + t) * 256 + h * 32;
        float kv[32];
#pragma unroll
        for (int z = 0; z < 8; ++z) {
            float4 x = *(const float4*)(kr + z * 4);
            kv[4 * z] = x.x; kv[4 * z + 1] = x.y; kv[4 * z + 2] = x.z; kv[4 * z + 3] = x.w;
        }
#pragma unroll 4
        for (int j = 0; j < 40; ++j) {
            float a0 = 0, a1 = 0, a2 = 0, a3 = 0;
#pragma unroll
            for (int z = 0; z < 8; ++z) {
                const float4 q4 = *(const float4*)&Qs[j][z * 4];
                a0 = fmaf(kv[4 * z], q4.x, a0);
                a1 = fmaf(kv[4 * z + 1], q4.y, a1);
                a2 = fmaf(kv[4 * z + 2], q4.z, a2);
                a3 = fmaf(kv[4 * z + 3], q4.w, a3);
            }
            sc[j][t] = ((a0 + a1) + (a2 + a3)) * scale;
        }
    }
    __syncthreads();

    {
        const int w = t >> 6, lane = t & 63;
#pragma unroll
        for (int r = 0; r < 8; ++r) {
            const int j = w * 8 + r;
            float x0 = sc[j][lane], x1 = sc[j][lane + 64];
            float x2 = sc[j][lane + 128], x3 = sc[j][lane + 192];
            float m = fmaxf(fmaxf(x0, x1), fmaxf(x2, x3));
#pragma unroll
            for (int off = 1; off < 64; off <<= 1) m = fmaxf(m, __shfl_xor(m, off, 64));
            const float e0 = __expf(x0 - m), e1 = __expf(x1 - m);
            const float e2 = __expf(x2 - m), e3 = __expf(x3 - m);
            sc[j][lane] = e0; sc[j][lane + 64] = e1;
            sc[j][lane + 128] = e2; sc[j][lane + 192] = e3;
            float s = (e0 + e1) + (e2 + e3);
#pragma unroll
            for (int off = 1; off < 64; off <<= 1) s += __shfl_xor(s, off, 64);
            if (lane == 0) { mred[j] = m; sred[j] = s; }
        }
    }
    __syncthreads();

    {
        const int j = t >> 3, qq = t & 7;
        float4 acc = make_float4(0.f, 0.f, 0.f, 0.f);
        for (int l = 0; l < 256; ++l) {
            const float p = sc[j][l];
            const float4 v4 = *(const float4*)&Vs[l][qq * 4];
            acc.x = fmaf(p, v4.x, acc.x);
            acc.y = fmaf(p, v4.y, acc.y);
            acc.z = fmaf(p, v4.z, acc.z);
            acc.w = fmaf(p, v4.w, acc.w);
        }
        const size_t o = (size_t)(i * 8 + c) * 40 + j;
        *(float4*)&oPart[o * 32 + qq * 4] = acc;
        if (qq == 0) { mPart[o] = mred[j]; sPart[o] = sred[j]; }
    }
}

// ---------------------------------------------------------------------------
// Merge the 8 chunk partials per (i,j) with softmax rescaling.
// ---------------------------------------------------------------------------
__global__ __launch_bounds__(256) void attn_combine(const float* __restrict__ mPart,
                                                    const float* __restrict__ sPart,
                                                    const float* __restrict__ oPart,
                                                    float* __restrict__ attnOut) {
    const int i = blockIdx.x;
    const int b = i >> 3, h = i & 7;
    const int t = threadIdx.x;
    for (int e = t; e < 1280; e += 256) {
        const int j = e >> 5, d = e & 31;
        float mv[8];
        float M = -INFINITY;
#pragma unroll
        for (int c = 0; c < 8; ++c) {
            mv[c] = mPart[(size_t)(i * 8 + c) * 40 + j];
            M = fmaxf(M, mv[c]);
        }
        float S = 0.f, O = 0.f;
#pragma unroll
        for (int c = 0; c < 8; ++c) {
            const float sc_ = __expf(mv[c] - M);
            const size_t o = (size_t)(i * 8 + c) * 40 + j;
            S = fmaf(sPart[o], sc_, S);
            O = fmaf(oPart[o * 32 + d], sc_, O);
        }
        attnOut[((size_t)b * 40 + j) * 256 + h * 32 + d] = O / S;
    }
}

// ---------------------------------------------------------------------------
extern "C" void kernel_launch(void* const* d_in, const int* in_sizes, int n_in,
                              void* d_out, int out_size, void* d_ws, size_t ws_size,
                              hipStream_t stream) {
    const float* q  = (const float*)d_in[0];
    const float* k  = (const float*)d_in[1];
    const float* v  = (const float*)d_in[2];
    const float* Wq = (const float*)d_in[3];
    const float* bq = (const float*)d_in[4];
    const float* Wk = (const float*)d_in[5];
    const float* bk = (const float*)d_in[6];
    const float* Wv = (const float*)d_in[7];
    const float* bv = (const float*)d_in[8];
    const float* Wc = (const float*)d_in[9];
    const float* bc = (const float*)d_in[10];
    const int* idx  = (const int*)d_in[11];
    float* out = (float*)d_out;

    char* w = (char*)d_ws;
    float*          qp      = (float*)(w);                        // 8 MB
    float*          kp      = (float*)(w + (8u << 20));           // 8 MB
    float*          vp      = (float*)(w + (16u << 20));          // 8 MB
    unsigned short* Khi     = (unsigned short*)(w + (24u << 20)); // 4 MB (dead after mpart_mfma)
    unsigned short* Klo     = (unsigned short*)(w + (28u << 20)); // 4 MB
    float*          Mmax    = (float*)(w + (32u << 20));                    // 256 KB
    float*          Mv      = (float*)(w + (32u << 20) + (256u << 10));     // 256 KB
    float*          Qmean   = (float*)(w + (32u << 20) + (512u << 10));     // 256 KB
    float*          Ssum    = (float*)(w + (32u << 20) + (768u << 10));     // 4 KB
    int*            candIdx = (int*)  (w + (32u << 20) + (772u << 10));     // 8 KB
    float*          refPart = (float*)(w + (32u << 20) + (780u << 10));     // 32 KB
    int*            topIdx  = (int*)  (w + (32u << 20) + (812u << 10));     // 5 KB
    float*          attnOut = (float*)(w + (32u << 20) + (820u << 10));     // 160 KB
    float*          Kpart   = (float*)(w + (33u << 20));                    // 256 KB
    // attn partials overlay the Khi region (free once mpart_mfma is done):
    float*          mPart   = (float*)(w + (24u << 20));                    // 40 KB
    float*          sPart   = (float*)(w + (24u << 20) + (64u << 10));      // 40 KB
    float*          oPart   = (float*)(w + (24u << 20) + (128u << 10));     // 1.25 MB

    const int Mrows = B_ * L_;  // 8192
    dim3 gProj((Mrows + 63) / 64, 4);
    hipLaunchKernelGGL(gemm_xwT, gProj, dim3(256), 0, stream, q, Wq, bq, qp, Mrows);
    hipLaunchKernelGGL(gemm_xwT, gProj, dim3(256), 0, stream, k, Wk, bk, kp, Mrows);
    hipLaunchKernelGGL(gemm_xwT, gProj, dim3(256), 0, stream, v, Wv, bv, vp, Mrows);

    hipLaunchKernelGGL(ksum_part, dim3(256), dim3(256), 0, stream, kp, idx, Kpart);
    hipLaunchKernelGGL(ksum_final, dim3(4), dim3(256), 0, stream, Kpart, Ssum);
    hipLaunchKernelGGL(kconv_kernel, dim3(256), dim3(256), 0, stream, kp, idx, Khi, Klo);
    hipLaunchKernelGGL(mpart_mfma, dim3(1024), dim3(256), 0, stream, qp, Khi, Klo, Mmax);
    hipLaunchKernelGGL(mcombine_kernel, dim3(256), dim3(256), 0, stream, Mmax, qp, Ssum, Mv, Qmean);
    hipLaunchKernelGGL(topk64_kernel, dim3(32), dim3(256), 0, stream, Mv, candIdx);
    hipLaunchKernelGGL(refine_kernel, dim3(128), dim3(256), 0, stream, qp, kp, idx, candIdx, refPart);
    hipLaunchKernelGGL(select40_kernel, dim3(32), dim3(64), 0, stream, candIdx, refPart, Qmean, topIdx);
    hipLaunchKernelGGL(attn_part, dim3(256), dim3(320), 0, stream, qp, kp, vp, topIdx, mPart, sPart, oPart);
    hipLaunchKernelGGL(attn_combine, dim3(32), dim3(256), 0, stream, mPart, sPart, oPart, attnOut);

    dim3 gOut((B_ * U_ + 63) / 64, 4);  // M = 160
    hipLaunchKernelGGL(gemm_xwT, gOut, dim3(256), 0, stream, attnOut, Wc, bc, out, B_ * U_);
}

// Round 7
// 326.428 us; speedup vs baseline: 1.9750x; 1.0789x over previous
//
#include <hip/hip_runtime.h>
#include <math.h>

// Problem constants
#define B_ 4
#define L_ 2048
#define D_ 256
#define H_ 8
#define DH_ 32
#define NH_ 32           // B*H
#define U_ 40
#define LD_ 524288       // L_*D_ floats per batch

typedef __attribute__((ext_vector_type(8))) short short8;
typedef __attribute__((ext_vector_type(4))) float floatx4;

static __device__ __forceinline__ unsigned long long ullmin_(unsigned long long a, unsigned long long b) {
    return a < b ? a : b;
}
static __device__ __forceinline__ unsigned short f2bf_rne(float x) {
    unsigned u = __float_as_uint(x);
    unsigned r = u + 0x7FFFu + ((u >> 16) & 1u);
    return (unsigned short)(r >> 16);
}
static __device__ __forceinline__ float bf2f(unsigned short h) {
    return __uint_as_float(((unsigned)h) << 16);
}

// ---------------------------------------------------------------------------
// Convert the 4 weight matrices into MFMA B-fragment layout, 3-way split
// bf16 (hi/mid/lo): W = hi + mid + lo captures ~26 mantissa bits >= fp32.
// off(c,k) = (k>>5)*8192 + (c>>4)*512 + (c&15)*32 + (k&31); 65536 shorts each.
// Exactly 16384 threads: 64 blocks x 256.
// ---------------------------------------------------------------------------
__global__ __launch_bounds__(256) void wconv_kernel(const float* __restrict__ Wq,
                                                    const float* __restrict__ Wk,
                                                    const float* __restrict__ Wv,
                                                    const float* __restrict__ Wc,
                                                    unsigned short* __restrict__ Wf3h,
                                                    unsigned short* __restrict__ Wf3m,
                                                    unsigned short* __restrict__ Wf3l,
                                                    unsigned short* __restrict__ Wch,
                                                    unsigned short* __restrict__ Wcm,
                                                    unsigned short* __restrict__ Wcl) {
    const int e = blockIdx.x * 256 + threadIdx.x;  // 0..16383
    const int c = e >> 6;                          // 0..255
    const int k4 = (e & 63) * 4;                   // 0..252
    const size_t off = (size_t)(k4 >> 5) * 8192 + (size_t)(c >> 4) * 512 + (c & 15) * 32 + (k4 & 31);
    const float* srcs[4] = {Wq, Wk, Wv, Wc};
    unsigned short* dsth[4] = {Wf3h, Wf3h + 65536, Wf3h + 131072, Wch};
    unsigned short* dstm[4] = {Wf3m, Wf3m + 65536, Wf3m + 131072, Wcm};
    unsigned short* dstl[4] = {Wf3l, Wf3l + 65536, Wf3l + 131072, Wcl};
#pragma unroll
    for (int widx = 0; widx < 4; ++widx) {
        const float4 x = *(const float4*)(srcs[widx] + (size_t)c * 256 + k4);
        float xs[4] = {x.x, x.y, x.z, x.w};
        unsigned short hv[4], mv[4], lv[4];
#pragma unroll
        for (int j = 0; j < 4; ++j) {
            hv[j] = f2bf_rne(xs[j]);
            const float e1 = xs[j] - bf2f(hv[j]);
            mv[j] = f2bf_rne(e1);
            const float e2 = e1 - bf2f(mv[j]);
            lv[j] = f2bf_rne(e2);
        }
        *(ushort4*)(dsth[widx] + off) = make_ushort4(hv[0], hv[1], hv[2], hv[3]);
        *(ushort4*)(dstm[widx] + off) = make_ushort4(mv[0], mv[1], mv[2], mv[3]);
        *(ushort4*)(dstl[widx] + off) = make_ushort4(lv[0], lv[1], lv[2], lv[3]);
    }
}

// ---------------------------------------------------------------------------
// Y[m,c] = sum_k X[m,k]*W[c,k] + bias[c] via 3-way-split bf16 MFMA, 6 terms:
// hh + hm + mh + hl + lh + mm  (dropped ml/lm/ll are <= 2^-27 relative).
// Per-dot error ~2e-7: more accurate than an fp32 FMA chain -> safe for the
// selection statistic M computed downstream from qp/kp.
// Block: 256 thr = 4 waves; wave owns 16 rows x 128 cols (8 n-tiles, in two
// halves of 4 to bound VGPRs). Grid: (ceil(M/64), 2).
// ---------------------------------------------------------------------------
__global__ __launch_bounds__(256) void gemm_mfma(const float* __restrict__ X,
                                                 const unsigned short* __restrict__ Wfh,
                                                 const unsigned short* __restrict__ Wfm,
                                                 const unsigned short* __restrict__ Wfl,
                                                 const float* __restrict__ bias,
                                                 float* __restrict__ Y, int M) {
    const int t = threadIdx.x;
    const int w = t >> 6, lane = t & 63;
    const int lq = lane & 15, quad = lane >> 4;
    const int rowBase = blockIdx.x * 64 + w * 16;
    const int colBase = blockIdx.y * 128;
    const int m = rowBase + lq;
    const bool mval = (m < M);

    floatx4 acc[8];
#pragma unroll
    for (int nt = 0; nt < 8; ++nt) acc[nt] = (floatx4){0.f, 0.f, 0.f, 0.f};

    for (int kt = 0; kt < 8; ++kt) {
        short8 Ah, Am, Al;
        {
            float xs[8] = {0.f, 0.f, 0.f, 0.f, 0.f, 0.f, 0.f, 0.f};
            if (mval) {
                const float* xr = X + (size_t)m * 256 + kt * 32 + quad * 8;
                const float4 x0 = *(const float4*)xr;
                const float4 x1 = *(const float4*)(xr + 4);
                xs[0] = x0.x; xs[1] = x0.y; xs[2] = x0.z; xs[3] = x0.w;
                xs[4] = x1.x; xs[5] = x1.y; xs[6] = x1.z; xs[7] = x1.w;
            }
#pragma unroll
            for (int j = 0; j < 8; ++j) {
                const unsigned short h = f2bf_rne(xs[j]);
                const float e1 = xs[j] - bf2f(h);
                const unsigned short md = f2bf_rne(e1);
                const float e2 = e1 - bf2f(md);
                Ah[j] = (short)h;
                Am[j] = (short)md;
                Al[j] = (short)f2bf_rne(e2);
            }
        }
        const size_t off0 = (size_t)kt * 8192 + (size_t)(colBase >> 4) * 512 + lq * 32 + quad * 8;
#pragma unroll
        for (int half = 0; half < 2; ++half) {
            short8 Bh[4], Bm[4], Bl[4];
#pragma unroll
            for (int j = 0; j < 4; ++j) {
                const size_t o = off0 + (size_t)(half * 4 + j) * 512;
                Bh[j] = *(const short8*)(Wfh + o);
                Bm[j] = *(const short8*)(Wfm + o);
                Bl[j] = *(const short8*)(Wfl + o);
            }
#pragma unroll
            for (int j = 0; j < 4; ++j) {
                const int nt = half * 4 + j;
                floatx4 a = acc[nt];
                a = __builtin_amdgcn_mfma_f32_16x16x32_bf16(Am, Bm[j], a, 0, 0, 0);
                a = __builtin_amdgcn_mfma_f32_16x16x32_bf16(Ah, Bl[j], a, 0, 0, 0);
                a = __builtin_amdgcn_mfma_f32_16x16x32_bf16(Al, Bh[j], a, 0, 0, 0);
                a = __builtin_amdgcn_mfma_f32_16x16x32_bf16(Ah, Bm[j], a, 0, 0, 0);
                a = __builtin_amdgcn_mfma_f32_16x16x32_bf16(Am, Bh[j], a, 0, 0, 0);
                a = __builtin_amdgcn_mfma_f32_16x16x32_bf16(Ah, Bh[j], a, 0, 0, 0);
                acc[nt] = a;
            }
        }
    }

    // C layout: col = lane&15 (n), row = quad*4+reg (m within wave's 16 rows)
#pragma unroll
    for (int nt = 0; nt < 8; ++nt) {
        const int c = colBase + nt * 16 + lq;
        const float bv = bias[c];
#pragma unroll
        for (int r = 0; r < 4; ++r) {
            const int mr = rowBase + quad * 4 + r;
            if (mr < M) Y[(size_t)mr * 256 + c] = acc[nt][r] + bv;
        }
    }
}

// ---------------------------------------------------------------------------
// Stage 1: Kpart[(b*64+c)][d] = sum_{u in chunk c (32 rows)} kp[b, idx[u], d]
// ---------------------------------------------------------------------------
__global__ __launch_bounds__(256) void ksum_part(const float* __restrict__ kp,
                                                 const int* __restrict__ idx,
                                                 float* __restrict__ Kpart) {
    const int blk = blockIdx.x;
    const int b = blk >> 6, c = blk & 63;
    const int t = threadIdx.x;
    const float* base = kp + (size_t)b * LD_ + t;
    float acc = 0.f;
#pragma unroll 4
    for (int r = 0; r < 32; ++r)
        acc += base[(size_t)idx[c * 32 + r] * D_];
    Kpart[(size_t)blk * D_ + t] = acc;
}

// ---------------------------------------------------------------------------
// Stage 2: Ssum[b*8+h][d] = sum_{c=0..63} Kpart[b*64+c][h*32+d]  (fixed order)
// ---------------------------------------------------------------------------
__global__ __launch_bounds__(256) void ksum_final(const float* __restrict__ Kpart,
                                                  float* __restrict__ Ssum) {
    const int b = blockIdx.x;
    const int t = threadIdx.x;
    const float* p = Kpart + (size_t)b * 64 * D_ + t;
    float acc = 0.f;
#pragma unroll 8
    for (int c = 0; c < 64; ++c) acc += p[(size_t)c * D_];
    const int h = t >> 5, d = t & 31;
    Ssum[(b * 8 + h) * 32 + d] = acc;
}

// ---------------------------------------------------------------------------
// Gather K_sample rows per head and split fp32 -> bf16 hi/lo (2-way: the
// approx M sweep only needs to land the true top-40 inside the top-64).
// ---------------------------------------------------------------------------
__global__ __launch_bounds__(256) void kconv_kernel(const float* __restrict__ kp,
                                                    const int* __restrict__ idx,
                                                    unsigned short* __restrict__ Khi,
                                                    unsigned short* __restrict__ Klo) {
    const int blk = blockIdx.x;  // 256: i*8 + uc
    const int i = blk >> 3, uc = blk & 7;
    const int b = i >> 3, h = i & 7;
    const int t = threadIdx.x;
    const int dq = (t & 7) * 4;
    const int ur = t >> 3;  // 0..31
#pragma unroll
    for (int p = 0; p < 8; ++p) {
        int u = uc * 256 + p * 32 + ur;
        const float4 x = *(const float4*)(kp + (size_t)b * LD_ + (size_t)idx[u] * D_ + h * DH_ + dq);
        float xs[4] = {x.x, x.y, x.z, x.w};
        unsigned short hv[4], lv[4];
#pragma unroll
        for (int j = 0; j < 4; ++j) {
            hv[j] = f2bf_rne(xs[j]);
            lv[j] = f2bf_rne(xs[j] - bf2f(hv[j]));
        }
        size_t o = ((size_t)i * 2048 + u) * 32 + dq;
        *(ushort4*)(Khi + o) = make_ushort4(hv[0], hv[1], hv[2], hv[3]);
        *(ushort4*)(Klo + o) = make_ushort4(lv[0], lv[1], lv[2], lv[3]);
    }
}

// ---------------------------------------------------------------------------
// Approx M-sweep on MFMA (split-bf16, 16x16x32, K=DH=32) + fused mcombine:
// Mv[i,l] = max_u(q·K_sample) - (q·Ssum)/L;  Qmean stored for refine.
// ---------------------------------------------------------------------------
__global__ __launch_bounds__(256) void mpart_mfma(const float* __restrict__ qp,
                                                  const unsigned short* __restrict__ Khi,
                                                  const unsigned short* __restrict__ Klo,
                                                  const float* __restrict__ Ssum,
                                                  float* __restrict__ Mv,
                                                  float* __restrict__ Qmean) {
    const int blk = blockIdx.x;
    const int i = blk >> 5;
    const int lg = blk & 31;
    const int t = threadIdx.x;
    const int w = t >> 6;
    const int lane = t & 63;
    const int lq = lane & 15;
    const int quad = lane >> 4;

    short8 Ah[4], Al[4];
#pragma unroll
    for (int lt = 0; lt < 4; ++lt) {
        const int l = lg * 64 + lt * 16 + lq;
        const float* qrow = qp + ((size_t)i * 2048 + l) * 32 + quad * 8;
        float4 x0 = *(const float4*)(qrow);
        float4 x1 = *(const float4*)(qrow + 4);
        float xs[8] = {x0.x, x0.y, x0.z, x0.w, x1.x, x1.y, x1.z, x1.w};
#pragma unroll
        for (int j = 0; j < 8; ++j) {
            unsigned short h = f2bf_rne(xs[j]);
            unsigned short lo = f2bf_rne(xs[j] - bf2f(h));
            Ah[lt][j] = (short)h;
            Al[lt][j] = (short)lo;
        }
    }

    floatx4 rmax[4];
#pragma unroll
    for (int lt = 0; lt < 4; ++lt)
        rmax[lt] = (floatx4){-INFINITY, -INFINITY, -INFINITY, -INFINITY};

    const size_t kfrag = ((size_t)i * 2048 + w * 512 + lq) * 32 + quad * 8;
    const unsigned short* ph = Khi + kfrag;
    const unsigned short* pl = Klo + kfrag;
#pragma unroll 2
    for (int s = 0; s < 32; ++s) {
        short8 Bh = *(const short8*)(ph + (size_t)s * 512);
        short8 Bl = *(const short8*)(pl + (size_t)s * 512);
#pragma unroll
        for (int lt = 0; lt < 4; ++lt) {
            floatx4 acc = (floatx4){0.f, 0.f, 0.f, 0.f};
            acc = __builtin_amdgcn_mfma_f32_16x16x32_bf16(Al[lt], Bh, acc, 0, 0, 0);
            acc = __builtin_amdgcn_mfma_f32_16x16x32_bf16(Ah[lt], Bl, acc, 0, 0, 0);
            acc = __builtin_amdgcn_mfma_f32_16x16x32_bf16(Ah[lt], Bh, acc, 0, 0, 0);
#pragma unroll
            for (int r = 0; r < 4; ++r) rmax[lt][r] = fmaxf(rmax[lt][r], acc[r]);
        }
    }

#pragma unroll
    for (int lt = 0; lt < 4; ++lt)
#pragma unroll
        for (int r = 0; r < 4; ++r) {
            float v = rmax[lt][r];
#pragma unroll
            for (int off = 1; off < 16; off <<= 1)
                v = fmaxf(v, __shfl_xor(v, off, 64));
            rmax[lt][r] = v;
        }
    __shared__ float red[4][64];
    if (lq == 0) {
#pragma unroll
        for (int lt = 0; lt < 4; ++lt)
#pragma unroll
            for (int r = 0; r < 4; ++r)
                red[w][lt * 16 + quad * 4 + r] = rmax[lt][r];
    }
    __syncthreads();
    if (t < 64) {
        const int l = lg * 64 + t;
        float m = fmaxf(fmaxf(red[0][t], red[1][t]), fmaxf(red[2][t], red[3][t]));
        const float4* q4 = (const float4*)(qp + ((size_t)i * 2048 + l) * 32);
        const float4* s4 = (const float4*)(Ssum + i * 32);
        float qs = 0.f;
#pragma unroll
        for (int z = 0; z < 8; ++z) {
            float4 a = q4[z];
            float4 c = s4[z];
            qs = fmaf(a.x, c.x, qs);
            qs = fmaf(a.y, c.y, qs);
            qs = fmaf(a.z, c.z, qs);
            qs = fmaf(a.w, c.w, qs);
        }
        const float qm = qs * (1.0f / 2048.0f);
        Qmean[(size_t)i * 2048 + l] = qm;
        Mv[(size_t)i * 2048 + l] = m - qm;
    }
}

// ---------------------------------------------------------------------------
// Bottom-64 candidates per i from approx Mv (ascending, index tie-break).
// ---------------------------------------------------------------------------
__global__ __launch_bounds__(256) void topk64_kernel(const float* __restrict__ Mv,
                                                     int* __restrict__ candIdx) {
    const int i = blockIdx.x;
    const int t = threadIdx.x;
    __shared__ unsigned long long keys[2048];
    __shared__ unsigned long long wred[4];
#pragma unroll
    for (int j = 0; j < 8; ++j) {
        int l = t + 256 * j;
        unsigned u32 = __float_as_uint(Mv[(size_t)i * 2048 + l]);
        u32 = (u32 & 0x80000000u) ? ~u32 : (u32 | 0x80000000u);
        keys[l] = ((unsigned long long)u32 << 32) | (unsigned)l;
    }
    __syncthreads();
    for (int it = 0; it < 64; ++it) {
        unsigned long long best = ~0ULL;
#pragma unroll
        for (int j = 0; j < 8; ++j) best = ullmin_(best, keys[t + 256 * j]);
#pragma unroll
        for (int off = 32; off > 0; off >>= 1)
            best = ullmin_(best, __shfl_down(best, off, 64));
        if ((t & 63) == 0) wred[t >> 6] = best;
        __syncthreads();
        unsigned long long m = ullmin_(ullmin_(wred[0], wred[1]), ullmin_(wred[2], wred[3]));
        int l = (int)(m & 0xffffffffu);
        if (t == 0) {
            candIdx[i * 64 + it] = l;
            keys[l] = ~0ULL;
        }
        __syncthreads();
    }
}

// ---------------------------------------------------------------------------
// Exact fp32 re-computation of max_u q·K_sample for the 64 candidates.
// ---------------------------------------------------------------------------
__global__ __launch_bounds__(256) void refine_kernel(const float* __restrict__ qp,
                                                     const float* __restrict__ kp,
                                                     const int* __restrict__ idx,
                                                     const int* __restrict__ candIdx,
                                                     float* __restrict__ refPart) {
    const int blk = blockIdx.x;  // 128
    const int i = blk >> 2, c = blk & 3;
    const int b = i >> 3, h = i & 7;
    const int t = threadIdx.x;
    __shared__ float qc[64][40];
    __shared__ float Ks[128][40];

    {
        const int cand = t >> 2, dp = (t & 3) * 8;
        const int l = candIdx[i * 64 + cand];
        const float* src = qp + ((size_t)i * 2048 + l) * 32 + dp;
        *(float4*)&qc[cand][dp] = *(const float4*)(src);
        *(float4*)&qc[cand][dp + 4] = *(const float4*)(src + 4);
    }
    __syncthreads();

    const int cand = t >> 2, usub = t & 3;
    float qv[32];
#pragma unroll
    for (int z = 0; z < 8; ++z) {
        float4 a = *(const float4*)&qc[cand][z * 4];
        qv[4 * z] = a.x; qv[4 * z + 1] = a.y; qv[4 * z + 2] = a.z; qv[4 * z + 3] = a.w;
    }

    float m = -INFINITY;
    for (int s = 0; s < 4; ++s) {
        {
            const int r = t >> 1, half = t & 1;
            const int u = c * 512 + s * 128 + r;
            const float* krow = kp + (size_t)b * LD_ + (size_t)idx[u] * D_ + h * DH_ + half * 16;
#pragma unroll
            for (int z = 0; z < 4; ++z)
                *(float4*)&Ks[r][half * 16 + z * 4] = *(const float4*)(krow + z * 4);
        }
        __syncthreads();
        for (int ur = usub; ur < 128; ur += 4) {
            float a0 = 0, a1 = 0, a2 = 0, a3 = 0;
#pragma unroll
            for (int z = 0; z < 8; ++z) {
                float4 kv = *(const float4*)&Ks[ur][z * 4];
                a0 = fmaf(qv[4 * z], kv.x, a0);
                a1 = fmaf(qv[4 * z + 1], kv.y, a1);
                a2 = fmaf(qv[4 * z + 2], kv.z, a2);
                a3 = fmaf(qv[4 * z + 3], kv.w, a3);
            }
            m = fmaxf(m, (a0 + a1) + (a2 + a3));
        }
        __syncthreads();
    }
#pragma unroll
    for (int off = 1; off < 4; off <<= 1)
        m = fmaxf(m, __shfl_xor(m, off, 64));
    if ((t & 3) == 0) refPart[((size_t)i * 4 + c) * 64 + cand] = m;
}

// ---------------------------------------------------------------------------
// Final exact top-40 from 64 candidates. One wave per i.
// ---------------------------------------------------------------------------
__global__ __launch_bounds__(64) void select40_kernel(const int* __restrict__ candIdx,
                                                      const float* __restrict__ refPart,
                                                      const float* __restrict__ Qmean,
                                                      int* __restrict__ topIdx) {
    const int i = blockIdx.x;
    const int t = threadIdx.x;
    const int l = candIdx[i * 64 + t];
    float m = -INFINITY;
#pragma unroll
    for (int c = 0; c < 4; ++c) m = fmaxf(m, refPart[((size_t)i * 4 + c) * 64 + t]);
    float Mex = m - Qmean[(size_t)i * 2048 + l];
    unsigned u32 = __float_as_uint(Mex);
    u32 = (u32 & 0x80000000u) ? ~u32 : (u32 | 0x80000000u);
    unsigned long long key = ((unsigned long long)u32 << 32) | (unsigned)l;
    for (int it = 0; it < 40; ++it) {
        unsigned long long k2 = key;
#pragma unroll
        for (int off = 1; off < 64; off <<= 1) k2 = ullmin_(k2, __shfl_xor(k2, off, 64));
        if (key == k2) {
            topIdx[i * 40 + it] = l;
            key = ~0ULL;
        }
    }
}

// ---------------------------------------------------------------------------
// Flash-style attention, split over L. Grid: 32 i x 8 chunks, 320 threads.
// ---------------------------------------------------------------------------
#define SCP 258   // sc row pad (floats)
#define VSP 36    // Vs row pad (floats)

__global__ __launch_bounds__(320) void attn_part(const float* __restrict__ qp,
                                                 const float* __restrict__ kp,
                                                 const float* __restrict__ vp,
                                                 const int* __restrict__ topIdx,
                                                 float* __restrict__ mPart,
                                                 float* __restrict__ sPart,
                                                 float* __restrict__ oPart) {
    const int blk = blockIdx.x;  // 256 = i*8 + c
    const int i = blk >> 3, c = blk & 7;
    const int b = i >> 3, h = i & 7;
    const int t = threadIdx.x;

    __shared__ float Qs[40][32];
    __shared__ float Vs[256][VSP];
    __shared__ float sc[40][SCP];
    __shared__ float mred[40], sred[40];

    {
        const int r = t >> 3, qq = t & 7;
        const int lq = topIdx[i * 40 + r];
        *(float4*)&Qs[r][qq * 4] = *(const float4*)(qp + ((size_t)i * 2048 + lq) * 32 + qq * 4);
    }
    for (int e = t; e < 2048; e += 320) {
        const int r = e >> 3, qq = e & 7;
        *(float4*)&Vs[r][qq * 4] =
            *(const float4*)(vp + (size_t)b * LD_ + (size_t)(c * 256 + r) * 256 + h * 32 + qq * 4);
    }
    __syncthreads();

    const float scale = 0.17677669529663687f;  // 1/sqrt(32)

    if (t < 256) {
        const float* kr = kp + (size_t)b * LD_ + (size_t)(c * 256 + t) * 256 + h * 32;
        float kv[32];
#pragma unroll
        for (int z = 0; z < 8; ++z) {
            float4 x = *(const float4*)(kr + z * 4);
            kv[4 * z] = x.x; kv[4 * z + 1] = x.y; kv[4 * z + 2] = x.z; kv[4 * z + 3] = x.w;
        }
#pragma unroll 4
        for (int j = 0; j < 40; ++j) {
            float a0 = 0, a1 = 0, a2 = 0, a3 = 0;
#pragma unroll
            for (int z = 0; z < 8; ++z) {
                const float4 q4 = *(const float4*)&Qs[j][z * 4];
                a0 = fmaf(kv[4 * z], q4.x, a0);
                a1 = fmaf(kv[4 * z + 1], q4.y, a1);
                a2 = fmaf(kv[4 * z + 2], q4.z, a2);
                a3 = fmaf(kv[4 * z + 3], q4.w, a3);
            }
            sc[j][t] = ((a0 + a1) + (a2 + a3)) * scale;
        }
    }
    __syncthreads();

    {
        const int w = t >> 6, lane = t & 63;
#pragma unroll
        for (int r = 0; r < 8; ++r) {
            const int j = w * 8 + r;
            float x0 = sc[j][lane], x1 = sc[j][lane + 64];
            float x2 = sc[j][lane + 128], x3 = sc[j][lane + 192];
            float m = fmaxf(fmaxf(x0, x1), fmaxf(x2, x3));
#pragma unroll
            for (int off = 1; off < 64; off <<= 1) m = fmaxf(m, __shfl_xor(m, off, 64));
            const float e0 = __expf(x0 - m), e1 = __expf(x1 - m);
            const float e2 = __expf(x2 - m), e3 = __expf(x3 - m);
            sc[j][lane] = e0; sc[j][lane + 64] = e1;
            sc[j][lane + 128] = e2; sc[j][lane + 192] = e3;
            float s = (e0 + e1) + (e2 + e3);
#pragma unroll
            for (int off = 1; off < 64; off <<= 1) s += __shfl_xor(s, off, 64);
            if (lane == 0) { mred[j] = m; sred[j] = s; }
        }
    }
    __syncthreads();

    {
        const int j = t >> 3, qq = t & 7;
        float4 acc = make_float4(0.f, 0.f, 0.f, 0.f);
        for (int l = 0; l < 256; ++l) {
            const float p = sc[j][l];
            const float4 v4 = *(const float4*)&Vs[l][qq * 4];
            acc.x = fmaf(p, v4.x, acc.x);
            acc.y = fmaf(p, v4.y, acc.y);
            acc.z = fmaf(p, v4.z, acc.z);
            acc.w = fmaf(p, v4.w, acc.w);
        }
        const size_t o = (size_t)(i * 8 + c) * 40 + j;
        *(float4*)&oPart[o * 32 + qq * 4] = acc;
        if (qq == 0) { mPart[o] = mred[j]; sPart[o] = sred[j]; }
    }
}

// ---------------------------------------------------------------------------
// Merge the 8 chunk partials per (i,j) with softmax rescaling.
// ---------------------------------------------------------------------------
__global__ __launch_bounds__(256) void attn_combine(const float* __restrict__ mPart,
                                                    const float* __restrict__ sPart,
                                                    const float* __restrict__ oPart,
                                                    float* __restrict__ attnOut) {
    const int i = blockIdx.x;
    const int b = i >> 3, h = i & 7;
    const int t = threadIdx.x;
    for (int e = t; e < 1280; e += 256) {
        const int j = e >> 5, d = e & 31;
        float mv[8];
        float M = -INFINITY;
#pragma unroll
        for (int c = 0; c < 8; ++c) {
            mv[c] = mPart[(size_t)(i * 8 + c) * 40 + j];
            M = fmaxf(M, mv[c]);
        }
        float S = 0.f, O = 0.f;
#pragma unroll
        for (int c = 0; c < 8; ++c) {
            const float sc_ = __expf(mv[c] - M);
            const size_t o = (size_t)(i * 8 + c) * 40 + j;
            S = fmaf(sPart[o], sc_, S);
            O = fmaf(oPart[o * 32 + d], sc_, O);
        }
        attnOut[((size_t)b * 40 + j) * 256 + h * 32 + d] = O / S;
    }
}

// ---------------------------------------------------------------------------
extern "C" void kernel_launch(void* const* d_in, const int* in_sizes, int n_in,
                              void* d_out, int out_size, void* d_ws, size_t ws_size,
                              hipStream_t stream) {
    const float* q  = (const float*)d_in[0];
    const float* k  = (const float*)d_in[1];
    const float* v  = (const float*)d_in[2];
    const float* Wq = (const float*)d_in[3];
    const float* bq = (const float*)d_in[4];
    const float* Wk = (const float*)d_in[5];
    const float* bk = (const float*)d_in[6];
    const float* Wv = (const float*)d_in[7];
    const float* bv = (const float*)d_in[8];
    const float* Wc = (const float*)d_in[9];
    const float* bc = (const float*)d_in[10];
    const int* idx  = (const int*)d_in[11];
    float* out = (float*)d_out;

    // Workspace map (peak ~33 MB + 1.1 MB):
    //  [0,8)MB qp | [8,16) kp | [16,24) vp
    //  [24,28) Khi (kconv); earlier Wf3h/Wf3m/Wf3l (wconv, 1.125 MB, dead
    //          before kconv); later mPart/sPart/oPart (attn partials)
    //  [28,32) Klo
    //  32M+0: Mv (256K; earlier aliased as Kpart) | +256K Qmean (256K)
    //  +512K Wch | +640K Wcm | +768K Wcl (128K each, persistent)
    //  +896K Ssum(4K) | +900K candIdx(8K) | +908K refPart(32K)
    //  +940K topIdx(8K) | +948K attnOut(160K)
    char* w = (char*)d_ws;
    float*          qp      = (float*)(w);
    float*          kp      = (float*)(w + (8u << 20));
    float*          vp      = (float*)(w + (16u << 20));
    unsigned short* Khi     = (unsigned short*)(w + (24u << 20));
    unsigned short* Klo     = (unsigned short*)(w + (28u << 20));
    unsigned short* Wf3h    = (unsigned short*)(w + (24u << 20));                // 384 KB transient
    unsigned short* Wf3m    = (unsigned short*)(w + (24u << 20) + (384u << 10)); // 384 KB transient
    unsigned short* Wf3l    = (unsigned short*)(w + (24u << 20) + (768u << 10)); // 384 KB transient
    float*          Mv      = (float*)(w + (32u << 20));                         // 256 KB
    float*          Kpart   = (float*)(w + (32u << 20));                         // alias (disjoint lifetime)
    float*          Qmean   = (float*)(w + (32u << 20) + (256u << 10));          // 256 KB
    unsigned short* Wch     = (unsigned short*)(w + (32u << 20) + (512u << 10)); // 128 KB persistent
    unsigned short* Wcm     = (unsigned short*)(w + (32u << 20) + (640u << 10)); // 128 KB persistent
    unsigned short* Wcl     = (unsigned short*)(w + (32u << 20) + (768u << 10)); // 128 KB persistent
    float*          Ssum    = (float*)(w + (32u << 20) + (896u << 10));          // 4 KB
    int*            candIdx = (int*)  (w + (32u << 20) + (900u << 10));          // 8 KB
    float*          refPart = (float*)(w + (32u << 20) + (908u << 10));          // 32 KB
    int*            topIdx  = (int*)  (w + (32u << 20) + (940u << 10));          // 8 KB
    float*          attnOut = (float*)(w + (32u << 20) + (948u << 10));          // 160 KB
    float*          mPart   = (float*)(w + (24u << 20));                         // 40 KB (after mpart_mfma)
    float*          sPart   = (float*)(w + (24u << 20) + (64u << 10));           // 40 KB
    float*          oPart   = (float*)(w + (24u << 20) + (128u << 10));          // 1.25 MB

    const int Mrows = B_ * L_;  // 8192
    hipLaunchKernelGGL(wconv_kernel, dim3(64), dim3(256), 0, stream,
                       Wq, Wk, Wv, Wc, Wf3h, Wf3m, Wf3l, Wch, Wcm, Wcl);

    dim3 gProj((Mrows + 63) / 64, 2);
    hipLaunchKernelGGL(gemm_mfma, gProj, dim3(256), 0, stream, q,
                       Wf3h + 0 * 65536, Wf3m + 0 * 65536, Wf3l + 0 * 65536, bq, qp, Mrows);
    hipLaunchKernelGGL(gemm_mfma, gProj, dim3(256), 0, stream, k,
                       Wf3h + 1 * 65536, Wf3m + 1 * 65536, Wf3l + 1 * 65536, bk, kp, Mrows);
    hipLaunchKernelGGL(gemm_mfma, gProj, dim3(256), 0, stream, v,
                       Wf3h + 2 * 65536, Wf3m + 2 * 65536, Wf3l + 2 * 65536, bv, vp, Mrows);

    hipLaunchKernelGGL(ksum_part, dim3(256), dim3(256), 0, stream, kp, idx, Kpart);
    hipLaunchKernelGGL(ksum_final, dim3(4), dim3(256), 0, stream, Kpart, Ssum);
    hipLaunchKernelGGL(kconv_kernel, dim3(256), dim3(256), 0, stream, kp, idx, Khi, Klo);
    hipLaunchKernelGGL(mpart_mfma, dim3(1024), dim3(256), 0, stream, qp, Khi, Klo, Ssum, Mv, Qmean);
    hipLaunchKernelGGL(topk64_kernel, dim3(32), dim3(256), 0, stream, Mv, candIdx);
    hipLaunchKernelGGL(refine_kernel, dim3(128), dim3(256), 0, stream, qp, kp, idx, candIdx, refPart);
    hipLaunchKernelGGL(select40_kernel, dim3(32), dim3(64), 0, stream, candIdx, refPart, Qmean, topIdx);
    hipLaunchKernelGGL(attn_part, dim3(256), dim3(320), 0, stream, qp, kp, vp, topIdx, mPart, sPart, oPart);
    hipLaunchKernelGGL(attn_combine, dim3(32), dim3(256), 0, stream, mPart, sPart, oPart, attnOut);

    dim3 gOut((B_ * U_ + 63) / 64, 2);  // M = 160
    hipLaunchKernelGGL(gemm_mfma, gOut, dim3(256), 0, stream, attnOut, Wch, Wcm, Wcl, bc, out, B_ * U_);
}

// Round 8
// 308.712 us; speedup vs baseline: 2.0884x; 1.0574x over previous
//
#include <hip/hip_runtime.h>
#include <math.h>

// Problem constants
#define B_ 4
#define L_ 2048
#define D_ 256
#define H_ 8
#define DH_ 32
#define NH_ 32           // B*H
#define U_ 40
#define LD_ 524288       // L_*D_ floats per batch

typedef __attribute__((ext_vector_type(8))) short short8;
typedef __attribute__((ext_vector_type(4))) float floatx4;

static __device__ __forceinline__ unsigned long long ullmin_(unsigned long long a, unsigned long long b) {
    return a < b ? a : b;
}
static __device__ __forceinline__ unsigned short f2bf_rne(float x) {
    unsigned u = __float_as_uint(x);
    unsigned r = u + 0x7FFFu + ((u >> 16) & 1u);
    return (unsigned short)(r >> 16);
}
static __device__ __forceinline__ float bf2f(unsigned short h) {
    return __uint_as_float(((unsigned)h) << 16);
}

// ---------------------------------------------------------------------------
// Convert the 4 weight matrices into MFMA B-fragment layout, 3-way split
// bf16 (hi/mid/lo): W = hi + mid + lo captures ~26 mantissa bits >= fp32.
// off(c,k) = (k>>5)*8192 + (c>>4)*512 + (c&15)*32 + (k&31); 65536 shorts each.
// Exactly 16384 threads: 64 blocks x 256.
// ---------------------------------------------------------------------------
__global__ __launch_bounds__(256) void wconv_kernel(const float* __restrict__ Wq,
                                                    const float* __restrict__ Wk,
                                                    const float* __restrict__ Wv,
                                                    const float* __restrict__ Wc,
                                                    unsigned short* __restrict__ Wf3h,
                                                    unsigned short* __restrict__ Wf3m,
                                                    unsigned short* __restrict__ Wf3l,
                                                    unsigned short* __restrict__ Wch,
                                                    unsigned short* __restrict__ Wcm,
                                                    unsigned short* __restrict__ Wcl) {
    const int e = blockIdx.x * 256 + threadIdx.x;  // 0..16383
    const int c = e >> 6;                          // 0..255
    const int k4 = (e & 63) * 4;                   // 0..252
    const size_t off = (size_t)(k4 >> 5) * 8192 + (size_t)(c >> 4) * 512 + (c & 15) * 32 + (k4 & 31);
    const float* srcs[4] = {Wq, Wk, Wv, Wc};
    unsigned short* dsth[4] = {Wf3h, Wf3h + 65536, Wf3h + 131072, Wch};
    unsigned short* dstm[4] = {Wf3m, Wf3m + 65536, Wf3m + 131072, Wcm};
    unsigned short* dstl[4] = {Wf3l, Wf3l + 65536, Wf3l + 131072, Wcl};
#pragma unroll
    for (int widx = 0; widx < 4; ++widx) {
        const float4 x = *(const float4*)(srcs[widx] + (size_t)c * 256 + k4);
        float xs[4] = {x.x, x.y, x.z, x.w};
        unsigned short hv[4], mv[4], lv[4];
#pragma unroll
        for (int j = 0; j < 4; ++j) {
            hv[j] = f2bf_rne(xs[j]);
            const float e1 = xs[j] - bf2f(hv[j]);
            mv[j] = f2bf_rne(e1);
            const float e2 = e1 - bf2f(mv[j]);
            lv[j] = f2bf_rne(e2);
        }
        *(ushort4*)(dsth[widx] + off) = make_ushort4(hv[0], hv[1], hv[2], hv[3]);
        *(ushort4*)(dstm[widx] + off) = make_ushort4(mv[0], mv[1], mv[2], mv[3]);
        *(ushort4*)(dstl[widx] + off) = make_ushort4(lv[0], lv[1], lv[2], lv[3]);
    }
}

// ---------------------------------------------------------------------------
// Batched projection GEMM: all 3 of {q,k,v} x W^T + b in ONE launch.
// 3-way-split bf16 MFMA, 6 terms (hh+hm+mh+hl+lh+mm); per-dot err ~2e-7.
// Grid (128, 4, 3): z picks the matrix; block = 4 waves, each wave owns
// 16 rows x 64 cols (4 n-tiles). M = 8192 exactly -> no bounds checks.
// 1536 blocks = 6 blocks/CU -> real latency hiding (r7 had 1 block/CU).
// ---------------------------------------------------------------------------
__global__ __launch_bounds__(256) void gemm_mfma3(const float* __restrict__ q,
                                                  const float* __restrict__ k,
                                                  const float* __restrict__ v,
                                                  const unsigned short* __restrict__ Wf3h,
                                                  const unsigned short* __restrict__ Wf3m,
                                                  const unsigned short* __restrict__ Wf3l,
                                                  const float* __restrict__ bq,
                                                  const float* __restrict__ bk,
                                                  const float* __restrict__ bv,
                                                  float* __restrict__ qp,
                                                  float* __restrict__ kp,
                                                  float* __restrict__ vp) {
    const int mat = blockIdx.z;
    const float* X = (mat == 0) ? q : (mat == 1) ? k : v;
    const float* bias = (mat == 0) ? bq : (mat == 1) ? bk : bv;
    float* Y = (mat == 0) ? qp : (mat == 1) ? kp : vp;
    const unsigned short* Wfh = Wf3h + (size_t)mat * 65536;
    const unsigned short* Wfm = Wf3m + (size_t)mat * 65536;
    const unsigned short* Wfl = Wf3l + (size_t)mat * 65536;

    const int t = threadIdx.x;
    const int w = t >> 6, lane = t & 63;
    const int lq = lane & 15, quad = lane >> 4;
    const int rowBase = blockIdx.x * 64 + w * 16;
    const int colBase = blockIdx.y * 64;
    const int m = rowBase + lq;

    floatx4 acc[4];
#pragma unroll
    for (int nt = 0; nt < 4; ++nt) acc[nt] = (floatx4){0.f, 0.f, 0.f, 0.f};

    for (int kt = 0; kt < 8; ++kt) {
        short8 Ah, Am, Al;
        {
            const float* xr = X + (size_t)m * 256 + kt * 32 + quad * 8;
            const float4 x0 = *(const float4*)xr;
            const float4 x1 = *(const float4*)(xr + 4);
            float xs[8] = {x0.x, x0.y, x0.z, x0.w, x1.x, x1.y, x1.z, x1.w};
#pragma unroll
            for (int j = 0; j < 8; ++j) {
                const unsigned short h = f2bf_rne(xs[j]);
                const float e1 = xs[j] - bf2f(h);
                const unsigned short md = f2bf_rne(e1);
                const float e2 = e1 - bf2f(md);
                Ah[j] = (short)h;
                Am[j] = (short)md;
                Al[j] = (short)f2bf_rne(e2);
            }
        }
        const size_t off0 = (size_t)kt * 8192 + (size_t)(colBase >> 4) * 512 + lq * 32 + quad * 8;
        short8 Bh[4], Bm[4], Bl[4];
#pragma unroll
        for (int j = 0; j < 4; ++j) {
            const size_t o = off0 + (size_t)j * 512;
            Bh[j] = *(const short8*)(Wfh + o);
            Bm[j] = *(const short8*)(Wfm + o);
            Bl[j] = *(const short8*)(Wfl + o);
        }
#pragma unroll
        for (int j = 0; j < 4; ++j) {
            floatx4 a = acc[j];
            a = __builtin_amdgcn_mfma_f32_16x16x32_bf16(Am, Bm[j], a, 0, 0, 0);
            a = __builtin_amdgcn_mfma_f32_16x16x32_bf16(Ah, Bl[j], a, 0, 0, 0);
            a = __builtin_amdgcn_mfma_f32_16x16x32_bf16(Al, Bh[j], a, 0, 0, 0);
            a = __builtin_amdgcn_mfma_f32_16x16x32_bf16(Ah, Bm[j], a, 0, 0, 0);
            a = __builtin_amdgcn_mfma_f32_16x16x32_bf16(Am, Bh[j], a, 0, 0, 0);
            a = __builtin_amdgcn_mfma_f32_16x16x32_bf16(Ah, Bh[j], a, 0, 0, 0);
            acc[j] = a;
        }
    }

    // C layout: col = lane&15 (n), row = quad*4+reg
#pragma unroll
    for (int nt = 0; nt < 4; ++nt) {
        const int c = colBase + nt * 16 + lq;
        const float bv_ = bias[c];
#pragma unroll
        for (int r = 0; r < 4; ++r) {
            const int mr = rowBase + quad * 4 + r;
            Y[(size_t)mr * 256 + c] = acc[nt][r] + bv_;
        }
    }
}

// ---------------------------------------------------------------------------
// Final-projection GEMM (M=160), bounds-checked, 6-term split. Grid (3, 2).
// ---------------------------------------------------------------------------
__global__ __launch_bounds__(256) void gemm_mfma(const float* __restrict__ X,
                                                 const unsigned short* __restrict__ Wfh,
                                                 const unsigned short* __restrict__ Wfm,
                                                 const unsigned short* __restrict__ Wfl,
                                                 const float* __restrict__ bias,
                                                 float* __restrict__ Y, int M) {
    const int t = threadIdx.x;
    const int w = t >> 6, lane = t & 63;
    const int lq = lane & 15, quad = lane >> 4;
    const int rowBase = blockIdx.x * 64 + w * 16;
    const int colBase = blockIdx.y * 128;
    const int m = rowBase + lq;
    const bool mval = (m < M);

    floatx4 acc[8];
#pragma unroll
    for (int nt = 0; nt < 8; ++nt) acc[nt] = (floatx4){0.f, 0.f, 0.f, 0.f};

    for (int kt = 0; kt < 8; ++kt) {
        short8 Ah, Am, Al;
        {
            float xs[8] = {0.f, 0.f, 0.f, 0.f, 0.f, 0.f, 0.f, 0.f};
            if (mval) {
                const float* xr = X + (size_t)m * 256 + kt * 32 + quad * 8;
                const float4 x0 = *(const float4*)xr;
                const float4 x1 = *(const float4*)(xr + 4);
                xs[0] = x0.x; xs[1] = x0.y; xs[2] = x0.z; xs[3] = x0.w;
                xs[4] = x1.x; xs[5] = x1.y; xs[6] = x1.z; xs[7] = x1.w;
            }
#pragma unroll
            for (int j = 0; j < 8; ++j) {
                const unsigned short h = f2bf_rne(xs[j]);
                const float e1 = xs[j] - bf2f(h);
                const unsigned short md = f2bf_rne(e1);
                const float e2 = e1 - bf2f(md);
                Ah[j] = (short)h;
                Am[j] = (short)md;
                Al[j] = (short)f2bf_rne(e2);
            }
        }
        const size_t off0 = (size_t)kt * 8192 + (size_t)(colBase >> 4) * 512 + lq * 32 + quad * 8;
#pragma unroll
        for (int half = 0; half < 2; ++half) {
            short8 Bh[4], Bm[4], Bl[4];
#pragma unroll
            for (int j = 0; j < 4; ++j) {
                const size_t o = off0 + (size_t)(half * 4 + j) * 512;
                Bh[j] = *(const short8*)(Wfh + o);
                Bm[j] = *(const short8*)(Wfm + o);
                Bl[j] = *(const short8*)(Wfl + o);
            }
#pragma unroll
            for (int j = 0; j < 4; ++j) {
                const int nt = half * 4 + j;
                floatx4 a = acc[nt];
                a = __builtin_amdgcn_mfma_f32_16x16x32_bf16(Am, Bm[j], a, 0, 0, 0);
                a = __builtin_amdgcn_mfma_f32_16x16x32_bf16(Ah, Bl[j], a, 0, 0, 0);
                a = __builtin_amdgcn_mfma_f32_16x16x32_bf16(Al, Bh[j], a, 0, 0, 0);
                a = __builtin_amdgcn_mfma_f32_16x16x32_bf16(Ah, Bm[j], a, 0, 0, 0);
                a = __builtin_amdgcn_mfma_f32_16x16x32_bf16(Am, Bh[j], a, 0, 0, 0);
                a = __builtin_amdgcn_mfma_f32_16x16x32_bf16(Ah, Bh[j], a, 0, 0, 0);
                acc[nt] = a;
            }
        }
    }

#pragma unroll
    for (int nt = 0; nt < 8; ++nt) {
        const int c = colBase + nt * 16 + lq;
        const float bv = bias[c];
#pragma unroll
        for (int r = 0; r < 4; ++r) {
            const int mr = rowBase + quad * 4 + r;
            if (mr < M) Y[(size_t)mr * 256 + c] = acc[nt][r] + bv;
        }
    }
}

// ---------------------------------------------------------------------------
// Stage 1: Kpart[(b*64+c)][d] = sum_{u in chunk c (32 rows)} kp[b, idx[u], d]
// ---------------------------------------------------------------------------
__global__ __launch_bounds__(256) void ksum_part(const float* __restrict__ kp,
                                                 const int* __restrict__ idx,
                                                 float* __restrict__ Kpart) {
    const int blk = blockIdx.x;
    const int b = blk >> 6, c = blk & 63;
    const int t = threadIdx.x;
    const float* base = kp + (size_t)b * LD_ + t;
    float acc = 0.f;
#pragma unroll 4
    for (int r = 0; r < 32; ++r)
        acc += base[(size_t)idx[c * 32 + r] * D_];
    Kpart[(size_t)blk * D_ + t] = acc;
}

// ---------------------------------------------------------------------------
// Stage 2: Ssum[b*8+h][d] = sum_{c=0..63} Kpart[b*64+c][h*32+d]  (fixed order)
// ---------------------------------------------------------------------------
__global__ __launch_bounds__(256) void ksum_final(const float* __restrict__ Kpart,
                                                  float* __restrict__ Ssum) {
    const int b = blockIdx.x;
    const int t = threadIdx.x;
    const float* p = Kpart + (size_t)b * 64 * D_ + t;
    float acc = 0.f;
#pragma unroll 8
    for (int c = 0; c < 64; ++c) acc += p[(size_t)c * D_];
    const int h = t >> 5, d = t & 31;
    Ssum[(b * 8 + h) * 32 + d] = acc;
}

// ---------------------------------------------------------------------------
// Gather K_sample rows per head and split fp32 -> bf16 hi/lo (2-way: the
// approx M sweep only needs to land the true top-40 inside the top-64).
// ---------------------------------------------------------------------------
__global__ __launch_bounds__(256) void kconv_kernel(const float* __restrict__ kp,
                                                    const int* __restrict__ idx,
                                                    unsigned short* __restrict__ Khi,
                                                    unsigned short* __restrict__ Klo) {
    const int blk = blockIdx.x;  // 256: i*8 + uc
    const int i = blk >> 3, uc = blk & 7;
    const int b = i >> 3, h = i & 7;
    const int t = threadIdx.x;
    const int dq = (t & 7) * 4;
    const int ur = t >> 3;  // 0..31
#pragma unroll
    for (int p = 0; p < 8; ++p) {
        int u = uc * 256 + p * 32 + ur;
        const float4 x = *(const float4*)(kp + (size_t)b * LD_ + (size_t)idx[u] * D_ + h * DH_ + dq);
        float xs[4] = {x.x, x.y, x.z, x.w};
        unsigned short hv[4], lv[4];
#pragma unroll
        for (int j = 0; j < 4; ++j) {
            hv[j] = f2bf_rne(xs[j]);
            lv[j] = f2bf_rne(xs[j] - bf2f(hv[j]));
        }
        size_t o = ((size_t)i * 2048 + u) * 32 + dq;
        *(ushort4*)(Khi + o) = make_ushort4(hv[0], hv[1], hv[2], hv[3]);
        *(ushort4*)(Klo + o) = make_ushort4(lv[0], lv[1], lv[2], lv[3]);
    }
}

// ---------------------------------------------------------------------------
// Approx M-sweep on MFMA (split-bf16, 16x16x32, K=DH=32) + fused mcombine:
// Mv[i,l] = max_u(q·K_sample) - (q·Ssum)/L;  Qmean stored for refine.
// ---------------------------------------------------------------------------
__global__ __launch_bounds__(256) void mpart_mfma(const float* __restrict__ qp,
                                                  const unsigned short* __restrict__ Khi,
                                                  const unsigned short* __restrict__ Klo,
                                                  const float* __restrict__ Ssum,
                                                  float* __restrict__ Mv,
                                                  float* __restrict__ Qmean) {
    const int blk = blockIdx.x;
    const int i = blk >> 5;
    const int lg = blk & 31;
    const int t = threadIdx.x;
    const int w = t >> 6;
    const int lane = t & 63;
    const int lq = lane & 15;
    const int quad = lane >> 4;

    short8 Ah[4], Al[4];
#pragma unroll
    for (int lt = 0; lt < 4; ++lt) {
        const int l = lg * 64 + lt * 16 + lq;
        const float* qrow = qp + ((size_t)i * 2048 + l) * 32 + quad * 8;
        float4 x0 = *(const float4*)(qrow);
        float4 x1 = *(const float4*)(qrow + 4);
        float xs[8] = {x0.x, x0.y, x0.z, x0.w, x1.x, x1.y, x1.z, x1.w};
#pragma unroll
        for (int j = 0; j < 8; ++j) {
            unsigned short h = f2bf_rne(xs[j]);
            unsigned short lo = f2bf_rne(xs[j] - bf2f(h));
            Ah[lt][j] = (short)h;
            Al[lt][j] = (short)lo;
        }
    }

    floatx4 rmax[4];
#pragma unroll
    for (int lt = 0; lt < 4; ++lt)
        rmax[lt] = (floatx4){-INFINITY, -INFINITY, -INFINITY, -INFINITY};

    const size_t kfrag = ((size_t)i * 2048 + w * 512 + lq) * 32 + quad * 8;
    const unsigned short* ph = Khi + kfrag;
    const unsigned short* pl = Klo + kfrag;
#pragma unroll 2
    for (int s = 0; s < 32; ++s) {
        short8 Bh = *(const short8*)(ph + (size_t)s * 512);
        short8 Bl = *(const short8*)(pl + (size_t)s * 512);
#pragma unroll
        for (int lt = 0; lt < 4; ++lt) {
            floatx4 acc = (floatx4){0.f, 0.f, 0.f, 0.f};
            acc = __builtin_amdgcn_mfma_f32_16x16x32_bf16(Al[lt], Bh, acc, 0, 0, 0);
            acc = __builtin_amdgcn_mfma_f32_16x16x32_bf16(Ah[lt], Bl, acc, 0, 0, 0);
            acc = __builtin_amdgcn_mfma_f32_16x16x32_bf16(Ah[lt], Bh, acc, 0, 0, 0);
#pragma unroll
            for (int r = 0; r < 4; ++r) rmax[lt][r] = fmaxf(rmax[lt][r], acc[r]);
        }
    }

#pragma unroll
    for (int lt = 0; lt < 4; ++lt)
#pragma unroll
        for (int r = 0; r < 4; ++r) {
            float v = rmax[lt][r];
#pragma unroll
            for (int off = 1; off < 16; off <<= 1)
                v = fmaxf(v, __shfl_xor(v, off, 64));
            rmax[lt][r] = v;
        }
    __shared__ float red[4][64];
    if (lq == 0) {
#pragma unroll
        for (int lt = 0; lt < 4; ++lt)
#pragma unroll
            for (int r = 0; r < 4; ++r)
                red[w][lt * 16 + quad * 4 + r] = rmax[lt][r];
    }
    __syncthreads();
    if (t < 64) {
        const int l = lg * 64 + t;
        float m = fmaxf(fmaxf(red[0][t], red[1][t]), fmaxf(red[2][t], red[3][t]));
        const float4* q4 = (const float4*)(qp + ((size_t)i * 2048 + l) * 32);
        const float4* s4 = (const float4*)(Ssum + i * 32);
        float qs = 0.f;
#pragma unroll
        for (int z = 0; z < 8; ++z) {
            float4 a = q4[z];
            float4 c = s4[z];
            qs = fmaf(a.x, c.x, qs);
            qs = fmaf(a.y, c.y, qs);
            qs = fmaf(a.z, c.z, qs);
            qs = fmaf(a.w, c.w, qs);
        }
        const float qm = qs * (1.0f / 2048.0f);
        Qmean[(size_t)i * 2048 + l] = qm;
        Mv[(size_t)i * 2048 + l] = m - qm;
    }
}

// ---------------------------------------------------------------------------
// Bottom-64 candidates per i from approx Mv. Keys held in REGISTERS (8/thread)
// -- no LDS rescan per iteration. Removal by owner equality (index bits make
// keys unique). Ascending order, index tie-break.
// ---------------------------------------------------------------------------
__global__ __launch_bounds__(256) void topk64_kernel(const float* __restrict__ Mv,
                                                     int* __restrict__ candIdx) {
    const int i = blockIdx.x;
    const int t = threadIdx.x;
    unsigned long long keys[8];
    __shared__ unsigned long long wred[4];
#pragma unroll
    for (int j = 0; j < 8; ++j) {
        const int l = t + 256 * j;
        unsigned u32 = __float_as_uint(Mv[(size_t)i * 2048 + l]);
        u32 = (u32 & 0x80000000u) ? ~u32 : (u32 | 0x80000000u);
        keys[j] = ((unsigned long long)u32 << 32) | (unsigned)l;
    }
    for (int it = 0; it < 64; ++it) {
        unsigned long long best = keys[0];
#pragma unroll
        for (int j = 1; j < 8; ++j) best = ullmin_(best, keys[j]);
#pragma unroll
        for (int off = 1; off < 64; off <<= 1)
            best = ullmin_(best, __shfl_xor(best, off, 64));
        if ((t & 63) == 0) wred[t >> 6] = best;
        __syncthreads();
        const unsigned long long m = ullmin_(ullmin_(wred[0], wred[1]), ullmin_(wred[2], wred[3]));
        if (t == 0) candIdx[i * 64 + it] = (int)(m & 0xffffffffu);
#pragma unroll
        for (int j = 0; j < 8; ++j)
            if (keys[j] == m) keys[j] = ~0ULL;
        __syncthreads();
    }
}

// ---------------------------------------------------------------------------
// Exact fp32 re-computation of max_u q·K_sample for the 64 candidates.
// ---------------------------------------------------------------------------
__global__ __launch_bounds__(256) void refine_kernel(const float* __restrict__ qp,
                                                     const float* __restrict__ kp,
                                                     const int* __restrict__ idx,
                                                     const int* __restrict__ candIdx,
                                                     float* __restrict__ refPart) {
    const int blk = blockIdx.x;  // 128
    const int i = blk >> 2, c = blk & 3;
    const int b = i >> 3, h = i & 7;
    const int t = threadIdx.x;
    __shared__ float qc[64][40];
    __shared__ float Ks[128][40];

    {
        const int cand = t >> 2, dp = (t & 3) * 8;
        const int l = candIdx[i * 64 + cand];
        const float* src = qp + ((size_t)i * 2048 + l) * 32 + dp;
        *(float4*)&qc[cand][dp] = *(const float4*)(src);
        *(float4*)&qc[cand][dp + 4] = *(const float4*)(src + 4);
    }
    __syncthreads();

    const int cand = t >> 2, usub = t & 3;
    float qv[32];
#pragma unroll
    for (int z = 0; z < 8; ++z) {
        float4 a = *(const float4*)&qc[cand][z * 4];
        qv[4 * z] = a.x; qv[4 * z + 1] = a.y; qv[4 * z + 2] = a.z; qv[4 * z + 3] = a.w;
    }

    float m = -INFINITY;
    for (int s = 0; s < 4; ++s) {
        {
            const int r = t >> 1, half = t & 1;
            const int u = c * 512 + s * 128 + r;
            const float* krow = kp + (size_t)b * LD_ + (size_t)idx[u] * D_ + h * DH_ + half * 16;
#pragma unroll
            for (int z = 0; z < 4; ++z)
                *(float4*)&Ks[r][half * 16 + z * 4] = *(const float4*)(krow + z * 4);
        }
        __syncthreads();
        for (int ur = usub; ur < 128; ur += 4) {
            float a0 = 0, a1 = 0, a2 = 0, a3 = 0;
#pragma unroll
            for (int z = 0; z < 8; ++z) {
                float4 kv = *(const float4*)&Ks[ur][z * 4];
                a0 = fmaf(qv[4 * z], kv.x, a0);
                a1 = fmaf(qv[4 * z + 1], kv.y, a1);
                a2 = fmaf(qv[4 * z + 2], kv.z, a2);
                a3 = fmaf(qv[4 * z + 3], kv.w, a3);
            }
            m = fmaxf(m, (a0 + a1) + (a2 + a3));
        }
        __syncthreads();
    }
#pragma unroll
    for (int off = 1; off < 4; off <<= 1)
        m = fmaxf(m, __shfl_xor(m, off, 64));
    if ((t & 3) == 0) refPart[((size_t)i * 4 + c) * 64 + cand] = m;
}

// ---------------------------------------------------------------------------
// Final exact top-40 from 64 candidates. One wave per i.
// ---------------------------------------------------------------------------
__global__ __launch_bounds__(64) void select40_kernel(const int* __restrict__ candIdx,
                                                      const float* __restrict__ refPart,
                                                      const float* __restrict__ Qmean,
                                                      int* __restrict__ topIdx) {
    const int i = blockIdx.x;
    const int t = threadIdx.x;
    const int l = candIdx[i * 64 + t];
    float m = -INFINITY;
#pragma unroll
    for (int c = 0; c < 4; ++c) m = fmaxf(m, refPart[((size_t)i * 4 + c) * 64 + t]);
    float Mex = m - Qmean[(size_t)i * 2048 + l];
    unsigned u32 = __float_as_uint(Mex);
    u32 = (u32 & 0x80000000u) ? ~u32 : (u32 | 0x80000000u);
    unsigned long long key = ((unsigned long long)u32 << 32) | (unsigned)l;
    for (int it = 0; it < 40; ++it) {
        unsigned long long k2 = key;
#pragma unroll
        for (int off = 1; off < 64; off <<= 1) k2 = ullmin_(k2, __shfl_xor(k2, off, 64));
        if (key == k2) {
            topIdx[i * 40 + it] = l;
            key = ~0ULL;
        }
    }
}

// ---------------------------------------------------------------------------
// Flash-style attention, split over L. Grid: 32 i x 8 chunks, 320 threads.
// ---------------------------------------------------------------------------
#define SCP 258   // sc row pad (floats)
#define VSP 36    // Vs row pad (floats)

__global__ __launch_bounds__(320) void attn_part(const float* __restrict__ qp,
                                                 const float* __restrict__ kp,
                                                 const float* __restrict__ vp,
                                                 const int* __restrict__ topIdx,
                                                 float* __restrict__ mPart,
                                                 float* __restrict__ sPart,
                                                 float* __restrict__ oPart) {
    const int blk = blockIdx.x;  // 256 = i*8 + c
    const int i = blk >> 3, c = blk & 7;
    const int b = i >> 3, h = i & 7;
    const int t = threadIdx.x;

    __shared__ float Qs[40][32];
    __shared__ float Vs[256][VSP];
    __shared__ float sc[40][SCP];
    __shared__ float mred[40], sred[40];

    {
        const int r = t >> 3, qq = t & 7;
        const int lq = topIdx[i * 40 + r];
        *(float4*)&Qs[r][qq * 4] = *(const float4*)(qp + ((size_t)i * 2048 + lq) * 32 + qq * 4);
    }
    for (int e = t; e < 2048; e += 320) {
        const int r = e >> 3, qq = e & 7;
        *(float4*)&Vs[r][qq * 4] =
            *(const float4*)(vp + (size_t)b * LD_ + (size_t)(c * 256 + r) * 256 + h * 32 + qq * 4);
    }
    __syncthreads();

    const float scale = 0.17677669529663687f;  // 1/sqrt(32)

    if (t < 256) {
        const float* kr = kp + (size_t)b * LD_ + (size_t)(c * 256 + t) * 256 + h * 32;
        float kv[32];
#pragma unroll
        for (int z = 0; z < 8; ++z) {
            float4 x = *(const float4*)(kr + z * 4);
            kv[4 * z] = x.x; kv[4 * z + 1] = x.y; kv[4 * z + 2] = x.z; kv[4 * z + 3] = x.w;
        }
#pragma unroll 4
        for (int j = 0; j < 40; ++j) {
            float a0 = 0, a1 = 0, a2 = 0, a3 = 0;
#pragma unroll
            for (int z = 0; z < 8; ++z) {
                const float4 q4 = *(const float4*)&Qs[j][z * 4];
                a0 = fmaf(kv[4 * z], q4.x, a0);
                a1 = fmaf(kv[4 * z + 1], q4.y, a1);
                a2 = fmaf(kv[4 * z + 2], q4.z, a2);
                a3 = fmaf(kv[4 * z + 3], q4.w, a3);
            }
            sc[j][t] = ((a0 + a1) + (a2 + a3)) * scale;
        }
    }
    __syncthreads();

    {
        const int w = t >> 6, lane = t & 63;
#pragma unroll
        for (int r = 0; r < 8; ++r) {
            const int j = w * 8 + r;
            float x0 = sc[j][lane], x1 = sc[j][lane + 64];
            float x2 = sc[j][lane + 128], x3 = sc[j][lane + 192];
            float m = fmaxf(fmaxf(x0, x1), fmaxf(x2, x3));
#pragma unroll
            for (int off = 1; off < 64; off <<= 1) m = fmaxf(m, __shfl_xor(m, off, 64));
            const float e0 = __expf(x0 - m), e1 = __expf(x1 - m);
            const float e2 = __expf(x2 - m), e3 = __expf(x3 - m);
            sc[j][lane] = e0; sc[j][lane + 64] = e1;
            sc[j][lane + 128] = e2; sc[j][lane + 192] = e3;
            float s = (e0 + e1) + (e2 + e3);
#pragma unroll
            for (int off = 1; off < 64; off <<= 1) s += __shfl_xor(s, off, 64);
            if (lane == 0) { mred[j] = m; sred[j] = s; }
        }
    }
    __syncthreads();

    {
        const int j = t >> 3, qq = t & 7;
        float4 acc = make_float4(0.f, 0.f, 0.f, 0.f);
        for (int l = 0; l < 256; ++l) {
            const float p = sc[j][l];
            const float4 v4 = *(const float4*)&Vs[l][qq * 4];
            acc.x = fmaf(p, v4.x, acc.x);
            acc.y = fmaf(p, v4.y, acc.y);
            acc.z = fmaf(p, v4.z, acc.z);
            acc.w = fmaf(p, v4.w, acc.w);
        }
        const size_t o = (size_t)(i * 8 + c) * 40 + j;
        *(float4*)&oPart[o * 32 + qq * 4] = acc;
        if (qq == 0) { mPart[o] = mred[j]; sPart[o] = sred[j]; }
    }
}

// ---------------------------------------------------------------------------
// Merge the 8 chunk partials per (i,j) with softmax rescaling.
// ---------------------------------------------------------------------------
__global__ __launch_bounds__(256) void attn_combine(const float* __restrict__ mPart,
                                                    const float* __restrict__ sPart,
                                                    const float* __restrict__ oPart,
                                                    float* __restrict__ attnOut) {
    const int i = blockIdx.x;
    const int b = i >> 3, h = i & 7;
    const int t = threadIdx.x;
    for (int e = t; e < 1280; e += 256) {
        const int j = e >> 5, d = e & 31;
        float mv[8];
        float M = -INFINITY;
#pragma unroll
        for (int c = 0; c < 8; ++c) {
            mv[c] = mPart[(size_t)(i * 8 + c) * 40 + j];
            M = fmaxf(M, mv[c]);
        }
        float S = 0.f, O = 0.f;
#pragma unroll
        for (int c = 0; c < 8; ++c) {
            const float sc_ = __expf(mv[c] - M);
            const size_t o = (size_t)(i * 8 + c) * 40 + j;
            S = fmaf(sPart[o], sc_, S);
            O = fmaf(oPart[o * 32 + d], sc_, O);
        }
        attnOut[((size_t)b * 40 + j) * 256 + h * 32 + d] = O / S;
    }
}

// ---------------------------------------------------------------------------
extern "C" void kernel_launch(void* const* d_in, const int* in_sizes, int n_in,
                              void* d_out, int out_size, void* d_ws, size_t ws_size,
                              hipStream_t stream) {
    const float* q  = (const float*)d_in[0];
    const float* k  = (const float*)d_in[1];
    const float* v  = (const float*)d_in[2];
    const float* Wq = (const float*)d_in[3];
    const float* bq = (const float*)d_in[4];
    const float* Wk = (const float*)d_in[5];
    const float* bk = (const float*)d_in[6];
    const float* Wv = (const float*)d_in[7];
    const float* bv = (const float*)d_in[8];
    const float* Wc = (const float*)d_in[9];
    const float* bc = (const float*)d_in[10];
    const int* idx  = (const int*)d_in[11];
    float* out = (float*)d_out;

    // Workspace map (peak ~33 MB + 1.1 MB):
    //  [0,8)MB qp | [8,16) kp | [16,24) vp
    //  [24,28) Khi (kconv); earlier Wf3h/Wf3m/Wf3l (wconv, 1.125 MB, dead
    //          before kconv); later mPart/sPart/oPart (attn partials)
    //  [28,32) Klo
    //  32M+0: Mv (256K; earlier aliased as Kpart) | +256K Qmean (256K)
    //  +512K Wch | +640K Wcm | +768K Wcl (128K each, persistent)
    //  +896K Ssum(4K) | +900K candIdx(8K) | +908K refPart(32K)
    //  +940K topIdx(8K) | +948K attnOut(160K)
    char* w = (char*)d_ws;
    float*          qp      = (float*)(w);
    float*          kp      = (float*)(w + (8u << 20));
    float*          vp      = (float*)(w + (16u << 20));
    unsigned short* Khi     = (unsigned short*)(w + (24u << 20));
    unsigned short* Klo     = (unsigned short*)(w + (28u << 20));
    unsigned short* Wf3h    = (unsigned short*)(w + (24u << 20));                // 384 KB transient
    unsigned short* Wf3m    = (unsigned short*)(w + (24u << 20) + (384u << 10)); // 384 KB transient
    unsigned short* Wf3l    = (unsigned short*)(w + (24u << 20) + (768u << 10)); // 384 KB transient
    float*          Mv      = (float*)(w + (32u << 20));                         // 256 KB
    float*          Kpart   = (float*)(w + (32u << 20));                         // alias (disjoint lifetime)
    float*          Qmean   = (float*)(w + (32u << 20) + (256u << 10));          // 256 KB
    unsigned short* Wch     = (unsigned short*)(w + (32u << 20) + (512u << 10)); // 128 KB persistent
    unsigned short* Wcm     = (unsigned short*)(w + (32u << 20) + (640u << 10)); // 128 KB persistent
    unsigned short* Wcl     = (unsigned short*)(w + (32u << 20) + (768u << 10)); // 128 KB persistent
    float*          Ssum    = (float*)(w + (32u << 20) + (896u << 10));          // 4 KB
    int*            candIdx = (int*)  (w + (32u << 20) + (900u << 10));          // 8 KB
    float*          refPart = (float*)(w + (32u << 20) + (908u << 10));          // 32 KB
    int*            topIdx  = (int*)  (w + (32u << 20) + (940u << 10));          // 8 KB
    float*          attnOut = (float*)(w + (32u << 20) + (948u << 10));          // 160 KB
    float*          mPart   = (float*)(w + (24u << 20));                         // 40 KB (after mpart_mfma)
    float*          sPart   = (float*)(w + (24u << 20) + (64u << 10));           // 40 KB
    float*          oPart   = (float*)(w + (24u << 20) + (128u << 10));          // 1.25 MB

    hipLaunchKernelGGL(wconv_kernel, dim3(64), dim3(256), 0, stream,
                       Wq, Wk, Wv, Wc, Wf3h, Wf3m, Wf3l, Wch, Wcm, Wcl);

    // Batched q/k/v projections: one launch, 1536 blocks (6/CU).
    hipLaunchKernelGGL(gemm_mfma3, dim3(128, 4, 3), dim3(256), 0, stream,
                       q, k, v, Wf3h, Wf3m, Wf3l, bq, bk, bv, qp, kp, vp);

    hipLaunchKernelGGL(ksum_part, dim3(256), dim3(256), 0, stream, kp, idx, Kpart);
    hipLaunchKernelGGL(ksum_final, dim3(4), dim3(256), 0, stream, Kpart, Ssum);
    hipLaunchKernelGGL(kconv_kernel, dim3(256), dim3(256), 0, stream, kp, idx, Khi, Klo);
    hipLaunchKernelGGL(mpart_mfma, dim3(1024), dim3(256), 0, stream, qp, Khi, Klo, Ssum, Mv, Qmean);
    hipLaunchKernelGGL(topk64_kernel, dim3(32), dim3(256), 0, stream, Mv, candIdx);
    hipLaunchKernelGGL(refine_kernel, dim3(128), dim3(256), 0, stream, qp, kp, idx, candIdx, refPart);
    hipLaunchKernelGGL(select40_kernel, dim3(32), dim3(64), 0, stream, candIdx, refPart, Qmean, topIdx);
    hipLaunchKernelGGL(attn_part, dim3(256), dim3(320), 0, stream, qp, kp, vp, topIdx, mPart, sPart, oPart);
    hipLaunchKernelGGL(attn_combine, dim3(32), dim3(256), 0, stream, mPart, sPart, oPart, attnOut);

    dim3 gOut((B_ * U_ + 63) / 64, 2);  // M = 160
    hipLaunchKernelGGL(gemm_mfma, gOut, dim3(256), 0, stream, attnOut, Wch, Wcm, Wcl, bc, out, B_ * U_);
}

// Round 10
// 274.106 us; speedup vs baseline: 2.3520x; 1.1263x over previous
//
#include <hip/hip_runtime.h>
#include <math.h>

// Problem constants
#define B_ 4
#define L_ 2048
#define D_ 256
#define H_ 8
#define DH_ 32
#define NH_ 32           // B*H
#define U_ 40
#define LD_ 524288       // L_*D_ floats per batch

typedef __attribute__((ext_vector_type(8))) short short8;
typedef __attribute__((ext_vector_type(4))) float floatx4;

static __device__ __forceinline__ unsigned long long ullmin_(unsigned long long a, unsigned long long b) {
    return a < b ? a : b;
}
static __device__ __forceinline__ unsigned short f2bf_rne(float x) {
    unsigned u = __float_as_uint(x);
    unsigned r = u + 0x7FFFu + ((u >> 16) & 1u);
    return (unsigned short)(r >> 16);
}
static __device__ __forceinline__ float bf2f(unsigned short h) {
    return __uint_as_float(((unsigned)h) << 16);
}

// ---------------------------------------------------------------------------
// Convert the 4 weight matrices into MFMA B-fragment layout, 3-way split
// bf16 (hi/mid/lo): W = hi + mid + lo captures ~26 mantissa bits >= fp32.
// off(c,k) = (k>>5)*8192 + (c>>4)*512 + (c&15)*32 + (k&31); 65536 shorts each.
// Exactly 16384 threads: 64 blocks x 256.
// ---------------------------------------------------------------------------
__global__ __launch_bounds__(256) void wconv_kernel(const float* __restrict__ Wq,
                                                    const float* __restrict__ Wk,
                                                    const float* __restrict__ Wv,
                                                    const float* __restrict__ Wc,
                                                    unsigned short* __restrict__ Wf3h,
                                                    unsigned short* __restrict__ Wf3m,
                                                    unsigned short* __restrict__ Wf3l,
                                                    unsigned short* __restrict__ Wch,
                                                    unsigned short* __restrict__ Wcm,
                                                    unsigned short* __restrict__ Wcl) {
    const int e = blockIdx.x * 256 + threadIdx.x;  // 0..16383
    const int c = e >> 6;                          // 0..255
    const int k4 = (e & 63) * 4;                   // 0..252
    const size_t off = (size_t)(k4 >> 5) * 8192 + (size_t)(c >> 4) * 512 + (c & 15) * 32 + (k4 & 31);
    const float* srcs[4] = {Wq, Wk, Wv, Wc};
    unsigned short* dsth[4] = {Wf3h, Wf3h + 65536, Wf3h + 131072, Wch};
    unsigned short* dstm[4] = {Wf3m, Wf3m + 65536, Wf3m + 131072, Wcm};
    unsigned short* dstl[4] = {Wf3l, Wf3l + 65536, Wf3l + 131072, Wcl};
#pragma unroll
    for (int widx = 0; widx < 4; ++widx) {
        const float4 x = *(const float4*)(srcs[widx] + (size_t)c * 256 + k4);
        float xs[4] = {x.x, x.y, x.z, x.w};
        unsigned short hv[4], mv[4], lv[4];
#pragma unroll
        for (int j = 0; j < 4; ++j) {
            hv[j] = f2bf_rne(xs[j]);
            const float e1 = xs[j] - bf2f(hv[j]);
            mv[j] = f2bf_rne(e1);
            const float e2 = e1 - bf2f(mv[j]);
            lv[j] = f2bf_rne(e2);
        }
        *(ushort4*)(dsth[widx] + off) = make_ushort4(hv[0], hv[1], hv[2], hv[3]);
        *(ushort4*)(dstm[widx] + off) = make_ushort4(mv[0], mv[1], mv[2], mv[3]);
        *(ushort4*)(dstl[widx] + off) = make_ushort4(lv[0], lv[1], lv[2], lv[3]);
    }
}

// ---------------------------------------------------------------------------
// Batched projection GEMM v2: all 3 of {q,k,v} x W^T + b, LDS-staged B.
// Grid (64, 4, 3): block = 128 rows x 64 cols of one matrix; 768 blocks.
// B fragments staged to LDS in two 4-kt phases (48 KB) with short8 (16 B)
// units -- ROUND-9 BUG: ushort4 is 8 B, stride was 16 B -> half of LDS was
// uninitialized garbage -> NaN. short8 matches the 8-short stride exactly.
// 3-way-split bf16, 6 MFMA terms; per-dot err ~2e-7.
// ---------------------------------------------------------------------------
__global__ __launch_bounds__(256) void gemm_mfma3(const float* __restrict__ q,
                                                  const float* __restrict__ k,
                                                  const float* __restrict__ v,
                                                  const unsigned short* __restrict__ Wf3h,
                                                  const unsigned short* __restrict__ Wf3m,
                                                  const unsigned short* __restrict__ Wf3l,
                                                  const float* __restrict__ bq,
                                                  const float* __restrict__ bk,
                                                  const float* __restrict__ bv,
                                                  float* __restrict__ qp,
                                                  float* __restrict__ kp,
                                                  float* __restrict__ vp) {
    const int mat = blockIdx.z;
    const float* X = (mat == 0) ? q : (mat == 1) ? k : v;
    const float* bias = (mat == 0) ? bq : (mat == 1) ? bk : bv;
    float* Y = (mat == 0) ? qp : (mat == 1) ? kp : vp;
    const unsigned short* WB[3] = {Wf3h + (size_t)mat * 65536,
                                   Wf3m + (size_t)mat * 65536,
                                   Wf3l + (size_t)mat * 65536};

    const int t = threadIdx.x;
    const int w = t >> 6, lane = t & 63;
    const int lq = lane & 15, quad = lane >> 4;
    const int colBase = blockIdx.y * 64;
    const int rowBaseW = blockIdx.x * 128 + w * 32;  // wave owns 2 m-tiles

    // LDS: one phase = 3 comp x 4 ktl x (4 nt x 512) shorts = 48 KB
    __shared__ unsigned short Bls[24576];

    floatx4 acc[2][4];
#pragma unroll
    for (int mt = 0; mt < 2; ++mt)
#pragma unroll
        for (int nt = 0; nt < 4; ++nt) acc[mt][nt] = (floatx4){0.f, 0.f, 0.f, 0.f};

    const size_t colOff = (size_t)(colBase >> 4) * 512;

    for (int phase = 0; phase < 2; ++phase) {
        // ---- stage 48 KB of B: 3072 x 16B (short8) units, 12 per thread ----
        __syncthreads();  // protect previous phase's readers
#pragma unroll
        for (int r = 0; r < 12; ++r) {
            const int u = t + 256 * r;          // 0..3071
            const int c = u >> 10;              // comp
            const int rem = u & 1023;
            const int ktl = rem >> 8;
            const int pos = (rem & 255) * 8;    // 8 shorts = 16 B per unit
            const size_t src = (size_t)(phase * 4 + ktl) * 8192 + colOff + pos;
            *(short8*)&Bls[((c * 4 + ktl) << 11) + pos] = *(const short8*)(WB[c] + src);
        }
        __syncthreads();

        // ---- compute: 4 ktl x (B-read once, 2 m-tiles) ----
#pragma unroll
        for (int ktl = 0; ktl < 4; ++ktl) {
            const int kt = phase * 4 + ktl;
            short8 Bh[4], Bm[4], Bl[4];
            const int fo = lq * 32 + quad * 8;
#pragma unroll
            for (int j = 0; j < 4; ++j) {
                Bh[j] = *(const short8*)&Bls[((0 * 4 + ktl) << 11) + j * 512 + fo];
                Bm[j] = *(const short8*)&Bls[((1 * 4 + ktl) << 11) + j * 512 + fo];
                Bl[j] = *(const short8*)&Bls[((2 * 4 + ktl) << 11) + j * 512 + fo];
            }
#pragma unroll
            for (int mt = 0; mt < 2; ++mt) {
                const int m = rowBaseW + mt * 16 + lq;
                short8 Ah, Am, Al;
                {
                    const float* xr = X + (size_t)m * 256 + kt * 32 + quad * 8;
                    const float4 x0 = *(const float4*)xr;
                    const float4 x1 = *(const float4*)(xr + 4);
                    float xs[8] = {x0.x, x0.y, x0.z, x0.w, x1.x, x1.y, x1.z, x1.w};
#pragma unroll
                    for (int j = 0; j < 8; ++j) {
                        const unsigned short h = f2bf_rne(xs[j]);
                        const float e1 = xs[j] - bf2f(h);
                        const unsigned short md = f2bf_rne(e1);
                        const float e2 = e1 - bf2f(md);
                        Ah[j] = (short)h;
                        Am[j] = (short)md;
                        Al[j] = (short)f2bf_rne(e2);
                    }
                }
#pragma unroll
                for (int j = 0; j < 4; ++j) {
                    floatx4 a = acc[mt][j];
                    a = __builtin_amdgcn_mfma_f32_16x16x32_bf16(Am, Bm[j], a, 0, 0, 0);
                    a = __builtin_amdgcn_mfma_f32_16x16x32_bf16(Ah, Bl[j], a, 0, 0, 0);
                    a = __builtin_amdgcn_mfma_f32_16x16x32_bf16(Al, Bh[j], a, 0, 0, 0);
                    a = __builtin_amdgcn_mfma_f32_16x16x32_bf16(Ah, Bm[j], a, 0, 0, 0);
                    a = __builtin_amdgcn_mfma_f32_16x16x32_bf16(Am, Bh[j], a, 0, 0, 0);
                    a = __builtin_amdgcn_mfma_f32_16x16x32_bf16(Ah, Bh[j], a, 0, 0, 0);
                    acc[mt][j] = a;
                }
            }
        }
    }

    // C layout: col = lane&15 (n), row = quad*4+reg
#pragma unroll
    for (int mt = 0; mt < 2; ++mt)
#pragma unroll
        for (int nt = 0; nt < 4; ++nt) {
            const int c = colBase + nt * 16 + lq;
            const float bv_ = bias[c];
#pragma unroll
            for (int r = 0; r < 4; ++r) {
                const int mr = rowBaseW + mt * 16 + quad * 4 + r;
                Y[(size_t)mr * 256 + c] = acc[mt][nt][r] + bv_;
            }
        }
}

// ---------------------------------------------------------------------------
// Final-projection GEMM, M=160 exactly (10x16 tiles -> no bounds checks).
// Grid (10, 4), 64 threads (1 wave): wave owns 16 rows x 64 cols.
// ---------------------------------------------------------------------------
__global__ __launch_bounds__(64) void gemm_out(const float* __restrict__ X,
                                               const unsigned short* __restrict__ Wfh,
                                               const unsigned short* __restrict__ Wfm,
                                               const unsigned short* __restrict__ Wfl,
                                               const float* __restrict__ bias,
                                               float* __restrict__ Y) {
    const int lane = threadIdx.x;
    const int lq = lane & 15, quad = lane >> 4;
    const int rowBase = blockIdx.x * 16;
    const int colBase = blockIdx.y * 64;
    const int m = rowBase + lq;

    floatx4 acc[4];
#pragma unroll
    for (int nt = 0; nt < 4; ++nt) acc[nt] = (floatx4){0.f, 0.f, 0.f, 0.f};

    for (int kt = 0; kt < 8; ++kt) {
        short8 Ah, Am, Al;
        {
            const float* xr = X + (size_t)m * 256 + kt * 32 + quad * 8;
            const float4 x0 = *(const float4*)xr;
            const float4 x1 = *(const float4*)(xr + 4);
            float xs[8] = {x0.x, x0.y, x0.z, x0.w, x1.x, x1.y, x1.z, x1.w};
#pragma unroll
            for (int j = 0; j < 8; ++j) {
                const unsigned short h = f2bf_rne(xs[j]);
                const float e1 = xs[j] - bf2f(h);
                const unsigned short md = f2bf_rne(e1);
                const float e2 = e1 - bf2f(md);
                Ah[j] = (short)h;
                Am[j] = (short)md;
                Al[j] = (short)f2bf_rne(e2);
            }
        }
        const size_t off0 = (size_t)kt * 8192 + (size_t)(colBase >> 4) * 512 + lq * 32 + quad * 8;
        short8 Bh[4], Bm[4], Bl[4];
#pragma unroll
        for (int j = 0; j < 4; ++j) {
            const size_t o = off0 + (size_t)j * 512;
            Bh[j] = *(const short8*)(Wfh + o);
            Bm[j] = *(const short8*)(Wfm + o);
            Bl[j] = *(const short8*)(Wfl + o);
        }
#pragma unroll
        for (int j = 0; j < 4; ++j) {
            floatx4 a = acc[j];
            a = __builtin_amdgcn_mfma_f32_16x16x32_bf16(Am, Bm[j], a, 0, 0, 0);
            a = __builtin_amdgcn_mfma_f32_16x16x32_bf16(Ah, Bl[j], a, 0, 0, 0);
            a = __builtin_amdgcn_mfma_f32_16x16x32_bf16(Al, Bh[j], a, 0, 0, 0);
            a = __builtin_amdgcn_mfma_f32_16x16x32_bf16(Ah, Bm[j], a, 0, 0, 0);
            a = __builtin_amdgcn_mfma_f32_16x16x32_bf16(Am, Bh[j], a, 0, 0, 0);
            a = __builtin_amdgcn_mfma_f32_16x16x32_bf16(Ah, Bh[j], a, 0, 0, 0);
            acc[j] = a;
        }
    }

#pragma unroll
    for (int nt = 0; nt < 4; ++nt) {
        const int c = colBase + nt * 16 + lq;
        const float bv = bias[c];
#pragma unroll
        for (int r = 0; r < 4; ++r) {
            const int mr = rowBase + quad * 4 + r;
            Y[(size_t)mr * 256 + c] = acc[nt][r] + bv;
        }
    }
}

// ---------------------------------------------------------------------------
// Stage 1: Kpart[(b*64+c)][d] = sum_{u in chunk c (32 rows)} kp[b, idx[u], d]
// ---------------------------------------------------------------------------
__global__ __launch_bounds__(256) void ksum_part(const float* __restrict__ kp,
                                                 const int* __restrict__ idx,
                                                 float* __restrict__ Kpart) {
    const int blk = blockIdx.x;
    const int b = blk >> 6, c = blk & 63;
    const int t = threadIdx.x;
    const float* base = kp + (size_t)b * LD_ + t;
    float acc = 0.f;
#pragma unroll 4
    for (int r = 0; r < 32; ++r)
        acc += base[(size_t)idx[c * 32 + r] * D_];
    Kpart[(size_t)blk * D_ + t] = acc;
}

// ---------------------------------------------------------------------------
// Stage 2: Ssum[b*8+h][d] = sum_{c=0..63} Kpart[b*64+c][h*32+d]  (fixed order)
// ---------------------------------------------------------------------------
__global__ __launch_bounds__(256) void ksum_final(const float* __restrict__ Kpart,
                                                  float* __restrict__ Ssum) {
    const int b = blockIdx.x;
    const int t = threadIdx.x;
    const float* p = Kpart + (size_t)b * 64 * D_ + t;
    float acc = 0.f;
#pragma unroll 8
    for (int c = 0; c < 64; ++c) acc += p[(size_t)c * D_];
    const int h = t >> 5, d = t & 31;
    Ssum[(b * 8 + h) * 32 + d] = acc;
}

// ---------------------------------------------------------------------------
// Gather K_sample rows per head and split fp32 -> bf16 hi/lo (2-way: the
// approx M sweep only needs to land the true top-40 inside the top-64).
// ---------------------------------------------------------------------------
__global__ __launch_bounds__(256) void kconv_kernel(const float* __restrict__ kp,
                                                    const int* __restrict__ idx,
                                                    unsigned short* __restrict__ Khi,
                                                    unsigned short* __restrict__ Klo) {
    const int blk = blockIdx.x;  // 256: i*8 + uc
    const int i = blk >> 3, uc = blk & 7;
    const int b = i >> 3, h = i & 7;
    const int t = threadIdx.x;
    const int dq = (t & 7) * 4;
    const int ur = t >> 3;  // 0..31
#pragma unroll
    for (int p = 0; p < 8; ++p) {
        int u = uc * 256 + p * 32 + ur;
        const float4 x = *(const float4*)(kp + (size_t)b * LD_ + (size_t)idx[u] * D_ + h * DH_ + dq);
        float xs[4] = {x.x, x.y, x.z, x.w};
        unsigned short hv[4], lv[4];
#pragma unroll
        for (int j = 0; j < 4; ++j) {
            hv[j] = f2bf_rne(xs[j]);
            lv[j] = f2bf_rne(xs[j] - bf2f(hv[j]));
        }
        size_t o = ((size_t)i * 2048 + u) * 32 + dq;
        *(ushort4*)(Khi + o) = make_ushort4(hv[0], hv[1], hv[2], hv[3]);
        *(ushort4*)(Klo + o) = make_ushort4(lv[0], lv[1], lv[2], lv[3]);
    }
}

// ---------------------------------------------------------------------------
// Approx M-sweep on MFMA (split-bf16, 16x16x32, K=DH=32) + fused mcombine:
// Mv[i,l] = max_u(q·K_sample) - (q·Ssum)/L;  Qmean stored for refine.
// ---------------------------------------------------------------------------
__global__ __launch_bounds__(256) void mpart_mfma(const float* __restrict__ qp,
                                                  const unsigned short* __restrict__ Khi,
                                                  const unsigned short* __restrict__ Klo,
                                                  const float* __restrict__ Ssum,
                                                  float* __restrict__ Mv,
                                                  float* __restrict__ Qmean) {
    const int blk = blockIdx.x;
    const int i = blk >> 5;
    const int lg = blk & 31;
    const int t = threadIdx.x;
    const int w = t >> 6;
    const int lane = t & 63;
    const int lq = lane & 15;
    const int quad = lane >> 4;

    short8 Ah[4], Al[4];
#pragma unroll
    for (int lt = 0; lt < 4; ++lt) {
        const int l = lg * 64 + lt * 16 + lq;
        const float* qrow = qp + ((size_t)i * 2048 + l) * 32 + quad * 8;
        float4 x0 = *(const float4*)(qrow);
        float4 x1 = *(const float4*)(qrow + 4);
        float xs[8] = {x0.x, x0.y, x0.z, x0.w, x1.x, x1.y, x1.z, x1.w};
#pragma unroll
        for (int j = 0; j < 8; ++j) {
            unsigned short h = f2bf_rne(xs[j]);
            unsigned short lo = f2bf_rne(xs[j] - bf2f(h));
            Ah[lt][j] = (short)h;
            Al[lt][j] = (short)lo;
        }
    }

    floatx4 rmax[4];
#pragma unroll
    for (int lt = 0; lt < 4; ++lt)
        rmax[lt] = (floatx4){-INFINITY, -INFINITY, -INFINITY, -INFINITY};

    const size_t kfrag = ((size_t)i * 2048 + w * 512 + lq) * 32 + quad * 8;
    const unsigned short* ph = Khi + kfrag;
    const unsigned short* pl = Klo + kfrag;
#pragma unroll 2
    for (int s = 0; s < 32; ++s) {
        short8 Bh = *(const short8*)(ph + (size_t)s * 512);
        short8 Bl = *(const short8*)(pl + (size_t)s * 512);
#pragma unroll
        for (int lt = 0; lt < 4; ++lt) {
            floatx4 acc = (floatx4){0.f, 0.f, 0.f, 0.f};
            acc = __builtin_amdgcn_mfma_f32_16x16x32_bf16(Al[lt], Bh, acc, 0, 0, 0);
            acc = __builtin_amdgcn_mfma_f32_16x16x32_bf16(Ah[lt], Bl, acc, 0, 0, 0);
            acc = __builtin_amdgcn_mfma_f32_16x16x32_bf16(Ah[lt], Bh, acc, 0, 0, 0);
#pragma unroll
            for (int r = 0; r < 4; ++r) rmax[lt][r] = fmaxf(rmax[lt][r], acc[r]);
        }
    }

#pragma unroll
    for (int lt = 0; lt < 4; ++lt)
#pragma unroll
        for (int r = 0; r < 4; ++r) {
            float v = rmax[lt][r];
#pragma unroll
            for (int off = 1; off < 16; off <<= 1)
                v = fmaxf(v, __shfl_xor(v, off, 64));
            rmax[lt][r] = v;
        }
    __shared__ float red[4][64];
    if (lq == 0) {
#pragma unroll
        for (int lt = 0; lt < 4; ++lt)
#pragma unroll
            for (int r = 0; r < 4; ++r)
                red[w][lt * 16 + quad * 4 + r] = rmax[lt][r];
    }
    __syncthreads();
    if (t < 64) {
        const int l = lg * 64 + t;
        float m = fmaxf(fmaxf(red[0][t], red[1][t]), fmaxf(red[2][t], red[3][t]));
        const float4* q4 = (const float4*)(qp + ((size_t)i * 2048 + l) * 32);
        const float4* s4 = (const float4*)(Ssum + i * 32);
        float qs = 0.f;
#pragma unroll
        for (int z = 0; z < 8; ++z) {
            float4 a = q4[z];
            float4 c = s4[z];
            qs = fmaf(a.x, c.x, qs);
            qs = fmaf(a.y, c.y, qs);
            qs = fmaf(a.z, c.z, qs);
            qs = fmaf(a.w, c.w, qs);
        }
        const float qm = qs * (1.0f / 2048.0f);
        Qmean[(size_t)i * 2048 + l] = qm;
        Mv[(size_t)i * 2048 + l] = m - qm;
    }
}

// ---------------------------------------------------------------------------
// Bottom-64 candidates per i from approx Mv. Keys held in REGISTERS.
// ---------------------------------------------------------------------------
__global__ __launch_bounds__(256) void topk64_kernel(const float* __restrict__ Mv,
                                                     int* __restrict__ candIdx) {
    const int i = blockIdx.x;
    const int t = threadIdx.x;
    unsigned long long keys[8];
    __shared__ unsigned long long wred[4];
#pragma unroll
    for (int j = 0; j < 8; ++j) {
        const int l = t + 256 * j;
        unsigned u32 = __float_as_uint(Mv[(size_t)i * 2048 + l]);
        u32 = (u32 & 0x80000000u) ? ~u32 : (u32 | 0x80000000u);
        keys[j] = ((unsigned long long)u32 << 32) | (unsigned)l;
    }
    for (int it = 0; it < 64; ++it) {
        unsigned long long best = keys[0];
#pragma unroll
        for (int j = 1; j < 8; ++j) best = ullmin_(best, keys[j]);
#pragma unroll
        for (int off = 1; off < 64; off <<= 1)
            best = ullmin_(best, __shfl_xor(best, off, 64));
        if ((t & 63) == 0) wred[t >> 6] = best;
        __syncthreads();
        const unsigned long long m = ullmin_(ullmin_(wred[0], wred[1]), ullmin_(wred[2], wred[3]));
        if (t == 0) candIdx[i * 64 + it] = (int)(m & 0xffffffffu);
#pragma unroll
        for (int j = 0; j < 8; ++j)
            if (keys[j] == m) keys[j] = ~0ULL;
        __syncthreads();
    }
}

// ---------------------------------------------------------------------------
// Exact fp32 re-computation of max_u q·K_sample for the 64 candidates.
// ---------------------------------------------------------------------------
__global__ __launch_bounds__(256) void refine_kernel(const float* __restrict__ qp,
                                                     const float* __restrict__ kp,
                                                     const int* __restrict__ idx,
                                                     const int* __restrict__ candIdx,
                                                     float* __restrict__ refPart) {
    const int blk = blockIdx.x;  // 128
    const int i = blk >> 2, c = blk & 3;
    const int b = i >> 3, h = i & 7;
    const int t = threadIdx.x;
    __shared__ float qc[64][40];
    __shared__ float Ks[128][40];

    {
        const int cand = t >> 2, dp = (t & 3) * 8;
        const int l = candIdx[i * 64 + cand];
        const float* src = qp + ((size_t)i * 2048 + l) * 32 + dp;
        *(float4*)&qc[cand][dp] = *(const float4*)(src);
        *(float4*)&qc[cand][dp + 4] = *(const float4*)(src + 4);
    }
    __syncthreads();

    const int cand = t >> 2, usub = t & 3;
    float qv[32];
#pragma unroll
    for (int z = 0; z < 8; ++z) {
        float4 a = *(const float4*)&qc[cand][z * 4];
        qv[4 * z] = a.x; qv[4 * z + 1] = a.y; qv[4 * z + 2] = a.z; qv[4 * z + 3] = a.w;
    }

    float m = -INFINITY;
    for (int s = 0; s < 4; ++s) {
        {
            const int r = t >> 1, half = t & 1;
            const int u = c * 512 + s * 128 + r;
            const float* krow = kp + (size_t)b * LD_ + (size_t)idx[u] * D_ + h * DH_ + half * 16;
#pragma unroll
            for (int z = 0; z < 4; ++z)
                *(float4*)&Ks[r][half * 16 + z * 4] = *(const float4*)(krow + z * 4);
        }
        __syncthreads();
        for (int ur = usub; ur < 128; ur += 4) {
            float a0 = 0, a1 = 0, a2 = 0, a3 = 0;
#pragma unroll
            for (int z = 0; z < 8; ++z) {
                float4 kv = *(const float4*)&Ks[ur][z * 4];
                a0 = fmaf(qv[4 * z], kv.x, a0);
                a1 = fmaf(qv[4 * z + 1], kv.y, a1);
                a2 = fmaf(qv[4 * z + 2], kv.z, a2);
                a3 = fmaf(qv[4 * z + 3], kv.w, a3);
            }
            m = fmaxf(m, (a0 + a1) + (a2 + a3));
        }
        __syncthreads();
    }
#pragma unroll
    for (int off = 1; off < 4; off <<= 1)
        m = fmaxf(m, __shfl_xor(m, off, 64));
    if ((t & 3) == 0) refPart[((size_t)i * 4 + c) * 64 + cand] = m;
}

// ---------------------------------------------------------------------------
// Final exact top-40 from 64 candidates. One wave per i.
// ---------------------------------------------------------------------------
__global__ __launch_bounds__(64) void select40_kernel(const int* __restrict__ candIdx,
                                                      const float* __restrict__ refPart,
                                                      const float* __restrict__ Qmean,
                                                      int* __restrict__ topIdx) {
    const int i = blockIdx.x;
    const int t = threadIdx.x;
    const int l = candIdx[i * 64 + t];
    float m = -INFINITY;
#pragma unroll
    for (int c = 0; c < 4; ++c) m = fmaxf(m, refPart[((size_t)i * 4 + c) * 64 + t]);
    float Mex = m - Qmean[(size_t)i * 2048 + l];
    unsigned u32 = __float_as_uint(Mex);
    u32 = (u32 & 0x80000000u) ? ~u32 : (u32 | 0x80000000u);
    unsigned long long key = ((unsigned long long)u32 << 32) | (unsigned)l;
    for (int it = 0; it < 40; ++it) {
        unsigned long long k2 = key;
#pragma unroll
        for (int off = 1; off < 64; off <<= 1) k2 = ullmin_(k2, __shfl_xor(k2, off, 64));
        if (key == k2) {
            topIdx[i * 40 + it] = l;
            key = ~0ULL;
        }
    }
}

// ---------------------------------------------------------------------------
// Flash-style attention, split over L. Grid: 32 i x 8 chunks, 320 threads.
// ---------------------------------------------------------------------------
#define SCP 258   // sc row pad (floats)
#define VSP 36    // Vs row pad (floats)

__global__ __launch_bounds__(320) void attn_part(const float* __restrict__ qp,
                                                 const float* __restrict__ kp,
                                                 const float* __restrict__ vp,
                                                 const int* __restrict__ topIdx,
                                                 float* __restrict__ mPart,
                                                 float* __restrict__ sPart,
                                                 float* __restrict__ oPart) {
    const int blk = blockIdx.x;  // 256 = i*8 + c
    const int i = blk >> 3, c = blk & 7;
    const int b = i >> 3, h = i & 7;
    const int t = threadIdx.x;

    __shared__ float Qs[40][32];
    __shared__ float Vs[256][VSP];
    __shared__ float sc[40][SCP];
    __shared__ float mred[40], sred[40];

    {
        const int r = t >> 3, qq = t & 7;
        const int lq = topIdx[i * 40 + r];
        *(float4*)&Qs[r][qq * 4] = *(const float4*)(qp + ((size_t)i * 2048 + lq) * 32 + qq * 4);
    }
    for (int e = t; e < 2048; e += 320) {
        const int r = e >> 3, qq = e & 7;
        *(float4*)&Vs[r][qq * 4] =
            *(const float4*)(vp + (size_t)b * LD_ + (size_t)(c * 256 + r) * 256 + h * 32 + qq * 4);
    }
    __syncthreads();

    const float scale = 0.17677669529663687f;  // 1/sqrt(32)

    if (t < 256) {
        const float* kr = kp + (size_t)b * LD_ + (size_t)(c * 256 + t) * 256 + h * 32;
        float kv[32];
#pragma unroll
        for (int z = 0; z < 8; ++z) {
            float4 x = *(const float4*)(kr + z * 4);
            kv[4 * z] = x.x; kv[4 * z + 1] = x.y; kv[4 * z + 2] = x.z; kv[4 * z + 3] = x.w;
        }
#pragma unroll 4
        for (int j = 0; j < 40; ++j) {
            float a0 = 0, a1 = 0, a2 = 0, a3 = 0;
#pragma unroll
            for (int z = 0; z < 8; ++z) {
                const float4 q4 = *(const float4*)&Qs[j][z * 4];
                a0 = fmaf(kv[4 * z], q4.x, a0);
                a1 = fmaf(kv[4 * z + 1], q4.y, a1);
                a2 = fmaf(kv[4 * z + 2], q4.z, a2);
                a3 = fmaf(kv[4 * z + 3], q4.w, a3);
            }
            sc[j][t] = ((a0 + a1) + (a2 + a3)) * scale;
        }
    }
    __syncthreads();

    {
        const int w = t >> 6, lane = t & 63;
#pragma unroll
        for (int r = 0; r < 8; ++r) {
            const int j = w * 8 + r;
            float x0 = sc[j][lane], x1 = sc[j][lane + 64];
            float x2 = sc[j][lane + 128], x3 = sc[j][lane + 192];
            float m = fmaxf(fmaxf(x0, x1), fmaxf(x2, x3));
#pragma unroll
            for (int off = 1; off < 64; off <<= 1) m = fmaxf(m, __shfl_xor(m, off, 64));
            const float e0 = __expf(x0 - m), e1 = __expf(x1 - m);
            const float e2 = __expf(x2 - m), e3 = __expf(x3 - m);
            sc[j][lane] = e0; sc[j][lane + 64] = e1;
            sc[j][lane + 128] = e2; sc[j][lane + 192] = e3;
            float s = (e0 + e1) + (e2 + e3);
#pragma unroll
            for (int off = 1; off < 64; off <<= 1) s += __shfl_xor(s, off, 64);
            if (lane == 0) { mred[j] = m; sred[j] = s; }
        }
    }
    __syncthreads();

    {
        const int j = t >> 3, qq = t & 7;
        float4 acc = make_float4(0.f, 0.f, 0.f, 0.f);
        for (int l = 0; l < 256; ++l) {
            const float p = sc[j][l];
            const float4 v4 = *(const float4*)&Vs[l][qq * 4];
            acc.x = fmaf(p, v4.x, acc.x);
            acc.y = fmaf(p, v4.y, acc.y);
            acc.z = fmaf(p, v4.z, acc.z);
            acc.w = fmaf(p, v4.w, acc.w);
        }
        const size_t o = (size_t)(i * 8 + c) * 40 + j;
        *(float4*)&oPart[o * 32 + qq * 4] = acc;
        if (qq == 0) { mPart[o] = mred[j]; sPart[o] = sred[j]; }
    }
}

// ---------------------------------------------------------------------------
// Merge the 8 chunk partials per (i,j) with softmax rescaling.
// ---------------------------------------------------------------------------
__global__ __launch_bounds__(256) void attn_combine(const float* __restrict__ mPart,
                                                    const float* __restrict__ sPart,
                                                    const float* __restrict__ oPart,
                                                    float* __restrict__ attnOut) {
    const int i = blockIdx.x;
    const int b = i >> 3, h = i & 7;
    const int t = threadIdx.x;
    for (int e = t; e < 1280; e += 256) {
        const int j = e >> 5, d = e & 31;
        float mv[8];
        float M = -INFINITY;
#pragma unroll
        for (int c = 0; c < 8; ++c) {
            mv[c] = mPart[(size_t)(i * 8 + c) * 40 + j];
            M = fmaxf(M, mv[c]);
        }
        float S = 0.f, O = 0.f;
#pragma unroll
        for (int c = 0; c < 8; ++c) {
            const float sc_ = __expf(mv[c] - M);
            const size_t o = (size_t)(i * 8 + c) * 40 + j;
            S = fmaf(sPart[o], sc_, S);
            O = fmaf(oPart[o * 32 + d], sc_, O);
        }
        attnOut[((size_t)b * 40 + j) * 256 + h * 32 + d] = O / S;
    }
}

// ---------------------------------------------------------------------------
extern "C" void kernel_launch(void* const* d_in, const int* in_sizes, int n_in,
                              void* d_out, int out_size, void* d_ws, size_t ws_size,
                              hipStream_t stream) {
    const float* q  = (const float*)d_in[0];
    const float* k  = (const float*)d_in[1];
    const float* v  = (const float*)d_in[2];
    const float* Wq = (const float*)d_in[3];
    const float* bq = (const float*)d_in[4];
    const float* Wk = (const float*)d_in[5];
    const float* bk = (const float*)d_in[6];
    const float* Wv = (const float*)d_in[7];
    const float* bv = (const float*)d_in[8];
    const float* Wc = (const float*)d_in[9];
    const float* bc = (const float*)d_in[10];
    const int* idx  = (const int*)d_in[11];
    float* out = (float*)d_out;

    // Workspace map (peak ~33 MB + 1.1 MB):
    //  [0,8)MB qp | [8,16) kp | [16,24) vp
    //  [24,28) Khi (kconv); earlier Wf3h/Wf3m/Wf3l (wconv, 1.125 MB, dead
    //          before kconv); later mPart/sPart/oPart (attn partials)
    //  [28,32) Klo
    //  32M+0: Mv (256K; earlier aliased as Kpart) | +256K Qmean (256K)
    //  +512K Wch | +640K Wcm | +768K Wcl (128K each, persistent)
    //  +896K Ssum(4K) | +900K candIdx(8K) | +908K refPart(32K)
    //  +940K topIdx(8K) | +948K attnOut(160K)
    char* w = (char*)d_ws;
    float*          qp      = (float*)(w);
    float*          kp      = (float*)(w + (8u << 20));
    float*          vp      = (float*)(w + (16u << 20));
    unsigned short* Khi     = (unsigned short*)(w + (24u << 20));
    unsigned short* Klo     = (unsigned short*)(w + (28u << 20));
    unsigned short* Wf3h    = (unsigned short*)(w + (24u << 20));                // 384 KB transient
    unsigned short* Wf3m    = (unsigned short*)(w + (24u << 20) + (384u << 10)); // 384 KB transient
    unsigned short* Wf3l    = (unsigned short*)(w + (24u << 20) + (768u << 10)); // 384 KB transient
    float*          Mv      = (float*)(w + (32u << 20));                         // 256 KB
    float*          Kpart   = (float*)(w + (32u << 20));                         // alias (disjoint lifetime)
    float*          Qmean   = (float*)(w + (32u << 20) + (256u << 10));          // 256 KB
    unsigned short* Wch     = (unsigned short*)(w + (32u << 20) + (512u << 10)); // 128 KB persistent
    unsigned short* Wcm     = (unsigned short*)(w + (32u << 20) + (640u << 10)); // 128 KB persistent
    unsigned short* Wcl     = (unsigned short*)(w + (32u << 20) + (768u << 10)); // 128 KB persistent
    float*          Ssum    = (float*)(w + (32u << 20) + (896u << 10));          // 4 KB
    int*            candIdx = (int*)  (w + (32u << 20) + (900u << 10));          // 8 KB
    float*          refPart = (float*)(w + (32u << 20) + (908u << 10));          // 32 KB
    int*            topIdx  = (int*)  (w + (32u << 20) + (940u << 10));          // 8 KB
    float*          attnOut = (float*)(w + (32u << 20) + (948u << 10));          // 160 KB
    float*          mPart   = (float*)(w + (24u << 20));                         // 40 KB (after mpart_mfma)
    float*          sPart   = (float*)(w + (24u << 20) + (64u << 10));           // 40 KB
    float*          oPart   = (float*)(w + (24u << 20) + (128u << 10));          // 1.25 MB

    hipLaunchKernelGGL(wconv_kernel, dim3(64), dim3(256), 0, stream,
                       Wq, Wk, Wv, Wc, Wf3h, Wf3m, Wf3l, Wch, Wcm, Wcl);

    // Batched q/k/v projections with LDS-staged B: 768 blocks (3/CU).
    hipLaunchKernelGGL(gemm_mfma3, dim3(64, 4, 3), dim3(256), 0, stream,
                       q, k, v, Wf3h, Wf3m, Wf3l, bq, bk, bv, qp, kp, vp);

    hipLaunchKernelGGL(ksum_part, dim3(256), dim3(256), 0, stream, kp, idx, Kpart);
    hipLaunchKernelGGL(ksum_final, dim3(4), dim3(256), 0, stream, Kpart, Ssum);
    hipLaunchKernelGGL(kconv_kernel, dim3(256), dim3(256), 0, stream, kp, idx, Khi, Klo);
    hipLaunchKernelGGL(mpart_mfma, dim3(1024), dim3(256), 0, stream, qp, Khi, Klo, Ssum, Mv, Qmean);
    hipLaunchKernelGGL(topk64_kernel, dim3(32), dim3(256), 0, stream, Mv, candIdx);
    hipLaunchKernelGGL(refine_kernel, dim3(128), dim3(256), 0, stream, qp, kp, idx, candIdx, refPart);
    hipLaunchKernelGGL(select40_kernel, dim3(32), dim3(64), 0, stream, candIdx, refPart, Qmean, topIdx);
    hipLaunchKernelGGL(attn_part, dim3(256), dim3(320), 0, stream, qp, kp, vp, topIdx, mPart, sPart, oPart);
    hipLaunchKernelGGL(attn_combine, dim3(32), dim3(256), 0, stream, mPart, sPart, oPart, attnOut);

    // Final projection: M=160 = 10x16 tiles, one wave each, grid (10,4).
    hipLaunchKernelGGL(gemm_out, dim3(10, 4), dim3(64), 0, stream,
                       attnOut, Wch, Wcm, Wcl, bc, out);
}